// Round 17
// baseline (266.286 us; speedup 1.0000x reference)
//
#include <hip/hip_runtime.h>
#include <cstddef>

#define NPIX 1024   // H*W = 32*32

// ---------------------------------------------------------------------------
// Workspace layouts (float-slot offsets).
// BATCHED (both residual chains as images 0..31): peak 38,174,720 floats.
// FALLBACK (per-chain, R14 layout): peak 34,045,952 floats.
// ---------------------------------------------------------------------------
static constexpr size_t WQKV_OFF  = 0;
static constexpr size_t WPROJ_OFF = 98304;
static constexpr size_t WINV_OFF  = 163840;
static constexpr size_t WPW_OFF   = 294912;
// batched
static constexpr size_t BXT_OFF   = 425984;
static constexpr size_t BQKV_OFF  = 4620288;
static constexpr size_t BDPW_OFF  = 17203200;
static constexpr size_t BATT_OFF  = 29786112;
static constexpr size_t BT1T_OFF  = 425984;     // alias XT32
static constexpr size_t BH1T_OFF  = 4620288;    // alias QKV32..
static constexpr size_t BH2T_OFF  = 21397504;   // alias DPW-tail+ATT
static constexpr size_t BATCH_NEED_F = 38174720;
// fallback (R14)
static constexpr size_t XT_OFF    = 425984;
static constexpr size_t QKV_OFF   = 2523136;
static constexpr size_t DPW_OFF   = 8814592;
static constexpr size_t ATT_OFF   = 15106048;
static constexpr size_t T1_OFF    = 21463040;
static constexpr size_t T1T_OFF   = 25657344;
static constexpr size_t H1T_OFF   = 425984;
static constexpr size_t H2T_OFF   = 25657344;

typedef __attribute__((ext_vector_type(8))) short bf16x8;
typedef __attribute__((ext_vector_type(8))) unsigned short u16x8;
typedef __attribute__((ext_vector_type(4))) unsigned short u16x4;
typedef __attribute__((ext_vector_type(4))) float f32x4;

__device__ inline unsigned short f2bf(float f) {
    union { float f; unsigned int u; } v; v.f = f;
    unsigned int u = v.u;
    u += 0x7FFFu + ((u >> 16) & 1u);        // round-to-nearest-even
    return (unsigned short)(u >> 16);
}
__device__ inline float bf2f(unsigned short u) {
    union { float f; unsigned int u; } v; v.u = ((unsigned int)u) << 16;
    return v.f;
}
__device__ inline u16x8 zero8() {
    u16x8 z = {0, 0, 0, 0, 0, 0, 0, 0};
    return z;
}

// ---------------------------------------------------------------------------
// Weight convert (all 4 weights in ONE launch): fp32 [O][K] -> bf16 [K/8][O][8]
// ---------------------------------------------------------------------------
__global__ __launch_bounds__(256)
void wconv_all(const float* __restrict__ w0, const float* __restrict__ w1,
               const float* __restrict__ w2, const float* __restrict__ w3,
               unsigned short* __restrict__ d0, unsigned short* __restrict__ d1,
               unsigned short* __restrict__ d2, unsigned short* __restrict__ d3)
{
    const int bid = blockIdx.x;
    const float* W; unsigned short* WB; int O, K, base;
    if (bid < 96)       { W = w0; WB = d0; O = 768;  K = 256;  base = 0;   }
    else if (bid < 160) { W = w1; WB = d1; O = 256;  K = 512;  base = 96;  }
    else if (bid < 288) { W = w2; WB = d2; O = 1024; K = 256;  base = 160; }
    else                { W = w3; WB = d3; O = 256;  K = 1024; base = 288; }
    const int idx = (bid - base) * 256 + threadIdx.x;
    if (idx >= O * (K >> 3)) return;
    const int o = idx % O;
    const int koct = idx / O;
    u16x8 v;
#pragma unroll
    for (int j = 0; j < 8; j++) v[j] = f2bf(W[(size_t)o * K + koct * 8 + j]);
    *(u16x8*)(WB + ((size_t)koct * O + o) * 8) = v;
}

// ---------------------------------------------------------------------------
// Transpose, dual-source: image ib<16 from X0, else X1.
// ---------------------------------------------------------------------------
__global__ __launch_bounds__(256)
void xpose2(const float* __restrict__ X0, const float* __restrict__ X1,
            unsigned short* __restrict__ XT, const int C)
{
    __shared__ float tt[8][260];
    const int t = threadIdx.x;
    const int octs = C >> 3;
    const int strips = octs * 4;
    const int ib = blockIdx.x / strips;
    const int rem = blockIdx.x - ib * strips;
    const int coct = rem >> 2;
    const int n0 = (rem & 3) * 256;
    const float* src = (ib < 16) ? X0 + (size_t)ib * C * NPIX
                                 : X1 + (size_t)(ib - 16) * C * NPIX;
    const int cc = t >> 5;
    const int c8 = (t & 31) * 8;
    const float* xp = src + ((size_t)(coct * 8 + cc)) * NPIX + n0 + c8;
    *(float4*)(&tt[cc][c8])     = *(const float4*)(xp);
    *(float4*)(&tt[cc][c8 + 4]) = *(const float4*)(xp + 4);
    __syncthreads();
    u16x8 v;
#pragma unroll
    for (int j = 0; j < 8; j++) v[j] = f2bf(tt[j][t]);
    *(u16x8*)(XT + (((size_t)ib * octs + coct) * NPIX + n0 + t) * 8) = v;
}

// ---------------------------------------------------------------------------
// MFMA GEMM, DIRECT global->VGPR fragments (no LDS staging, no main-loop
// barriers). Operands blocked bf16 [K/8][rows][8].
// EPI: 0 plain; 1 BN + fp32 residual (res if b<16 else res2, image b&15);
//      2 bias+hswish; 3 DUAL: INTERLEAVED second K-stream X2 into acc2,
//      then v = scale*(acc+acc2) + 2*shift + bf16blk res (b) + res (b+16).
// OMODE: 0 fp32 [c][n] (+ACC); 1 bf16 [c][n]; 2 blocked bf16; 3 fp32+blocked.
// ---------------------------------------------------------------------------
template<int BM, int BN, int EPI, bool ACC, int OMODE>
__global__ __launch_bounds__(256)
void gemm_direct(const unsigned short* __restrict__ X, const unsigned short* __restrict__ X2,
                 const unsigned short* __restrict__ W,
                 float* __restrict__ Y, unsigned short* __restrict__ YB,
                 const int O, const int K,
                 const float* __restrict__ res, const float* __restrict__ res2,
                 const unsigned short* __restrict__ resb,
                 const float* __restrict__ bng, const float* __restrict__ bnb,
                 const float* __restrict__ bnm, const float* __restrict__ bnv,
                 const float* __restrict__ bias)
{
    constexpr int TN = NPIX / BN;
    constexpr int WAVES_N = (BN >= 128) ? 2 : 1;
    constexpr int WM = BM / (4 / WAVES_N);
    constexpr int MI = WM / 16;
    constexpr int NJ = 4;
    constexpr int TSTR = (OMODE == 1) ? (BN + 8) : (BM + 8);
    constexpr int TSZ  = (OMODE == 1) ? BM * TSTR : ((OMODE >= 2) ? BN * TSTR : 64);
    __shared__ unsigned short T[TSZ];

    const int t    = threadIdx.x;
    const int lane = t & 63;
    const int w    = t >> 6;

    // XCD-bijective block swizzle (all grids are multiples of 8)
    const int gx  = gridDim.x;
    const int nwg = gx * gridDim.y;
    int bid = blockIdx.y * gx + blockIdx.x;
    bid = (bid & 7) * (nwg >> 3) + (bid >> 3);
    const int bx = bid % gx;
    const int by = bid / gx;

    const int o0 = bx * BM;
    const int b  = by / TN;
    const int n0 = (by % TN) * BN;

    const int wn = (WAVES_N == 2) ? (w & 1) * 64 : 0;
    const int wo = (WAVES_N == 2) ? (w >> 1) * WM : w * WM;

    const int l16 = lane & 15;
    const int lq  = lane >> 4;

    f32x4 acc[MI][NJ];
    f32x4 acc2[MI][NJ];
#pragma unroll
    for (int i = 0; i < MI; i++)
#pragma unroll
        for (int j = 0; j < NJ; j++) {
            f32x4 z = {0.f, 0.f, 0.f, 0.f};
            acc[i][j] = z;
            acc2[i][j] = z;
        }

    const unsigned short* Ab = W + ((size_t)lq * O + o0 + wo + l16) * 8;
    const size_t strideA = (size_t)O * 8;
    const size_t strideB = (size_t)NPIX * 8;
    const size_t boff = ((size_t)lq * NPIX + n0 + wn + l16) * 8;
    const int octs = K >> 3;                    // multiple of 8

    auto ldA_ = [&](bf16x8* fr, int kb) {
#pragma unroll
        for (int i = 0; i < MI; i++)
            fr[i] = *(const bf16x8*)(Ab + (size_t)kb * strideA + i * 128);
    };
    auto ldB_ = [&](bf16x8* fr, const unsigned short* Bb, int kb) {
#pragma unroll
        for (int j = 0; j < NJ; j++)
            fr[j] = *(const bf16x8*)(Bb + (size_t)kb * strideB + j * 128);
    };
    auto domfma_ = [&](f32x4 (&ac)[MI][NJ], bf16x8* af, bf16x8* bf) {
#pragma unroll
        for (int i = 0; i < MI; i++)
#pragma unroll
            for (int j = 0; j < NJ; j++)
                ac[i][j] = __builtin_amdgcn_mfma_f32_16x16x32_bf16(
                    af[i], bf[j], ac[i][j], 0, 0, 0);
    };

    if (EPI != 3) {
        const unsigned short* Bb = X + (size_t)b * K * NPIX + boff;
        bf16x8 aA[MI], bA[NJ], aB[MI], bB[NJ];
        ldA_(aA, 0); ldB_(bA, Bb, 0);
        for (int kb = 0; kb < octs; kb += 8) {
            ldA_(aB, kb + 4); ldB_(bB, Bb, kb + 4);
            domfma_(acc, aA, bA);
            if (kb + 8 < octs) { ldA_(aA, kb + 8); ldB_(bA, Bb, kb + 8); }
            domfma_(acc, aB, bB);
        }
    } else {
        // interleaved dual stream, shared A
        const unsigned short* B1 = X  + (size_t)b * K * NPIX + boff;
        const unsigned short* B2 = X2 + (size_t)b * K * NPIX + boff;
        bf16x8 aA[MI], aB[MI], b1A[NJ], b1B[NJ], b2A[NJ], b2B[NJ];
        ldA_(aA, 0); ldB_(b1A, B1, 0); ldB_(b2A, B2, 0);
        for (int kb = 0; kb < octs; kb += 8) {
            ldA_(aB, kb + 4);
            ldB_(b1B, B1, kb + 4); ldB_(b2B, B2, kb + 4);
            domfma_(acc,  aA, b1A);
            domfma_(acc2, aA, b2A);
            if (kb + 8 < octs) {
                ldA_(aA, kb + 8);
                ldB_(b1A, B1, kb + 8); ldB_(b2A, B2, kb + 8);
            }
            domfma_(acc,  aB, b1B);
            domfma_(acc2, aB, b2B);
        }
    }

    // epilogue. C/D: col = lane&15 (n), row = (lane>>4)*4 + reg (o)
    const int r0q = lq * 4;
    float scale[MI][4], shift[MI][4];
    if (EPI == 1 || EPI == 3) {
#pragma unroll
        for (int i = 0; i < MI; i++)
#pragma unroll
            for (int r = 0; r < 4; r++) {
                const int o = o0 + wo + i * 16 + r0q + r;
                const float inv = bng[o] / sqrtf(bnv[o] + 1e-5f);
                scale[i][r] = inv;
                shift[i][r] = bnb[o] - bnm[o] * inv;
            }
    } else if (EPI == 2) {
#pragma unroll
        for (int i = 0; i < MI; i++)
#pragma unroll
            for (int r = 0; r < 4; r++)
                shift[i][r] = bias[o0 + wo + i * 16 + r0q + r];
    }

#pragma unroll
    for (int i = 0; i < MI; i++) {
#pragma unroll
        for (int j = 0; j < NJ; j++) {
            const int nn = n0 + wn + j * 16 + l16;
            const int nl = wn + j * 16 + l16;
            const int ob = wo + i * 16 + r0q;
            const size_t base = ((size_t)b * O + o0 + ob) * NPIX + nn;
            u16x4 r1v, r2v;
            if (EPI == 3) {
                const size_t ro = (((size_t)(b * 32 + ((o0 + ob) >> 3)) * NPIX + nn) * 8
                                   + ((o0 + ob) & 7));
                r1v = *(const u16x4*)(resb + ro);
                r2v = *(const u16x4*)(resb + (size_t)16 * 262144 + ro);
            }
            u16x4 p4;
#pragma unroll
            for (int r = 0; r < 4; r++) {
                const size_t off = base + (size_t)r * NPIX;
                float v = acc[i][j][r];
                if (EPI == 1) {
                    const float* rs = (b < 16) ? res : res2;
                    const size_t roff = ((size_t)(b & 15) * O + o0 + ob + r) * NPIX + nn;
                    v = v * scale[i][r] + shift[i][r] + rs[roff];
                } else if (EPI == 2) {
                    v += shift[i][r];
                    v = v * fminf(fmaxf(v + 3.f, 0.f), 6.f) * (1.f / 6.f);
                } else if (EPI == 3) {
                    v = (v + acc2[i][j][r]) * scale[i][r] + 2.f * shift[i][r]
                        + bf2f(r1v[r]) + bf2f(r2v[r]);
                }
                if (OMODE == 0 || OMODE == 3) {
                    if (ACC) v += Y[off];
                    Y[off] = v;
                }
                if (OMODE == 1) {
                    T[(size_t)(ob + r) * TSTR + nl] = f2bf(v);
                } else if (OMODE >= 2) {
                    p4[r] = f2bf(v);
                }
            }
            if (OMODE >= 2)
                *(u16x4*)(T + (size_t)nl * TSTR + ob) = p4;
        }
    }

    if (OMODE >= 1) {
        __syncthreads();
        constexpr int CNT = BM * BN / 2048;
        if (OMODE == 1) {
#pragma unroll
            for (int k = 0; k < CNT; k++) {
                const int idx = t + k * 256;
                const int o   = idx / (BN / 8);
                const int n8  = (idx % (BN / 8)) * 8;
                const u16x8 v = *(const u16x8*)(T + (size_t)o * TSTR + n8);
                *(u16x8*)(YB + ((size_t)b * O + o0 + o) * NPIX + n0 + n8) = v;
            }
        } else {
#pragma unroll
            for (int k = 0; k < CNT; k++) {
                const int idx = t + k * 256;
                const int oo  = idx / BN;
                const int nn  = idx % BN;
                const u16x8 v = *(const u16x8*)(T + (size_t)nn * TSTR + oo * 8);
                *(u16x8*)(YB + (((size_t)b * (O >> 3) + (o0 >> 3) + oo) * NPIX + n0 + nn) * 8) = v;
            }
        }
    }
}

// ---------------------------------------------------------------------------
// Depthwise 5x5 SAME, bf16 [c][n] in/out. 2 channels/block, stride-44 fp32 LDS.
// ---------------------------------------------------------------------------
__global__ __launch_bounds__(256)
void dwconv5x5_v3(const unsigned short* __restrict__ X, const float* __restrict__ Wd,
                  unsigned short* __restrict__ Y)
{
    __shared__ float tile[2 * 36 * 44];
    __shared__ float wl[64];
    const int t     = threadIdx.x;
    const int cpair = blockIdx.x % 384;
    const int b     = blockIdx.x / 384;
    const int cbase = cpair * 2;
    const unsigned short* xp = X + ((size_t)b * 768 + cbase) * NPIX;

#pragma unroll
    for (int k = 0; k < 4; k++) {
        const int i = t + k * 256;
        if (i < 792) {
            f32x4 z = {0.f, 0.f, 0.f, 0.f};
            *(f32x4*)(&tile[i * 4]) = z;
        }
    }
    if (t < 50) wl[(t / 25) * 32 + (t % 25)] = Wd[cbase * 25 + t];
    __syncthreads();

    const int ch = t >> 7;
    const int tm = t & 127;
    const int r  = tm >> 2;
    const int c8 = (tm & 3) * 8;

    {
        const u16x8 v = *(const u16x8*)(xp + (size_t)ch * NPIX + r * 32 + c8);
        float* wp = &tile[ch * 1584 + (r + 2) * 44 + c8 + 2];
#pragma unroll
        for (int j = 0; j < 8; j += 2) {
            float2 f2v = make_float2(bf2f(v[j]), bf2f(v[j + 1]));
            *(float2*)(wp + j) = f2v;
        }
    }
    float wk[25];
#pragma unroll
    for (int i = 0; i < 25; i++) wk[i] = wl[ch * 32 + i];
    __syncthreads();

    float acc[8];
#pragma unroll
    for (int j = 0; j < 8; j++) acc[j] = 0.f;

#pragma unroll
    for (int ky = 0; ky < 5; ky++) {
        const float* rp = &tile[ch * 1584 + (r + ky) * 44 + c8];
        const f32x4 a = *(const f32x4*)(rp);
        const f32x4 bq = *(const f32x4*)(rp + 4);
        const f32x4 cq = *(const f32x4*)(rp + 8);
        const float in[12] = {a[0], a[1], a[2], a[3], bq[0], bq[1], bq[2], bq[3],
                              cq[0], cq[1], cq[2], cq[3]};
#pragma unroll
        for (int kx = 0; kx < 5; kx++) {
            const float wv = wk[ky * 5 + kx];
#pragma unroll
            for (int j = 0; j < 8; j++)
                acc[j] = fmaf(in[j + kx], wv, acc[j]);
        }
    }

    u16x8 o8;
#pragma unroll
    for (int j = 0; j < 8; j++) o8[j] = f2bf(acc[j]);
    *(u16x8*)(Y + ((size_t)b * 768 + cbase + ch) * NPIX + r * 32 + c8) = o8;
}

// ---------------------------------------------------------------------------
// Depthwise 3x3 + bias + hswish, blocked bf16 in/out — DIRECT GLOBAL reads.
// No pixel LDS, no bulk barrier: each thread issues its 18 overlapping
// global_load_dwordx4 (wave window ~4KB/row -> L1/L2 hits), deep MLP,
// waves drift independently. Only weights/bias go through LDS.
// ---------------------------------------------------------------------------
__global__ __launch_bounds__(256)
void dwconv3x3_dg(const unsigned short* __restrict__ X, const float* __restrict__ Wd,
                  const float* __restrict__ bias, unsigned short* __restrict__ Y)
{
    __shared__ float wl[72];
    __shared__ float bb[8];
    const int t    = threadIdx.x;
    const int coct = blockIdx.x & 127;
    const int b    = blockIdx.x >> 7;
    const unsigned short* xp = X + ((size_t)(b * 128 + coct)) * NPIX * 8;
    if (t < 72) wl[t] = Wd[coct * 72 + t];
    if (t < 8)  bb[t] = bias[coct * 8 + t];
    __syncthreads();

    const int px0 = t * 4;
    const int h   = px0 >> 5;
    const int c0  = px0 & 31;

    float acc[8][4];
#pragma unroll
    for (int ch = 0; ch < 8; ch++)
#pragma unroll
        for (int j = 0; j < 4; j++) acc[ch][j] = bb[ch];

#pragma unroll
    for (int ky = 0; ky < 3; ky++) {
        const int rr = h + ky - 1;
        if (rr >= 0 && rr < 32) {
            u16x8 P[6];
#pragma unroll
            for (int m = 0; m < 6; m++) {
                const int col = c0 - 1 + m;
                const int colc = col < 0 ? 0 : (col > 31 ? 31 : col);
                u16x8 v = *(const u16x8*)(xp + (size_t)(rr * 32 + colc) * 8);
                if (col < 0 || col > 31) v = zero8();
                P[m] = v;
            }
#pragma unroll
            for (int ch = 0; ch < 8; ch++) {
                float g[6];
#pragma unroll
                for (int m = 0; m < 6; m++) g[m] = bf2f(P[m][ch]);
#pragma unroll
                for (int j = 0; j < 4; j++)
#pragma unroll
                    for (int kx = 0; kx < 3; kx++)
                        acc[ch][j] = fmaf(g[j + kx], wl[ch * 9 + ky * 3 + kx], acc[ch][j]);
            }
        }
    }
    unsigned short* yp = Y + ((size_t)(b * 128 + coct)) * NPIX * 8 + (size_t)px0 * 8;
#pragma unroll
    for (int j = 0; j < 4; j++) {
        u16x8 o8;
#pragma unroll
        for (int ch = 0; ch < 8; ch++) {
            float v = acc[ch][j];
            v = v * fminf(fmaxf(v + 3.f, 0.f), 6.f) * (1.f / 6.f);
            o8[ch] = f2bf(v);
        }
        *(u16x8*)(yp + j * 8) = o8;
    }
}

// ---------------------------------------------------------------------------
// Grouped 32->32 1x1 (24 groups), in-place on bf16 [c][n] D.
// ---------------------------------------------------------------------------
__global__ __launch_bounds__(256)
void grouped_pw(unsigned short* __restrict__ D, const float* __restrict__ Wg)
{
    __shared__ float ws[1024];
    const int t     = threadIdx.x;
    const int blk   = blockIdx.x;
    const int chunk = blk & 3;
    const int bg    = blk >> 2;
    const int g     = bg % 24;
    const int b     = bg / 24;
    for (int i = t; i < 1024; i += 256) ws[i] = Wg[g * 1024 + i];
    __syncthreads();
    const int px = chunk * 256 + t;
    unsigned short* dp = D + ((size_t)(b * 768 + g * 32)) * NPIX + px;
    float in[32];
#pragma unroll
    for (int i = 0; i < 32; i++) in[i] = bf2f(dp[(size_t)i * NPIX]);
#pragma unroll
    for (int o = 0; o < 32; o++) {
        float s = 0.f;
#pragma unroll
        for (int i = 0; i < 32; i++) s = fmaf(ws[o * 32 + i], in[i], s);
        dp[(size_t)o * NPIX] = f2bf(s);
    }
}

// ---------------------------------------------------------------------------
// FUSED attention: one block per (b,h), 4 waves. (b up to 31 when batched.)
// ---------------------------------------------------------------------------
__global__ __launch_bounds__(256)
void attn_fused(const unsigned short* __restrict__ qkv,
                const unsigned short* __restrict__ dpw,
                unsigned short* __restrict__ att)
{
    __shared__ float kvred[4][33 * 33];
    __shared__ float kvs[1056];
    __shared__ float dlds[4][256];
    __shared__ unsigned short T[4][256 * 40];

    const int t    = threadIdx.x;
    const int lane = t & 63;
    const int w    = t >> 6;
    const int bh   = blockIdx.x;
    const int b    = bh >> 4;
    const int h    = bh & 15;

    const unsigned short* base = (h < 8)
        ? qkv + ((size_t)(b * 768 + h * 96)) * NPIX
        : dpw + ((size_t)(b * 768 + (h - 8) * 96)) * NPIX;
    const unsigned short* qp = base;
    const unsigned short* kp = base + 32 * NPIX;
    const unsigned short* vp = base + 64 * NPIX;

    const int l16 = lane & 15;
    const int lq  = lane >> 4;
    const int ko  = lq * 8;
    const int nb  = w * 256;

    // phase 1: kv partials
    {
        f32x4 acc[3][2];
#pragma unroll
        for (int i = 0; i < 3; i++)
#pragma unroll
            for (int j = 0; j < 2; j++) {
                f32x4 z = {0.f, 0.f, 0.f, 0.f};
                acc[i][j] = z;
            }
        bf16x8 ones;
#pragma unroll
        for (int j = 0; j < 8; j++) ones[j] = (l16 == 0) ? (short)0x3F80 : (short)0;

#pragma unroll
        for (int s = 0; s < 8; s++) {
            const int n0 = nb + s * 32 + ko;
            const bf16x8 av0 = *(const bf16x8*)(vp + (size_t)l16 * NPIX + n0);
            const bf16x8 av1 = *(const bf16x8*)(vp + (size_t)(16 + l16) * NPIX + n0);
            const u16x8 k0 = *(const u16x8*)(kp + (size_t)l16 * NPIX + n0);
            const u16x8 k1 = *(const u16x8*)(kp + (size_t)(16 + l16) * NPIX + n0);
            bf16x8 bk0, bk1;
#pragma unroll
            for (int j = 0; j < 8; j++) {
                bk0[j] = (k0[j] & 0x8000u) ? (short)0 : (short)k0[j];
                bk1[j] = (k1[j] & 0x8000u) ? (short)0 : (short)k1[j];
            }
            acc[0][0] = __builtin_amdgcn_mfma_f32_16x16x32_bf16(av0,  bk0, acc[0][0], 0, 0, 0);
            acc[0][1] = __builtin_amdgcn_mfma_f32_16x16x32_bf16(av0,  bk1, acc[0][1], 0, 0, 0);
            acc[1][0] = __builtin_amdgcn_mfma_f32_16x16x32_bf16(av1,  bk0, acc[1][0], 0, 0, 0);
            acc[1][1] = __builtin_amdgcn_mfma_f32_16x16x32_bf16(av1,  bk1, acc[1][1], 0, 0, 0);
            acc[2][0] = __builtin_amdgcn_mfma_f32_16x16x32_bf16(ones, bk0, acc[2][0], 0, 0, 0);
            acc[2][1] = __builtin_amdgcn_mfma_f32_16x16x32_bf16(ones, bk1, acc[2][1], 0, 0, 0);
        }
        const int rbase = lq * 4;
#pragma unroll
        for (int dt = 0; dt < 2; dt++)
#pragma unroll
            for (int et = 0; et < 2; et++)
#pragma unroll
                for (int r = 0; r < 4; r++)
                    kvred[w][(dt * 16 + rbase + r) * 33 + et * 16 + l16] = acc[dt][et][r];
        if (rbase == 0) {
#pragma unroll
            for (int et = 0; et < 2; et++)
                kvred[w][32 * 33 + et * 16 + l16] = acc[2][et][0];
        }
    }
    __syncthreads();
#pragma unroll
    for (int k = 0; k < 5; k++) {
        const int idx = t + k * 256;
        if (idx < 1056) {
            const int a = (idx >> 5) * 33 + (idx & 31);
            kvs[idx] = kvred[0][a] + kvred[1][a] + kvred[2][a] + kvred[3][a];
        }
    }
    __syncthreads();

    // phase 2: out = kv · relu(Q), K=32
    bf16x8 a0, a1, a2;
#pragma unroll
    for (int j = 0; j < 8; j++) {
        a0[j] = (short)f2bf(kvs[l16 * 32 + ko + j]);
        a1[j] = (short)f2bf(kvs[(16 + l16) * 32 + ko + j]);
        a2[j] = (l16 == 0) ? (short)f2bf(kvs[32 * 32 + ko + j]) : (short)0;
    }
    bf16x8 bfr[16];
    const unsigned short* qb = qp + (size_t)ko * NPIX + nb + l16;
#pragma unroll
    for (int tl = 0; tl < 16; tl++) {
        bf16x8 bf;
#pragma unroll
        for (int j = 0; j < 8; j++) {
            const unsigned short v = qb[(size_t)j * NPIX + tl * 16];
            bf[j] = (v & 0x8000u) ? (short)0 : (short)v;
        }
        bfr[tl] = bf;
    }
#pragma unroll
    for (int tl = 0; tl < 16; tl++) {
        f32x4 z = {0.f, 0.f, 0.f, 0.f};
        z = __builtin_amdgcn_mfma_f32_16x16x32_bf16(a2, bfr[tl], z, 0, 0, 0);
        if (lq == 0) dlds[w][tl * 16 + l16] = z[0];
    }
    __syncthreads();
#pragma unroll
    for (int tl = 0; tl < 16; tl++) {
        f32x4 c0 = {0.f, 0.f, 0.f, 0.f};
        f32x4 c1 = {0.f, 0.f, 0.f, 0.f};
        c0 = __builtin_amdgcn_mfma_f32_16x16x32_bf16(a0, bfr[tl], c0, 0, 0, 0);
        c1 = __builtin_amdgcn_mfma_f32_16x16x32_bf16(a1, bfr[tl], c1, 0, 0, 0);
        const float inv = 1.f / (dlds[w][tl * 16 + l16] + 1e-15f);
        u16x4 p0, p1;
#pragma unroll
        for (int r = 0; r < 4; r++) {
            p0[r] = f2bf(c0[r] * inv);
            p1[r] = f2bf(c1[r] * inv);
        }
        unsigned short* tp = &T[w][(tl * 16 + l16) * 40];
        *(u16x4*)(tp + lq * 4)      = p0;
        *(u16x4*)(tp + 16 + lq * 4) = p1;
    }
    __syncthreads();
#pragma unroll
    for (int k = 0; k < 16; k++) {
        const int idx = k * 64 + lane;
        const int db  = idx >> 8;
        const int px  = idx & 255;
        const u16x8 v = *(const u16x8*)(&T[w][px * 40 + db * 8]);
        *(u16x8*)(att + (((size_t)(b * 64 + h * 4 + db)) * NPIX + nb + px) * 8) = v;
    }
}

// ---------------------------------------------------------------------------
extern "C" void kernel_launch(void* const* d_in, const int* in_sizes, int n_in,
                              void* d_out, int out_size, void* d_ws, size_t ws_size,
                              hipStream_t stream)
{
    (void)in_sizes; (void)n_in; (void)out_size;

    const float* x      = (const float*)d_in[0];
    const float* y      = (const float*)d_in[1];
    const float* qkv_w  = (const float*)d_in[2];
    const float* dw5_w  = (const float*)d_in[3];
    const float* pwg_w  = (const float*)d_in[4];
    const float* proj_w = (const float*)d_in[5];
    const float* proj_g = (const float*)d_in[6];
    const float* proj_b = (const float*)d_in[7];
    const float* proj_m = (const float*)d_in[8];
    const float* proj_v = (const float*)d_in[9];
    const float* inv_w  = (const float*)d_in[10];
    const float* inv_b  = (const float*)d_in[11];
    const float* dwc_w  = (const float*)d_in[12];
    const float* dwc_b  = (const float*)d_in[13];
    const float* pw_w   = (const float*)d_in[14];
    const float* pw_g   = (const float*)d_in[15];
    const float* pw_b   = (const float*)d_in[16];
    const float* pw_m   = (const float*)d_in[17];
    const float* pw_v   = (const float*)d_in[18];

    float* ws = (float*)d_ws;
    unsigned short* wqkv_b  = (unsigned short*)(ws + WQKV_OFF);
    unsigned short* wproj_b = (unsigned short*)(ws + WPROJ_OFF);
    unsigned short* winv_b  = (unsigned short*)(ws + WINV_OFF);
    unsigned short* wpw_b   = (unsigned short*)(ws + WPW_OFF);
    float* out = (float*)d_out;

    wconv_all<<<dim3(416), 256, 0, stream>>>(qkv_w, proj_w, inv_w, pw_w,
                                             wqkv_b, wproj_b, winv_b, wpw_b);

    if (ws_size >= (size_t)BATCH_NEED_F * 4ull) {
        // ---------------- batched path: both chains as images 0..31 ----------
        unsigned short* bxt  = (unsigned short*)(ws + BXT_OFF);
        unsigned short* bqkv = (unsigned short*)(ws + BQKV_OFF);
        unsigned short* bdpw = (unsigned short*)(ws + BDPW_OFF);
        unsigned short* batt = (unsigned short*)(ws + BATT_OFF);
        unsigned short* bt1t = (unsigned short*)(ws + BT1T_OFF);
        unsigned short* bh1t = (unsigned short*)(ws + BH1T_OFF);
        unsigned short* bh2t = (unsigned short*)(ws + BH2T_OFF);

        xpose2<<<dim3(4096), 256, 0, stream>>>(x, y, bxt, 256);
        gemm_direct<128, 128, 0, false, 1><<<dim3(6, 256), 256, 0, stream>>>(
            bxt, nullptr, wqkv_b, nullptr, bqkv, 768, 256,
            nullptr, nullptr, nullptr, nullptr, nullptr, nullptr, nullptr, nullptr);
        dwconv5x5_v3<<<dim3(12288), 256, 0, stream>>>(bqkv, dw5_w, bdpw);
        grouped_pw<<<dim3(3072), 256, 0, stream>>>(bdpw, pwg_w);
        attn_fused<<<dim3(512), 256, 0, stream>>>(bqkv, bdpw, batt);
        gemm_direct<64, 64, 1, false, 2><<<dim3(4, 512), 256, 0, stream>>>(
            batt, nullptr, wproj_b, nullptr, bt1t, 256, 512,
            x, y, nullptr, proj_g, proj_b, proj_m, proj_v, nullptr);
        gemm_direct<128, 128, 2, false, 2><<<dim3(8, 256), 256, 0, stream>>>(
            bt1t, nullptr, winv_b, nullptr, bh1t, 1024, 256,
            nullptr, nullptr, nullptr, nullptr, nullptr, nullptr, nullptr, inv_b);
        dwconv3x3_dg<<<dim3(4096), 256, 0, stream>>>(bh1t, dwc_w, dwc_b, bh2t);
        gemm_direct<64, 64, 3, false, 0><<<dim3(4, 256), 256, 0, stream>>>(
            bh2t, bh2t + (size_t)16 * 1024 * 1024, wpw_b, out, nullptr, 256, 1024,
            nullptr, nullptr, bt1t, pw_g, pw_b, pw_m, pw_v, nullptr);
    } else {
        // ---------------- fallback: per-chain (R14 structure) ----------------
        unsigned short* wxt  = (unsigned short*)(ws + XT_OFF);
        unsigned short* wqkv = (unsigned short*)(ws + QKV_OFF);
        unsigned short* wdpw = (unsigned short*)(ws + DPW_OFF);
        unsigned short* watt = (unsigned short*)(ws + ATT_OFF);
        float*          wt1  = ws + T1_OFF;
        unsigned short* wt1t = (unsigned short*)(ws + T1T_OFF);
        unsigned short* wh1t = (unsigned short*)(ws + H1T_OFF);
        unsigned short* wh2t = (unsigned short*)(ws + H2T_OFF);

        for (int blk = 0; blk < 2; blk++) {
            const float* t = (blk == 0) ? x : y;
            xpose2<<<dim3(2048), 256, 0, stream>>>(t, t, wxt, 256);
            gemm_direct<128, 128, 0, false, 1><<<dim3(6, 128), 256, 0, stream>>>(
                wxt, nullptr, wqkv_b, nullptr, wqkv, 768, 256,
                nullptr, nullptr, nullptr, nullptr, nullptr, nullptr, nullptr, nullptr);
            dwconv5x5_v3<<<dim3(6144), 256, 0, stream>>>(wqkv, dw5_w, wdpw);
            grouped_pw<<<dim3(1536), 256, 0, stream>>>(wdpw, pwg_w);
            attn_fused<<<dim3(256), 256, 0, stream>>>(wqkv, wdpw, watt);
            gemm_direct<64, 64, 1, false, 3><<<dim3(4, 256), 256, 0, stream>>>(
                watt, watt, wproj_b, wt1, wt1t, 256, 512,
                t, t, nullptr, proj_g, proj_b, proj_m, proj_v, nullptr);
            gemm_direct<128, 128, 2, false, 2><<<dim3(8, 128), 256, 0, stream>>>(
                wt1t, nullptr, winv_b, nullptr, wh1t, 1024, 256,
                nullptr, nullptr, nullptr, nullptr, nullptr, nullptr, nullptr, inv_b);
            dwconv3x3_dg<<<dim3(2048), 256, 0, stream>>>(wh1t, dwc_w, dwc_b, wh2t);
            if (blk == 0) {
                gemm_direct<64, 64, 1, false, 0><<<dim3(4, 256), 256, 0, stream>>>(
                    wh2t, nullptr, wpw_b, out, nullptr, 256, 1024,
                    wt1, wt1, nullptr, pw_g, pw_b, pw_m, pw_v, nullptr);
            } else {
                gemm_direct<64, 64, 1, true, 0><<<dim3(4, 256), 256, 0, stream>>>(
                    wh2t, nullptr, wpw_b, out, nullptr, 256, 1024,
                    wt1, wt1, nullptr, pw_g, pw_b, pw_m, pw_v, nullptr);
            }
        }
    }
}

// Round 18
// 256.089 us; speedup vs baseline: 1.0398x; 1.0398x over previous
//
#include <hip/hip_runtime.h>
#include <cstddef>

#define NPIX 1024   // H*W = 32*32

// ---------------------------------------------------------------------------
// Workspace layouts (float-slot offsets).
// BATCHED (both residual chains as images 0..31): peak 38,174,720 floats.
// FALLBACK (per-chain, R14 layout): peak 34,045,952 floats.
// ---------------------------------------------------------------------------
static constexpr size_t WQKV_OFF  = 0;
static constexpr size_t WPROJ_OFF = 98304;
static constexpr size_t WINV_OFF  = 163840;
static constexpr size_t WPW_OFF   = 294912;
// batched
static constexpr size_t BXT_OFF   = 425984;
static constexpr size_t BQKV_OFF  = 4620288;
static constexpr size_t BDPW_OFF  = 17203200;
static constexpr size_t BATT_OFF  = 29786112;
static constexpr size_t BT1T_OFF  = 425984;     // alias XT32
static constexpr size_t BH1T_OFF  = 4620288;    // alias QKV32..
static constexpr size_t BH2T_OFF  = 21397504;   // alias DPW-tail+ATT
static constexpr size_t BATCH_NEED_F = 38174720;
// fallback (R14)
static constexpr size_t XT_OFF    = 425984;
static constexpr size_t QKV_OFF   = 2523136;
static constexpr size_t DPW_OFF   = 8814592;
static constexpr size_t ATT_OFF   = 15106048;
static constexpr size_t T1_OFF    = 21463040;
static constexpr size_t T1T_OFF   = 25657344;
static constexpr size_t H1T_OFF   = 425984;
static constexpr size_t H2T_OFF   = 25657344;

typedef __attribute__((ext_vector_type(8))) short bf16x8;
typedef __attribute__((ext_vector_type(8))) unsigned short u16x8;
typedef __attribute__((ext_vector_type(4))) unsigned short u16x4;
typedef __attribute__((ext_vector_type(4))) float f32x4;

__device__ inline unsigned short f2bf(float f) {
    union { float f; unsigned int u; } v; v.f = f;
    unsigned int u = v.u;
    u += 0x7FFFu + ((u >> 16) & 1u);        // round-to-nearest-even
    return (unsigned short)(u >> 16);
}
__device__ inline float bf2f(unsigned short u) {
    union { float f; unsigned int u; } v; v.u = ((unsigned int)u) << 16;
    return v.f;
}
__device__ inline u16x8 zero8() {
    u16x8 z = {0, 0, 0, 0, 0, 0, 0, 0};
    return z;
}

// ---------------------------------------------------------------------------
// Weight convert (all 4 weights in ONE launch): fp32 [O][K] -> bf16 [K/8][O][8]
// ---------------------------------------------------------------------------
__global__ __launch_bounds__(256)
void wconv_all(const float* __restrict__ w0, const float* __restrict__ w1,
               const float* __restrict__ w2, const float* __restrict__ w3,
               unsigned short* __restrict__ d0, unsigned short* __restrict__ d1,
               unsigned short* __restrict__ d2, unsigned short* __restrict__ d3)
{
    const int bid = blockIdx.x;
    const float* W; unsigned short* WB; int O, K, base;
    if (bid < 96)       { W = w0; WB = d0; O = 768;  K = 256;  base = 0;   }
    else if (bid < 160) { W = w1; WB = d1; O = 256;  K = 512;  base = 96;  }
    else if (bid < 288) { W = w2; WB = d2; O = 1024; K = 256;  base = 160; }
    else                { W = w3; WB = d3; O = 256;  K = 1024; base = 288; }
    const int idx = (bid - base) * 256 + threadIdx.x;
    if (idx >= O * (K >> 3)) return;
    const int o = idx % O;
    const int koct = idx / O;
    u16x8 v;
#pragma unroll
    for (int j = 0; j < 8; j++) v[j] = f2bf(W[(size_t)o * K + koct * 8 + j]);
    *(u16x8*)(WB + ((size_t)koct * O + o) * 8) = v;
}

// ---------------------------------------------------------------------------
// Transpose, dual-source: image ib<16 from X0, else X1.
// ---------------------------------------------------------------------------
__global__ __launch_bounds__(256)
void xpose2(const float* __restrict__ X0, const float* __restrict__ X1,
            unsigned short* __restrict__ XT, const int C)
{
    __shared__ float tt[8][260];
    const int t = threadIdx.x;
    const int octs = C >> 3;
    const int strips = octs * 4;
    const int ib = blockIdx.x / strips;
    const int rem = blockIdx.x - ib * strips;
    const int coct = rem >> 2;
    const int n0 = (rem & 3) * 256;
    const float* src = (ib < 16) ? X0 + (size_t)ib * C * NPIX
                                 : X1 + (size_t)(ib - 16) * C * NPIX;
    const int cc = t >> 5;
    const int c8 = (t & 31) * 8;
    const float* xp = src + ((size_t)(coct * 8 + cc)) * NPIX + n0 + c8;
    *(float4*)(&tt[cc][c8])     = *(const float4*)(xp);
    *(float4*)(&tt[cc][c8 + 4]) = *(const float4*)(xp + 4);
    __syncthreads();
    u16x8 v;
#pragma unroll
    for (int j = 0; j < 8; j++) v[j] = f2bf(tt[j][t]);
    *(u16x8*)(XT + (((size_t)ib * octs + coct) * NPIX + n0 + t) * 8) = v;
}

// ---------------------------------------------------------------------------
// MFMA GEMM, DIRECT global->VGPR fragments (no LDS staging, no main-loop
// barriers). Operands blocked bf16 [K/8][rows][8].
// EPI: 0 plain; 1 BN + fp32 residual (res if b<16 else res2, image b&15);
//      2 bias+hswish; 3 DUAL: INTERLEAVED second K-stream X2 into acc2,
//      then v = scale*(acc+acc2) + 2*shift + bf16blk res (b) + res (b+16).
// OMODE: 0 fp32 [c][n] (+ACC); 1 bf16 [c][n]; 2 blocked bf16; 3 fp32+blocked.
// ---------------------------------------------------------------------------
template<int BM, int BN, int EPI, bool ACC, int OMODE>
__global__ __launch_bounds__(256)
void gemm_direct(const unsigned short* __restrict__ X, const unsigned short* __restrict__ X2,
                 const unsigned short* __restrict__ W,
                 float* __restrict__ Y, unsigned short* __restrict__ YB,
                 const int O, const int K,
                 const float* __restrict__ res, const float* __restrict__ res2,
                 const unsigned short* __restrict__ resb,
                 const float* __restrict__ bng, const float* __restrict__ bnb,
                 const float* __restrict__ bnm, const float* __restrict__ bnv,
                 const float* __restrict__ bias)
{
    constexpr int TN = NPIX / BN;
    constexpr int WAVES_N = (BN >= 128) ? 2 : 1;
    constexpr int WM = BM / (4 / WAVES_N);
    constexpr int MI = WM / 16;
    constexpr int NJ = 4;
    constexpr int TSTR = (OMODE == 1) ? (BN + 8) : (BM + 8);
    constexpr int TSZ  = (OMODE == 1) ? BM * TSTR : ((OMODE >= 2) ? BN * TSTR : 64);
    __shared__ unsigned short T[TSZ];

    const int t    = threadIdx.x;
    const int lane = t & 63;
    const int w    = t >> 6;

    // XCD-bijective block swizzle (all grids are multiples of 8)
    const int gx  = gridDim.x;
    const int nwg = gx * gridDim.y;
    int bid = blockIdx.y * gx + blockIdx.x;
    bid = (bid & 7) * (nwg >> 3) + (bid >> 3);
    const int bx = bid % gx;
    const int by = bid / gx;

    const int o0 = bx * BM;
    const int b  = by / TN;
    const int n0 = (by % TN) * BN;

    const int wn = (WAVES_N == 2) ? (w & 1) * 64 : 0;
    const int wo = (WAVES_N == 2) ? (w >> 1) * WM : w * WM;

    const int l16 = lane & 15;
    const int lq  = lane >> 4;

    f32x4 acc[MI][NJ];
    f32x4 acc2[MI][NJ];
#pragma unroll
    for (int i = 0; i < MI; i++)
#pragma unroll
        for (int j = 0; j < NJ; j++) {
            f32x4 z = {0.f, 0.f, 0.f, 0.f};
            acc[i][j] = z;
            acc2[i][j] = z;
        }

    const unsigned short* Ab = W + ((size_t)lq * O + o0 + wo + l16) * 8;
    const size_t strideA = (size_t)O * 8;
    const size_t strideB = (size_t)NPIX * 8;
    const size_t boff = ((size_t)lq * NPIX + n0 + wn + l16) * 8;
    const int octs = K >> 3;                    // multiple of 8

    auto ldA_ = [&](bf16x8* fr, int kb) {
#pragma unroll
        for (int i = 0; i < MI; i++)
            fr[i] = *(const bf16x8*)(Ab + (size_t)kb * strideA + i * 128);
    };
    auto ldB_ = [&](bf16x8* fr, const unsigned short* Bb, int kb) {
#pragma unroll
        for (int j = 0; j < NJ; j++)
            fr[j] = *(const bf16x8*)(Bb + (size_t)kb * strideB + j * 128);
    };
    auto domfma_ = [&](f32x4 (&ac)[MI][NJ], bf16x8* af, bf16x8* bf) {
#pragma unroll
        for (int i = 0; i < MI; i++)
#pragma unroll
            for (int j = 0; j < NJ; j++)
                ac[i][j] = __builtin_amdgcn_mfma_f32_16x16x32_bf16(
                    af[i], bf[j], ac[i][j], 0, 0, 0);
    };

    if (EPI != 3) {
        const unsigned short* Bb = X + (size_t)b * K * NPIX + boff;
        bf16x8 aA[MI], bA[NJ], aB[MI], bB[NJ];
        ldA_(aA, 0); ldB_(bA, Bb, 0);
        for (int kb = 0; kb < octs; kb += 8) {
            ldA_(aB, kb + 4); ldB_(bB, Bb, kb + 4);
            domfma_(acc, aA, bA);
            if (kb + 8 < octs) { ldA_(aA, kb + 8); ldB_(bA, Bb, kb + 8); }
            domfma_(acc, aB, bB);
        }
    } else {
        // interleaved dual stream, shared A
        const unsigned short* B1 = X  + (size_t)b * K * NPIX + boff;
        const unsigned short* B2 = X2 + (size_t)b * K * NPIX + boff;
        bf16x8 aA[MI], aB[MI], b1A[NJ], b1B[NJ], b2A[NJ], b2B[NJ];
        ldA_(aA, 0); ldB_(b1A, B1, 0); ldB_(b2A, B2, 0);
        for (int kb = 0; kb < octs; kb += 8) {
            ldA_(aB, kb + 4);
            ldB_(b1B, B1, kb + 4); ldB_(b2B, B2, kb + 4);
            domfma_(acc,  aA, b1A);
            domfma_(acc2, aA, b2A);
            if (kb + 8 < octs) {
                ldA_(aA, kb + 8);
                ldB_(b1A, B1, kb + 8); ldB_(b2A, B2, kb + 8);
            }
            domfma_(acc,  aB, b1B);
            domfma_(acc2, aB, b2B);
        }
    }

    // epilogue. C/D: col = lane&15 (n), row = (lane>>4)*4 + reg (o)
    const int r0q = lq * 4;
    float scale[MI][4], shift[MI][4];
    if (EPI == 1 || EPI == 3) {
#pragma unroll
        for (int i = 0; i < MI; i++)
#pragma unroll
            for (int r = 0; r < 4; r++) {
                const int o = o0 + wo + i * 16 + r0q + r;
                const float inv = bng[o] / sqrtf(bnv[o] + 1e-5f);
                scale[i][r] = inv;
                shift[i][r] = bnb[o] - bnm[o] * inv;
            }
    } else if (EPI == 2) {
#pragma unroll
        for (int i = 0; i < MI; i++)
#pragma unroll
            for (int r = 0; r < 4; r++)
                shift[i][r] = bias[o0 + wo + i * 16 + r0q + r];
    }

#pragma unroll
    for (int i = 0; i < MI; i++) {
#pragma unroll
        for (int j = 0; j < NJ; j++) {
            const int nn = n0 + wn + j * 16 + l16;
            const int nl = wn + j * 16 + l16;
            const int ob = wo + i * 16 + r0q;
            const size_t base = ((size_t)b * O + o0 + ob) * NPIX + nn;
            u16x4 r1v, r2v;
            if (EPI == 3) {
                const size_t ro = (((size_t)(b * 32 + ((o0 + ob) >> 3)) * NPIX + nn) * 8
                                   + ((o0 + ob) & 7));
                r1v = *(const u16x4*)(resb + ro);
                r2v = *(const u16x4*)(resb + (size_t)16 * 262144 + ro);
            }
            u16x4 p4;
#pragma unroll
            for (int r = 0; r < 4; r++) {
                const size_t off = base + (size_t)r * NPIX;
                float v = acc[i][j][r];
                if (EPI == 1) {
                    const float* rs = (b < 16) ? res : res2;
                    const size_t roff = ((size_t)(b & 15) * O + o0 + ob + r) * NPIX + nn;
                    v = v * scale[i][r] + shift[i][r] + rs[roff];
                } else if (EPI == 2) {
                    v += shift[i][r];
                    v = v * fminf(fmaxf(v + 3.f, 0.f), 6.f) * (1.f / 6.f);
                } else if (EPI == 3) {
                    v = (v + acc2[i][j][r]) * scale[i][r] + 2.f * shift[i][r]
                        + bf2f(r1v[r]) + bf2f(r2v[r]);
                }
                if (OMODE == 0 || OMODE == 3) {
                    if (ACC) v += Y[off];
                    Y[off] = v;
                }
                if (OMODE == 1) {
                    T[(size_t)(ob + r) * TSTR + nl] = f2bf(v);
                } else if (OMODE >= 2) {
                    p4[r] = f2bf(v);
                }
            }
            if (OMODE >= 2)
                *(u16x4*)(T + (size_t)nl * TSTR + ob) = p4;
        }
    }

    if (OMODE >= 1) {
        __syncthreads();
        constexpr int CNT = BM * BN / 2048;
        if (OMODE == 1) {
#pragma unroll
            for (int k = 0; k < CNT; k++) {
                const int idx = t + k * 256;
                const int o   = idx / (BN / 8);
                const int n8  = (idx % (BN / 8)) * 8;
                const u16x8 v = *(const u16x8*)(T + (size_t)o * TSTR + n8);
                *(u16x8*)(YB + ((size_t)b * O + o0 + o) * NPIX + n0 + n8) = v;
            }
        } else {
#pragma unroll
            for (int k = 0; k < CNT; k++) {
                const int idx = t + k * 256;
                const int oo  = idx / BN;
                const int nn  = idx % BN;
                const u16x8 v = *(const u16x8*)(T + (size_t)nn * TSTR + oo * 8);
                *(u16x8*)(YB + (((size_t)b * (O >> 3) + (o0 >> 3) + oo) * NPIX + n0 + nn) * 8) = v;
            }
        }
    }
}

// ---------------------------------------------------------------------------
// Depthwise 5x5 SAME, bf16 [c][n] in/out. 2 channels/block, stride-44 fp32 LDS.
// ---------------------------------------------------------------------------
__global__ __launch_bounds__(256)
void dwconv5x5_v3(const unsigned short* __restrict__ X, const float* __restrict__ Wd,
                  unsigned short* __restrict__ Y)
{
    __shared__ float tile[2 * 36 * 44];
    __shared__ float wl[64];
    const int t     = threadIdx.x;
    const int cpair = blockIdx.x % 384;
    const int b     = blockIdx.x / 384;
    const int cbase = cpair * 2;
    const unsigned short* xp = X + ((size_t)b * 768 + cbase) * NPIX;

#pragma unroll
    for (int k = 0; k < 4; k++) {
        const int i = t + k * 256;
        if (i < 792) {
            f32x4 z = {0.f, 0.f, 0.f, 0.f};
            *(f32x4*)(&tile[i * 4]) = z;
        }
    }
    if (t < 50) wl[(t / 25) * 32 + (t % 25)] = Wd[cbase * 25 + t];
    __syncthreads();

    const int ch = t >> 7;
    const int tm = t & 127;
    const int r  = tm >> 2;
    const int c8 = (tm & 3) * 8;

    {
        const u16x8 v = *(const u16x8*)(xp + (size_t)ch * NPIX + r * 32 + c8);
        float* wp = &tile[ch * 1584 + (r + 2) * 44 + c8 + 2];
#pragma unroll
        for (int j = 0; j < 8; j += 2) {
            float2 f2v = make_float2(bf2f(v[j]), bf2f(v[j + 1]));
            *(float2*)(wp + j) = f2v;
        }
    }
    float wk[25];
#pragma unroll
    for (int i = 0; i < 25; i++) wk[i] = wl[ch * 32 + i];
    __syncthreads();

    float acc[8];
#pragma unroll
    for (int j = 0; j < 8; j++) acc[j] = 0.f;

#pragma unroll
    for (int ky = 0; ky < 5; ky++) {
        const float* rp = &tile[ch * 1584 + (r + ky) * 44 + c8];
        const f32x4 a = *(const f32x4*)(rp);
        const f32x4 bq = *(const f32x4*)(rp + 4);
        const f32x4 cq = *(const f32x4*)(rp + 8);
        const float in[12] = {a[0], a[1], a[2], a[3], bq[0], bq[1], bq[2], bq[3],
                              cq[0], cq[1], cq[2], cq[3]};
#pragma unroll
        for (int kx = 0; kx < 5; kx++) {
            const float wv = wk[ky * 5 + kx];
#pragma unroll
            for (int j = 0; j < 8; j++)
                acc[j] = fmaf(in[j + kx], wv, acc[j]);
        }
    }

    u16x8 o8;
#pragma unroll
    for (int j = 0; j < 8; j++) o8[j] = f2bf(acc[j]);
    *(u16x8*)(Y + ((size_t)b * 768 + cbase + ch) * NPIX + r * 32 + c8) = o8;
}

// ---------------------------------------------------------------------------
// Depthwise 3x3 + bias + hswish, blocked bf16 in/out — 2 px x 8 ch per thread
// (halved per-thread state vs R16/R17: acc[8][2]=16 regs, window P[4]=16 regs)
// -> lower VGPR -> ~2x occupancy for latency hiding. Direct global reads,
// no pixel LDS, no bulk barrier. Grid: 32 images x 128 octs x 2 halves.
// ---------------------------------------------------------------------------
__global__ __launch_bounds__(256)
void dwconv3x3_h2(const unsigned short* __restrict__ X, const float* __restrict__ Wd,
                  const float* __restrict__ bias, unsigned short* __restrict__ Y)
{
    __shared__ float wl[72];
    __shared__ float bb[8];
    const int t    = threadIdx.x;
    const int bid  = blockIdx.x;
    const int half = bid & 1;
    const int coct = (bid >> 1) & 127;
    const int b    = bid >> 8;
    const unsigned short* xp = X + ((size_t)(b * 128 + coct)) * NPIX * 8;
    if (t < 72) wl[t] = Wd[coct * 72 + t];
    if (t < 8)  bb[t] = bias[coct * 8 + t];
    __syncthreads();

    const int px0 = half * 512 + t * 2;   // 2 consecutive pixels
    const int hr  = px0 >> 5;             // image row
    const int c0  = px0 & 31;             // image col (even)

    float acc[8][2];
#pragma unroll
    for (int ch = 0; ch < 8; ch++) {
        acc[ch][0] = bb[ch];
        acc[ch][1] = bb[ch];
    }

#pragma unroll
    for (int ky = 0; ky < 3; ky++) {
        const int rr = hr + ky - 1;
        if (rr >= 0 && rr < 32) {
            u16x8 P[4];
#pragma unroll
            for (int m = 0; m < 4; m++) {
                const int col = c0 - 1 + m;
                const int colc = col < 0 ? 0 : (col > 31 ? 31 : col);
                u16x8 v = *(const u16x8*)(xp + (size_t)(rr * 32 + colc) * 8);
                if (col < 0 || col > 31) v = zero8();
                P[m] = v;
            }
#pragma unroll
            for (int ch = 0; ch < 8; ch++) {
                float g[4];
#pragma unroll
                for (int m = 0; m < 4; m++) g[m] = bf2f(P[m][ch]);
#pragma unroll
                for (int j = 0; j < 2; j++)
#pragma unroll
                    for (int kx = 0; kx < 3; kx++)
                        acc[ch][j] = fmaf(g[j + kx], wl[ch * 9 + ky * 3 + kx], acc[ch][j]);
            }
        }
    }
    unsigned short* yp = Y + ((size_t)(b * 128 + coct)) * NPIX * 8 + (size_t)px0 * 8;
#pragma unroll
    for (int j = 0; j < 2; j++) {
        u16x8 o8;
#pragma unroll
        for (int ch = 0; ch < 8; ch++) {
            float v = acc[ch][j];
            v = v * fminf(fmaxf(v + 3.f, 0.f), 6.f) * (1.f / 6.f);
            o8[ch] = f2bf(v);
        }
        *(u16x8*)(yp + j * 8) = o8;
    }
}

// ---------------------------------------------------------------------------
// Grouped 32->32 1x1 (24 groups), in-place on bf16 [c][n] D.
// ---------------------------------------------------------------------------
__global__ __launch_bounds__(256)
void grouped_pw(unsigned short* __restrict__ D, const float* __restrict__ Wg)
{
    __shared__ float ws[1024];
    const int t     = threadIdx.x;
    const int blk   = blockIdx.x;
    const int chunk = blk & 3;
    const int bg    = blk >> 2;
    const int g     = bg % 24;
    const int b     = bg / 24;
    for (int i = t; i < 1024; i += 256) ws[i] = Wg[g * 1024 + i];
    __syncthreads();
    const int px = chunk * 256 + t;
    unsigned short* dp = D + ((size_t)(b * 768 + g * 32)) * NPIX + px;
    float in[32];
#pragma unroll
    for (int i = 0; i < 32; i++) in[i] = bf2f(dp[(size_t)i * NPIX]);
#pragma unroll
    for (int o = 0; o < 32; o++) {
        float s = 0.f;
#pragma unroll
        for (int i = 0; i < 32; i++) s = fmaf(ws[o * 32 + i], in[i], s);
        dp[(size_t)o * NPIX] = f2bf(s);
    }
}

// ---------------------------------------------------------------------------
// FUSED attention: one block per (b,h), 4 waves. (b up to 31 when batched.)
// ---------------------------------------------------------------------------
__global__ __launch_bounds__(256)
void attn_fused(const unsigned short* __restrict__ qkv,
                const unsigned short* __restrict__ dpw,
                unsigned short* __restrict__ att)
{
    __shared__ float kvred[4][33 * 33];
    __shared__ float kvs[1056];
    __shared__ float dlds[4][256];
    __shared__ unsigned short T[4][256 * 40];

    const int t    = threadIdx.x;
    const int lane = t & 63;
    const int w    = t >> 6;
    const int bh   = blockIdx.x;
    const int b    = bh >> 4;
    const int h    = bh & 15;

    const unsigned short* base = (h < 8)
        ? qkv + ((size_t)(b * 768 + h * 96)) * NPIX
        : dpw + ((size_t)(b * 768 + (h - 8) * 96)) * NPIX;
    const unsigned short* qp = base;
    const unsigned short* kp = base + 32 * NPIX;
    const unsigned short* vp = base + 64 * NPIX;

    const int l16 = lane & 15;
    const int lq  = lane >> 4;
    const int ko  = lq * 8;
    const int nb  = w * 256;

    // phase 1: kv partials
    {
        f32x4 acc[3][2];
#pragma unroll
        for (int i = 0; i < 3; i++)
#pragma unroll
            for (int j = 0; j < 2; j++) {
                f32x4 z = {0.f, 0.f, 0.f, 0.f};
                acc[i][j] = z;
            }
        bf16x8 ones;
#pragma unroll
        for (int j = 0; j < 8; j++) ones[j] = (l16 == 0) ? (short)0x3F80 : (short)0;

#pragma unroll
        for (int s = 0; s < 8; s++) {
            const int n0 = nb + s * 32 + ko;
            const bf16x8 av0 = *(const bf16x8*)(vp + (size_t)l16 * NPIX + n0);
            const bf16x8 av1 = *(const bf16x8*)(vp + (size_t)(16 + l16) * NPIX + n0);
            const u16x8 k0 = *(const u16x8*)(kp + (size_t)l16 * NPIX + n0);
            const u16x8 k1 = *(const u16x8*)(kp + (size_t)(16 + l16) * NPIX + n0);
            bf16x8 bk0, bk1;
#pragma unroll
            for (int j = 0; j < 8; j++) {
                bk0[j] = (k0[j] & 0x8000u) ? (short)0 : (short)k0[j];
                bk1[j] = (k1[j] & 0x8000u) ? (short)0 : (short)k1[j];
            }
            acc[0][0] = __builtin_amdgcn_mfma_f32_16x16x32_bf16(av0,  bk0, acc[0][0], 0, 0, 0);
            acc[0][1] = __builtin_amdgcn_mfma_f32_16x16x32_bf16(av0,  bk1, acc[0][1], 0, 0, 0);
            acc[1][0] = __builtin_amdgcn_mfma_f32_16x16x32_bf16(av1,  bk0, acc[1][0], 0, 0, 0);
            acc[1][1] = __builtin_amdgcn_mfma_f32_16x16x32_bf16(av1,  bk1, acc[1][1], 0, 0, 0);
            acc[2][0] = __builtin_amdgcn_mfma_f32_16x16x32_bf16(ones, bk0, acc[2][0], 0, 0, 0);
            acc[2][1] = __builtin_amdgcn_mfma_f32_16x16x32_bf16(ones, bk1, acc[2][1], 0, 0, 0);
        }
        const int rbase = lq * 4;
#pragma unroll
        for (int dt = 0; dt < 2; dt++)
#pragma unroll
            for (int et = 0; et < 2; et++)
#pragma unroll
                for (int r = 0; r < 4; r++)
                    kvred[w][(dt * 16 + rbase + r) * 33 + et * 16 + l16] = acc[dt][et][r];
        if (rbase == 0) {
#pragma unroll
            for (int et = 0; et < 2; et++)
                kvred[w][32 * 33 + et * 16 + l16] = acc[2][et][0];
        }
    }
    __syncthreads();
#pragma unroll
    for (int k = 0; k < 5; k++) {
        const int idx = t + k * 256;
        if (idx < 1056) {
            const int a = (idx >> 5) * 33 + (idx & 31);
            kvs[idx] = kvred[0][a] + kvred[1][a] + kvred[2][a] + kvred[3][a];
        }
    }
    __syncthreads();

    // phase 2: out = kv · relu(Q), K=32
    bf16x8 a0, a1, a2;
#pragma unroll
    for (int j = 0; j < 8; j++) {
        a0[j] = (short)f2bf(kvs[l16 * 32 + ko + j]);
        a1[j] = (short)f2bf(kvs[(16 + l16) * 32 + ko + j]);
        a2[j] = (l16 == 0) ? (short)f2bf(kvs[32 * 32 + ko + j]) : (short)0;
    }
    bf16x8 bfr[16];
    const unsigned short* qb = qp + (size_t)ko * NPIX + nb + l16;
#pragma unroll
    for (int tl = 0; tl < 16; tl++) {
        bf16x8 bf;
#pragma unroll
        for (int j = 0; j < 8; j++) {
            const unsigned short v = qb[(size_t)j * NPIX + tl * 16];
            bf[j] = (v & 0x8000u) ? (short)0 : (short)v;
        }
        bfr[tl] = bf;
    }
#pragma unroll
    for (int tl = 0; tl < 16; tl++) {
        f32x4 z = {0.f, 0.f, 0.f, 0.f};
        z = __builtin_amdgcn_mfma_f32_16x16x32_bf16(a2, bfr[tl], z, 0, 0, 0);
        if (lq == 0) dlds[w][tl * 16 + l16] = z[0];
    }
    __syncthreads();
#pragma unroll
    for (int tl = 0; tl < 16; tl++) {
        f32x4 c0 = {0.f, 0.f, 0.f, 0.f};
        f32x4 c1 = {0.f, 0.f, 0.f, 0.f};
        c0 = __builtin_amdgcn_mfma_f32_16x16x32_bf16(a0, bfr[tl], c0, 0, 0, 0);
        c1 = __builtin_amdgcn_mfma_f32_16x16x32_bf16(a1, bfr[tl], c1, 0, 0, 0);
        const float inv = 1.f / (dlds[w][tl * 16 + l16] + 1e-15f);
        u16x4 p0, p1;
#pragma unroll
        for (int r = 0; r < 4; r++) {
            p0[r] = f2bf(c0[r] * inv);
            p1[r] = f2bf(c1[r] * inv);
        }
        unsigned short* tp = &T[w][(tl * 16 + l16) * 40];
        *(u16x4*)(tp + lq * 4)      = p0;
        *(u16x4*)(tp + 16 + lq * 4) = p1;
    }
    __syncthreads();
#pragma unroll
    for (int k = 0; k < 16; k++) {
        const int idx = k * 64 + lane;
        const int db  = idx >> 8;
        const int px  = idx & 255;
        const u16x8 v = *(const u16x8*)(&T[w][px * 40 + db * 8]);
        *(u16x8*)(att + (((size_t)(b * 64 + h * 4 + db)) * NPIX + nb + px) * 8) = v;
    }
}

// ---------------------------------------------------------------------------
extern "C" void kernel_launch(void* const* d_in, const int* in_sizes, int n_in,
                              void* d_out, int out_size, void* d_ws, size_t ws_size,
                              hipStream_t stream)
{
    (void)in_sizes; (void)n_in; (void)out_size;

    const float* x      = (const float*)d_in[0];
    const float* y      = (const float*)d_in[1];
    const float* qkv_w  = (const float*)d_in[2];
    const float* dw5_w  = (const float*)d_in[3];
    const float* pwg_w  = (const float*)d_in[4];
    const float* proj_w = (const float*)d_in[5];
    const float* proj_g = (const float*)d_in[6];
    const float* proj_b = (const float*)d_in[7];
    const float* proj_m = (const float*)d_in[8];
    const float* proj_v = (const float*)d_in[9];
    const float* inv_w  = (const float*)d_in[10];
    const float* inv_b  = (const float*)d_in[11];
    const float* dwc_w  = (const float*)d_in[12];
    const float* dwc_b  = (const float*)d_in[13];
    const float* pw_w   = (const float*)d_in[14];
    const float* pw_g   = (const float*)d_in[15];
    const float* pw_b   = (const float*)d_in[16];
    const float* pw_m   = (const float*)d_in[17];
    const float* pw_v   = (const float*)d_in[18];

    float* ws = (float*)d_ws;
    unsigned short* wqkv_b  = (unsigned short*)(ws + WQKV_OFF);
    unsigned short* wproj_b = (unsigned short*)(ws + WPROJ_OFF);
    unsigned short* winv_b  = (unsigned short*)(ws + WINV_OFF);
    unsigned short* wpw_b   = (unsigned short*)(ws + WPW_OFF);
    float* out = (float*)d_out;

    wconv_all<<<dim3(416), 256, 0, stream>>>(qkv_w, proj_w, inv_w, pw_w,
                                             wqkv_b, wproj_b, winv_b, wpw_b);

    if (ws_size >= (size_t)BATCH_NEED_F * 4ull) {
        // ---------------- batched path: both chains as images 0..31 ----------
        unsigned short* bxt  = (unsigned short*)(ws + BXT_OFF);
        unsigned short* bqkv = (unsigned short*)(ws + BQKV_OFF);
        unsigned short* bdpw = (unsigned short*)(ws + BDPW_OFF);
        unsigned short* batt = (unsigned short*)(ws + BATT_OFF);
        unsigned short* bt1t = (unsigned short*)(ws + BT1T_OFF);
        unsigned short* bh1t = (unsigned short*)(ws + BH1T_OFF);
        unsigned short* bh2t = (unsigned short*)(ws + BH2T_OFF);

        xpose2<<<dim3(4096), 256, 0, stream>>>(x, y, bxt, 256);
        gemm_direct<128, 128, 0, false, 1><<<dim3(6, 256), 256, 0, stream>>>(
            bxt, nullptr, wqkv_b, nullptr, bqkv, 768, 256,
            nullptr, nullptr, nullptr, nullptr, nullptr, nullptr, nullptr, nullptr);
        dwconv5x5_v3<<<dim3(12288), 256, 0, stream>>>(bqkv, dw5_w, bdpw);
        grouped_pw<<<dim3(3072), 256, 0, stream>>>(bdpw, pwg_w);
        attn_fused<<<dim3(512), 256, 0, stream>>>(bqkv, bdpw, batt);
        gemm_direct<64, 64, 1, false, 2><<<dim3(4, 512), 256, 0, stream>>>(
            batt, nullptr, wproj_b, nullptr, bt1t, 256, 512,
            x, y, nullptr, proj_g, proj_b, proj_m, proj_v, nullptr);
        gemm_direct<128, 128, 2, false, 2><<<dim3(8, 256), 256, 0, stream>>>(
            bt1t, nullptr, winv_b, nullptr, bh1t, 1024, 256,
            nullptr, nullptr, nullptr, nullptr, nullptr, nullptr, nullptr, inv_b);
        dwconv3x3_h2<<<dim3(8192), 256, 0, stream>>>(bh1t, dwc_w, dwc_b, bh2t);
        gemm_direct<64, 64, 3, false, 0><<<dim3(4, 256), 256, 0, stream>>>(
            bh2t, bh2t + (size_t)16 * 1024 * 1024, wpw_b, out, nullptr, 256, 1024,
            nullptr, nullptr, bt1t, pw_g, pw_b, pw_m, pw_v, nullptr);
    } else {
        // ---------------- fallback: per-chain (R14 structure) ----------------
        unsigned short* wxt  = (unsigned short*)(ws + XT_OFF);
        unsigned short* wqkv = (unsigned short*)(ws + QKV_OFF);
        unsigned short* wdpw = (unsigned short*)(ws + DPW_OFF);
        unsigned short* watt = (unsigned short*)(ws + ATT_OFF);
        float*          wt1  = ws + T1_OFF;
        unsigned short* wt1t = (unsigned short*)(ws + T1T_OFF);
        unsigned short* wh1t = (unsigned short*)(ws + H1T_OFF);
        unsigned short* wh2t = (unsigned short*)(ws + H2T_OFF);

        for (int blk = 0; blk < 2; blk++) {
            const float* t = (blk == 0) ? x : y;
            xpose2<<<dim3(2048), 256, 0, stream>>>(t, t, wxt, 256);
            gemm_direct<128, 128, 0, false, 1><<<dim3(6, 128), 256, 0, stream>>>(
                wxt, nullptr, wqkv_b, nullptr, wqkv, 768, 256,
                nullptr, nullptr, nullptr, nullptr, nullptr, nullptr, nullptr, nullptr);
            dwconv5x5_v3<<<dim3(6144), 256, 0, stream>>>(wqkv, dw5_w, wdpw);
            grouped_pw<<<dim3(1536), 256, 0, stream>>>(wdpw, pwg_w);
            attn_fused<<<dim3(256), 256, 0, stream>>>(wqkv, wdpw, watt);
            gemm_direct<64, 64, 1, false, 3><<<dim3(4, 256), 256, 0, stream>>>(
                watt, watt, wproj_b, wt1, wt1t, 256, 512,
                t, t, nullptr, proj_g, proj_b, proj_m, proj_v, nullptr);
            gemm_direct<128, 128, 2, false, 2><<<dim3(8, 128), 256, 0, stream>>>(
                wt1t, nullptr, winv_b, nullptr, wh1t, 1024, 256,
                nullptr, nullptr, nullptr, nullptr, nullptr, nullptr, nullptr, inv_b);
            dwconv3x3_h2<<<dim3(4096), 256, 0, stream>>>(wh1t, dwc_w, dwc_b, wh2t);
            if (blk == 0) {
                gemm_direct<64, 64, 1, false, 0><<<dim3(4, 256), 256, 0, stream>>>(
                    wh2t, nullptr, wpw_b, out, nullptr, 256, 1024,
                    wt1, wt1, nullptr, pw_g, pw_b, pw_m, pw_v, nullptr);
            } else {
                gemm_direct<64, 64, 1, true, 0><<<dim3(4, 256), 256, 0, stream>>>(
                    wh2t, nullptr, wpw_b, out, nullptr, 256, 1024,
                    wt1, wt1, nullptr, pw_g, pw_b, pw_m, pw_v, nullptr);
            }
        }
    }
}

// Round 19
// 252.451 us; speedup vs baseline: 1.0548x; 1.0144x over previous
//
#include <hip/hip_runtime.h>
#include <cstddef>

#define NPIX 1024   // H*W = 32*32

// ---------------------------------------------------------------------------
// Workspace layouts (float-slot offsets).
// BATCHED (both residual chains as images 0..31): peak 38,174,720 floats.
// FALLBACK (per-chain, R14 layout): peak 34,045,952 floats.
// ---------------------------------------------------------------------------
static constexpr size_t WQKV_OFF  = 0;
static constexpr size_t WPROJ_OFF = 98304;
static constexpr size_t WINV_OFF  = 163840;
static constexpr size_t WPW_OFF   = 294912;
// batched
static constexpr size_t BXT_OFF   = 425984;
static constexpr size_t BQKV_OFF  = 4620288;
static constexpr size_t BDPW_OFF  = 17203200;
static constexpr size_t BATT_OFF  = 29786112;
static constexpr size_t BT1T_OFF  = 425984;     // alias XT32
static constexpr size_t BH1T_OFF  = 4620288;    // alias QKV32..
static constexpr size_t BH2T_OFF  = 21397504;   // alias DPW-tail+ATT
static constexpr size_t BATCH_NEED_F = 38174720;
// fallback (R14)
static constexpr size_t XT_OFF    = 425984;
static constexpr size_t QKV_OFF   = 2523136;
static constexpr size_t DPW_OFF   = 8814592;
static constexpr size_t ATT_OFF   = 15106048;
static constexpr size_t T1_OFF    = 21463040;
static constexpr size_t T1T_OFF   = 25657344;
static constexpr size_t H1T_OFF   = 425984;
static constexpr size_t H2T_OFF   = 25657344;

typedef __attribute__((ext_vector_type(8))) short bf16x8;
typedef __attribute__((ext_vector_type(8))) unsigned short u16x8;
typedef __attribute__((ext_vector_type(4))) unsigned short u16x4;
typedef __attribute__((ext_vector_type(4))) float f32x4;

__device__ inline unsigned short f2bf(float f) {
    union { float f; unsigned int u; } v; v.f = f;
    unsigned int u = v.u;
    u += 0x7FFFu + ((u >> 16) & 1u);        // round-to-nearest-even
    return (unsigned short)(u >> 16);
}
__device__ inline float bf2f(unsigned short u) {
    union { float f; unsigned int u; } v; v.u = ((unsigned int)u) << 16;
    return v.f;
}
__device__ inline u16x8 zero8() {
    u16x8 z = {0, 0, 0, 0, 0, 0, 0, 0};
    return z;
}

// ---------------------------------------------------------------------------
// Weight convert (all 4 weights in ONE launch): fp32 [O][K] -> bf16 [K/8][O][8]
// ---------------------------------------------------------------------------
__global__ __launch_bounds__(256)
void wconv_all(const float* __restrict__ w0, const float* __restrict__ w1,
               const float* __restrict__ w2, const float* __restrict__ w3,
               unsigned short* __restrict__ d0, unsigned short* __restrict__ d1,
               unsigned short* __restrict__ d2, unsigned short* __restrict__ d3)
{
    const int bid = blockIdx.x;
    const float* W; unsigned short* WB; int O, K, base;
    if (bid < 96)       { W = w0; WB = d0; O = 768;  K = 256;  base = 0;   }
    else if (bid < 160) { W = w1; WB = d1; O = 256;  K = 512;  base = 96;  }
    else if (bid < 288) { W = w2; WB = d2; O = 1024; K = 256;  base = 160; }
    else                { W = w3; WB = d3; O = 256;  K = 1024; base = 288; }
    const int idx = (bid - base) * 256 + threadIdx.x;
    if (idx >= O * (K >> 3)) return;
    const int o = idx % O;
    const int koct = idx / O;
    u16x8 v;
#pragma unroll
    for (int j = 0; j < 8; j++) v[j] = f2bf(W[(size_t)o * K + koct * 8 + j]);
    *(u16x8*)(WB + ((size_t)koct * O + o) * 8) = v;
}

// ---------------------------------------------------------------------------
// Transpose, dual-source: image ib<16 from X0, else X1.
// ---------------------------------------------------------------------------
__global__ __launch_bounds__(256)
void xpose2(const float* __restrict__ X0, const float* __restrict__ X1,
            unsigned short* __restrict__ XT, const int C)
{
    __shared__ float tt[8][260];
    const int t = threadIdx.x;
    const int octs = C >> 3;
    const int strips = octs * 4;
    const int ib = blockIdx.x / strips;
    const int rem = blockIdx.x - ib * strips;
    const int coct = rem >> 2;
    const int n0 = (rem & 3) * 256;
    const float* src = (ib < 16) ? X0 + (size_t)ib * C * NPIX
                                 : X1 + (size_t)(ib - 16) * C * NPIX;
    const int cc = t >> 5;
    const int c8 = (t & 31) * 8;
    const float* xp = src + ((size_t)(coct * 8 + cc)) * NPIX + n0 + c8;
    *(float4*)(&tt[cc][c8])     = *(const float4*)(xp);
    *(float4*)(&tt[cc][c8 + 4]) = *(const float4*)(xp + 4);
    __syncthreads();
    u16x8 v;
#pragma unroll
    for (int j = 0; j < 8; j++) v[j] = f2bf(tt[j][t]);
    *(u16x8*)(XT + (((size_t)ib * octs + coct) * NPIX + n0 + t) * 8) = v;
}

// ---------------------------------------------------------------------------
// MFMA GEMM, DIRECT global->VGPR fragments (no LDS staging, no main-loop
// barriers). Operands blocked bf16 [K/8][rows][8].
// EPI: 0 plain; 1 BN + fp32 residual (res if b<16 else res2, image b&15);
//      2 bias+hswish; 3 DUAL: INTERLEAVED second K-stream X2 into acc2,
//      then v = scale*(acc+acc2) + 2*shift + bf16blk res (b) + res (b+16).
// OMODE: 0 fp32 [c][n] (+ACC); 1 bf16 [c][n]; 2 blocked bf16; 3 fp32+blocked.
// ---------------------------------------------------------------------------
template<int BM, int BN, int EPI, bool ACC, int OMODE>
__global__ __launch_bounds__(256)
void gemm_direct(const unsigned short* __restrict__ X, const unsigned short* __restrict__ X2,
                 const unsigned short* __restrict__ W,
                 float* __restrict__ Y, unsigned short* __restrict__ YB,
                 const int O, const int K,
                 const float* __restrict__ res, const float* __restrict__ res2,
                 const unsigned short* __restrict__ resb,
                 const float* __restrict__ bng, const float* __restrict__ bnb,
                 const float* __restrict__ bnm, const float* __restrict__ bnv,
                 const float* __restrict__ bias)
{
    constexpr int TN = NPIX / BN;
    constexpr int WAVES_N = (BN >= 128) ? 2 : 1;
    constexpr int WM = BM / (4 / WAVES_N);
    constexpr int MI = WM / 16;
    constexpr int NJ = 4;
    constexpr int TSTR = (OMODE == 1) ? (BN + 8) : (BM + 8);
    constexpr int TSZ  = (OMODE == 1) ? BM * TSTR : ((OMODE >= 2) ? BN * TSTR : 64);
    __shared__ unsigned short T[TSZ];

    const int t    = threadIdx.x;
    const int lane = t & 63;
    const int w    = t >> 6;

    // XCD-bijective block swizzle (all grids are multiples of 8)
    const int gx  = gridDim.x;
    const int nwg = gx * gridDim.y;
    int bid = blockIdx.y * gx + blockIdx.x;
    bid = (bid & 7) * (nwg >> 3) + (bid >> 3);
    const int bx = bid % gx;
    const int by = bid / gx;

    const int o0 = bx * BM;
    const int b  = by / TN;
    const int n0 = (by % TN) * BN;

    const int wn = (WAVES_N == 2) ? (w & 1) * 64 : 0;
    const int wo = (WAVES_N == 2) ? (w >> 1) * WM : w * WM;

    const int l16 = lane & 15;
    const int lq  = lane >> 4;

    f32x4 acc[MI][NJ];
    f32x4 acc2[MI][NJ];
#pragma unroll
    for (int i = 0; i < MI; i++)
#pragma unroll
        for (int j = 0; j < NJ; j++) {
            f32x4 z = {0.f, 0.f, 0.f, 0.f};
            acc[i][j] = z;
            acc2[i][j] = z;
        }

    const unsigned short* Ab = W + ((size_t)lq * O + o0 + wo + l16) * 8;
    const size_t strideA = (size_t)O * 8;
    const size_t strideB = (size_t)NPIX * 8;
    const size_t boff = ((size_t)lq * NPIX + n0 + wn + l16) * 8;
    const int octs = K >> 3;                    // multiple of 8

    auto ldA_ = [&](bf16x8* fr, int kb) {
#pragma unroll
        for (int i = 0; i < MI; i++)
            fr[i] = *(const bf16x8*)(Ab + (size_t)kb * strideA + i * 128);
    };
    auto ldB_ = [&](bf16x8* fr, const unsigned short* Bb, int kb) {
#pragma unroll
        for (int j = 0; j < NJ; j++)
            fr[j] = *(const bf16x8*)(Bb + (size_t)kb * strideB + j * 128);
    };
    auto domfma_ = [&](f32x4 (&ac)[MI][NJ], bf16x8* af, bf16x8* bf) {
#pragma unroll
        for (int i = 0; i < MI; i++)
#pragma unroll
            for (int j = 0; j < NJ; j++)
                ac[i][j] = __builtin_amdgcn_mfma_f32_16x16x32_bf16(
                    af[i], bf[j], ac[i][j], 0, 0, 0);
    };

    if (EPI != 3) {
        const unsigned short* Bb = X + (size_t)b * K * NPIX + boff;
        bf16x8 aA[MI], bA[NJ], aB[MI], bB[NJ];
        ldA_(aA, 0); ldB_(bA, Bb, 0);
        for (int kb = 0; kb < octs; kb += 8) {
            ldA_(aB, kb + 4); ldB_(bB, Bb, kb + 4);
            domfma_(acc, aA, bA);
            if (kb + 8 < octs) { ldA_(aA, kb + 8); ldB_(bA, Bb, kb + 8); }
            domfma_(acc, aB, bB);
        }
    } else {
        // interleaved dual stream, shared A
        const unsigned short* B1 = X  + (size_t)b * K * NPIX + boff;
        const unsigned short* B2 = X2 + (size_t)b * K * NPIX + boff;
        bf16x8 aA[MI], aB[MI], b1A[NJ], b1B[NJ], b2A[NJ], b2B[NJ];
        ldA_(aA, 0); ldB_(b1A, B1, 0); ldB_(b2A, B2, 0);
        for (int kb = 0; kb < octs; kb += 8) {
            ldA_(aB, kb + 4);
            ldB_(b1B, B1, kb + 4); ldB_(b2B, B2, kb + 4);
            domfma_(acc,  aA, b1A);
            domfma_(acc2, aA, b2A);
            if (kb + 8 < octs) {
                ldA_(aA, kb + 8);
                ldB_(b1A, B1, kb + 8); ldB_(b2A, B2, kb + 8);
            }
            domfma_(acc,  aB, b1B);
            domfma_(acc2, aB, b2B);
        }
    }

    // epilogue. C/D: col = lane&15 (n), row = (lane>>4)*4 + reg (o)
    const int r0q = lq * 4;
    float scale[MI][4], shift[MI][4];
    if (EPI == 1 || EPI == 3) {
#pragma unroll
        for (int i = 0; i < MI; i++)
#pragma unroll
            for (int r = 0; r < 4; r++) {
                const int o = o0 + wo + i * 16 + r0q + r;
                const float inv = bng[o] / sqrtf(bnv[o] + 1e-5f);
                scale[i][r] = inv;
                shift[i][r] = bnb[o] - bnm[o] * inv;
            }
    } else if (EPI == 2) {
#pragma unroll
        for (int i = 0; i < MI; i++)
#pragma unroll
            for (int r = 0; r < 4; r++)
                shift[i][r] = bias[o0 + wo + i * 16 + r0q + r];
    }

#pragma unroll
    for (int i = 0; i < MI; i++) {
#pragma unroll
        for (int j = 0; j < NJ; j++) {
            const int nn = n0 + wn + j * 16 + l16;
            const int nl = wn + j * 16 + l16;
            const int ob = wo + i * 16 + r0q;
            const size_t base = ((size_t)b * O + o0 + ob) * NPIX + nn;
            u16x4 r1v, r2v;
            if (EPI == 3) {
                const size_t ro = (((size_t)(b * 32 + ((o0 + ob) >> 3)) * NPIX + nn) * 8
                                   + ((o0 + ob) & 7));
                r1v = *(const u16x4*)(resb + ro);
                r2v = *(const u16x4*)(resb + (size_t)16 * 262144 + ro);
            }
            u16x4 p4;
#pragma unroll
            for (int r = 0; r < 4; r++) {
                const size_t off = base + (size_t)r * NPIX;
                float v = acc[i][j][r];
                if (EPI == 1) {
                    const float* rs = (b < 16) ? res : res2;
                    const size_t roff = ((size_t)(b & 15) * O + o0 + ob + r) * NPIX + nn;
                    v = v * scale[i][r] + shift[i][r] + rs[roff];
                } else if (EPI == 2) {
                    v += shift[i][r];
                    v = v * fminf(fmaxf(v + 3.f, 0.f), 6.f) * (1.f / 6.f);
                } else if (EPI == 3) {
                    v = (v + acc2[i][j][r]) * scale[i][r] + 2.f * shift[i][r]
                        + bf2f(r1v[r]) + bf2f(r2v[r]);
                }
                if (OMODE == 0 || OMODE == 3) {
                    if (ACC) v += Y[off];
                    Y[off] = v;
                }
                if (OMODE == 1) {
                    T[(size_t)(ob + r) * TSTR + nl] = f2bf(v);
                } else if (OMODE >= 2) {
                    p4[r] = f2bf(v);
                }
            }
            if (OMODE >= 2)
                *(u16x4*)(T + (size_t)nl * TSTR + ob) = p4;
        }
    }

    if (OMODE >= 1) {
        __syncthreads();
        constexpr int CNT = BM * BN / 2048;
        if (OMODE == 1) {
#pragma unroll
            for (int k = 0; k < CNT; k++) {
                const int idx = t + k * 256;
                const int o   = idx / (BN / 8);
                const int n8  = (idx % (BN / 8)) * 8;
                const u16x8 v = *(const u16x8*)(T + (size_t)o * TSTR + n8);
                *(u16x8*)(YB + ((size_t)b * O + o0 + o) * NPIX + n0 + n8) = v;
            }
        } else {
#pragma unroll
            for (int k = 0; k < CNT; k++) {
                const int idx = t + k * 256;
                const int oo  = idx / BN;
                const int nn  = idx % BN;
                const u16x8 v = *(const u16x8*)(T + (size_t)nn * TSTR + oo * 8);
                *(u16x8*)(YB + (((size_t)b * (O >> 3) + (o0 >> 3) + oo) * NPIX + n0 + nn) * 8) = v;
            }
        }
    }
}

// ---------------------------------------------------------------------------
// Depthwise 5x5 SAME, bf16 [c][n] in/out. 2 channels/block, stride-44 fp32 LDS.
// ---------------------------------------------------------------------------
__global__ __launch_bounds__(256)
void dwconv5x5_v3(const unsigned short* __restrict__ X, const float* __restrict__ Wd,
                  unsigned short* __restrict__ Y)
{
    __shared__ float tile[2 * 36 * 44];
    __shared__ float wl[64];
    const int t     = threadIdx.x;
    const int cpair = blockIdx.x % 384;
    const int b     = blockIdx.x / 384;
    const int cbase = cpair * 2;
    const unsigned short* xp = X + ((size_t)b * 768 + cbase) * NPIX;

#pragma unroll
    for (int k = 0; k < 4; k++) {
        const int i = t + k * 256;
        if (i < 792) {
            f32x4 z = {0.f, 0.f, 0.f, 0.f};
            *(f32x4*)(&tile[i * 4]) = z;
        }
    }
    if (t < 50) wl[(t / 25) * 32 + (t % 25)] = Wd[cbase * 25 + t];
    __syncthreads();

    const int ch = t >> 7;
    const int tm = t & 127;
    const int r  = tm >> 2;
    const int c8 = (tm & 3) * 8;

    {
        const u16x8 v = *(const u16x8*)(xp + (size_t)ch * NPIX + r * 32 + c8);
        float* wp = &tile[ch * 1584 + (r + 2) * 44 + c8 + 2];
#pragma unroll
        for (int j = 0; j < 8; j += 2) {
            float2 f2v = make_float2(bf2f(v[j]), bf2f(v[j + 1]));
            *(float2*)(wp + j) = f2v;
        }
    }
    float wk[25];
#pragma unroll
    for (int i = 0; i < 25; i++) wk[i] = wl[ch * 32 + i];
    __syncthreads();

    float acc[8];
#pragma unroll
    for (int j = 0; j < 8; j++) acc[j] = 0.f;

#pragma unroll
    for (int ky = 0; ky < 5; ky++) {
        const float* rp = &tile[ch * 1584 + (r + ky) * 44 + c8];
        const f32x4 a = *(const f32x4*)(rp);
        const f32x4 bq = *(const f32x4*)(rp + 4);
        const f32x4 cq = *(const f32x4*)(rp + 8);
        const float in[12] = {a[0], a[1], a[2], a[3], bq[0], bq[1], bq[2], bq[3],
                              cq[0], cq[1], cq[2], cq[3]};
#pragma unroll
        for (int kx = 0; kx < 5; kx++) {
            const float wv = wk[ky * 5 + kx];
#pragma unroll
            for (int j = 0; j < 8; j++)
                acc[j] = fmaf(in[j + kx], wv, acc[j]);
        }
    }

    u16x8 o8;
#pragma unroll
    for (int j = 0; j < 8; j++) o8[j] = f2bf(acc[j]);
    *(u16x8*)(Y + ((size_t)b * 768 + cbase + ch) * NPIX + r * 32 + c8) = o8;
}

// ---------------------------------------------------------------------------
// Depthwise 3x3 + bias + hswish, blocked bf16 in/out — 2 px x 8 ch per thread,
// direct global reads, no pixel LDS.
// ---------------------------------------------------------------------------
__global__ __launch_bounds__(256)
void dwconv3x3_h2(const unsigned short* __restrict__ X, const float* __restrict__ Wd,
                  const float* __restrict__ bias, unsigned short* __restrict__ Y)
{
    __shared__ float wl[72];
    __shared__ float bb[8];
    const int t    = threadIdx.x;
    const int bid  = blockIdx.x;
    const int half = bid & 1;
    const int coct = (bid >> 1) & 127;
    const int b    = bid >> 8;
    const unsigned short* xp = X + ((size_t)(b * 128 + coct)) * NPIX * 8;
    if (t < 72) wl[t] = Wd[coct * 72 + t];
    if (t < 8)  bb[t] = bias[coct * 8 + t];
    __syncthreads();

    const int px0 = half * 512 + t * 2;   // 2 consecutive pixels
    const int hr  = px0 >> 5;             // image row
    const int c0  = px0 & 31;             // image col (even)

    float acc[8][2];
#pragma unroll
    for (int ch = 0; ch < 8; ch++) {
        acc[ch][0] = bb[ch];
        acc[ch][1] = bb[ch];
    }

#pragma unroll
    for (int ky = 0; ky < 3; ky++) {
        const int rr = hr + ky - 1;
        if (rr >= 0 && rr < 32) {
            u16x8 P[4];
#pragma unroll
            for (int m = 0; m < 4; m++) {
                const int col = c0 - 1 + m;
                const int colc = col < 0 ? 0 : (col > 31 ? 31 : col);
                u16x8 v = *(const u16x8*)(xp + (size_t)(rr * 32 + colc) * 8);
                if (col < 0 || col > 31) v = zero8();
                P[m] = v;
            }
#pragma unroll
            for (int ch = 0; ch < 8; ch++) {
                float g[4];
#pragma unroll
                for (int m = 0; m < 4; m++) g[m] = bf2f(P[m][ch]);
#pragma unroll
                for (int j = 0; j < 2; j++)
#pragma unroll
                    for (int kx = 0; kx < 3; kx++)
                        acc[ch][j] = fmaf(g[j + kx], wl[ch * 9 + ky * 3 + kx], acc[ch][j]);
            }
        }
    }
    unsigned short* yp = Y + ((size_t)(b * 128 + coct)) * NPIX * 8 + (size_t)px0 * 8;
#pragma unroll
    for (int j = 0; j < 2; j++) {
        u16x8 o8;
#pragma unroll
        for (int ch = 0; ch < 8; ch++) {
            float v = acc[ch][j];
            v = v * fminf(fmaxf(v + 3.f, 0.f), 6.f) * (1.f / 6.f);
            o8[ch] = f2bf(v);
        }
        *(u16x8*)(yp + j * 8) = o8;
    }
}

// ---------------------------------------------------------------------------
// Grouped 32->32 1x1 (24 groups), in-place on bf16 [c][n] D.
// ---------------------------------------------------------------------------
__global__ __launch_bounds__(256)
void grouped_pw(unsigned short* __restrict__ D, const float* __restrict__ Wg)
{
    __shared__ float ws[1024];
    const int t     = threadIdx.x;
    const int blk   = blockIdx.x;
    const int chunk = blk & 3;
    const int bg    = blk >> 2;
    const int g     = bg % 24;
    const int b     = bg / 24;
    for (int i = t; i < 1024; i += 256) ws[i] = Wg[g * 1024 + i];
    __syncthreads();
    const int px = chunk * 256 + t;
    unsigned short* dp = D + ((size_t)(b * 768 + g * 32)) * NPIX + px;
    float in[32];
#pragma unroll
    for (int i = 0; i < 32; i++) in[i] = bf2f(dp[(size_t)i * NPIX]);
#pragma unroll
    for (int o = 0; o < 32; o++) {
        float s = 0.f;
#pragma unroll
        for (int i = 0; i < 32; i++) s = fmaf(ws[o * 32 + i], in[i], s);
        dp[(size_t)o * NPIX] = f2bf(s);
    }
}

// ---------------------------------------------------------------------------
// FUSED attention v2: one block per (b,h), 4 waves. NO transpose LDS:
// phase-2 output goes straight from MFMA regs to global — each lane's 4
// accumulator regs are 4 CONTIGUOUS channels in the blocked layout
// (d&7 = (lq&1)*4 + r), so a u16x4 (8B aligned) store suffices.
// Denominator broadcast via __shfl (col l16 lives in lane l16 reg0).
// LDS = kvred + kvs ~ 21.6 KB (was 105.5 KB -> 1 block/CU).
// ---------------------------------------------------------------------------
__global__ __launch_bounds__(256)
void attn_fused(const unsigned short* __restrict__ qkv,
                const unsigned short* __restrict__ dpw,
                unsigned short* __restrict__ att)
{
    __shared__ float kvred[4][33 * 33];
    __shared__ float kvs[1056];

    const int t    = threadIdx.x;
    const int lane = t & 63;
    const int w    = t >> 6;
    const int bh   = blockIdx.x;
    const int b    = bh >> 4;
    const int h    = bh & 15;

    const unsigned short* base = (h < 8)
        ? qkv + ((size_t)(b * 768 + h * 96)) * NPIX
        : dpw + ((size_t)(b * 768 + (h - 8) * 96)) * NPIX;
    const unsigned short* qp = base;
    const unsigned short* kp = base + 32 * NPIX;
    const unsigned short* vp = base + 64 * NPIX;

    const int l16 = lane & 15;
    const int lq  = lane >> 4;
    const int ko  = lq * 8;
    const int nb  = w * 256;

    // phase 1: kv partials
    {
        f32x4 acc[3][2];
#pragma unroll
        for (int i = 0; i < 3; i++)
#pragma unroll
            for (int j = 0; j < 2; j++) {
                f32x4 z = {0.f, 0.f, 0.f, 0.f};
                acc[i][j] = z;
            }
        bf16x8 ones;
#pragma unroll
        for (int j = 0; j < 8; j++) ones[j] = (l16 == 0) ? (short)0x3F80 : (short)0;

#pragma unroll
        for (int s = 0; s < 8; s++) {
            const int n0 = nb + s * 32 + ko;
            const bf16x8 av0 = *(const bf16x8*)(vp + (size_t)l16 * NPIX + n0);
            const bf16x8 av1 = *(const bf16x8*)(vp + (size_t)(16 + l16) * NPIX + n0);
            const u16x8 k0 = *(const u16x8*)(kp + (size_t)l16 * NPIX + n0);
            const u16x8 k1 = *(const u16x8*)(kp + (size_t)(16 + l16) * NPIX + n0);
            bf16x8 bk0, bk1;
#pragma unroll
            for (int j = 0; j < 8; j++) {
                bk0[j] = (k0[j] & 0x8000u) ? (short)0 : (short)k0[j];
                bk1[j] = (k1[j] & 0x8000u) ? (short)0 : (short)k1[j];
            }
            acc[0][0] = __builtin_amdgcn_mfma_f32_16x16x32_bf16(av0,  bk0, acc[0][0], 0, 0, 0);
            acc[0][1] = __builtin_amdgcn_mfma_f32_16x16x32_bf16(av0,  bk1, acc[0][1], 0, 0, 0);
            acc[1][0] = __builtin_amdgcn_mfma_f32_16x16x32_bf16(av1,  bk0, acc[1][0], 0, 0, 0);
            acc[1][1] = __builtin_amdgcn_mfma_f32_16x16x32_bf16(av1,  bk1, acc[1][1], 0, 0, 0);
            acc[2][0] = __builtin_amdgcn_mfma_f32_16x16x32_bf16(ones, bk0, acc[2][0], 0, 0, 0);
            acc[2][1] = __builtin_amdgcn_mfma_f32_16x16x32_bf16(ones, bk1, acc[2][1], 0, 0, 0);
        }
        const int rbase = lq * 4;
#pragma unroll
        for (int dt = 0; dt < 2; dt++)
#pragma unroll
            for (int et = 0; et < 2; et++)
#pragma unroll
                for (int r = 0; r < 4; r++)
                    kvred[w][(dt * 16 + rbase + r) * 33 + et * 16 + l16] = acc[dt][et][r];
        if (rbase == 0) {
#pragma unroll
            for (int et = 0; et < 2; et++)
                kvred[w][32 * 33 + et * 16 + l16] = acc[2][et][0];
        }
    }
    __syncthreads();
#pragma unroll
    for (int k = 0; k < 5; k++) {
        const int idx = t + k * 256;
        if (idx < 1056) {
            const int a = (idx >> 5) * 33 + (idx & 31);
            kvs[idx] = kvred[0][a] + kvred[1][a] + kvred[2][a] + kvred[3][a];
        }
    }
    __syncthreads();

    // phase 2: out = kv · relu(Q), K=32; output straight from regs.
    bf16x8 a0, a1, a2;
#pragma unroll
    for (int j = 0; j < 8; j++) {
        a0[j] = (short)f2bf(kvs[l16 * 32 + ko + j]);
        a1[j] = (short)f2bf(kvs[(16 + l16) * 32 + ko + j]);
        a2[j] = (l16 == 0) ? (short)f2bf(kvs[32 * 32 + ko + j]) : (short)0;
    }
    bf16x8 bfr[16];
    const unsigned short* qb = qp + (size_t)ko * NPIX + nb + l16;
#pragma unroll
    for (int tl = 0; tl < 16; tl++) {
        bf16x8 bf;
#pragma unroll
        for (int j = 0; j < 8; j++) {
            const unsigned short v = qb[(size_t)j * NPIX + tl * 16];
            bf[j] = (v & 0x8000u) ? (short)0 : (short)v;
        }
        bfr[tl] = bf;
    }

    // output bases: c0 covers d = lq*4+r  -> db0 = lq>>1, sub = (lq&1)*4
    //               c1 covers d = 16+...  -> db1 = 2 + (lq>>1)
    const int db0 = lq >> 1;
    const int sub = (lq & 1) * 4;
    unsigned short* ab0 = att + (((size_t)(b * 64 + h * 4 + db0)) * NPIX) * 8 + sub;
    unsigned short* ab1 = att + (((size_t)(b * 64 + h * 4 + 2 + db0)) * NPIX) * 8 + sub;

#pragma unroll
    for (int tl = 0; tl < 16; tl++) {
        f32x4 z = {0.f, 0.f, 0.f, 0.f};
        z = __builtin_amdgcn_mfma_f32_16x16x32_bf16(a2, bfr[tl], z, 0, 0, 0);
        const float den = __shfl(z[0], l16, 64);     // den(col l16) from lane l16
        const float inv = 1.f / (den + 1e-15f);
        f32x4 c0 = {0.f, 0.f, 0.f, 0.f};
        f32x4 c1 = {0.f, 0.f, 0.f, 0.f};
        c0 = __builtin_amdgcn_mfma_f32_16x16x32_bf16(a0, bfr[tl], c0, 0, 0, 0);
        c1 = __builtin_amdgcn_mfma_f32_16x16x32_bf16(a1, bfr[tl], c1, 0, 0, 0);
        u16x4 p0, p1;
#pragma unroll
        for (int r = 0; r < 4; r++) {
            p0[r] = f2bf(c0[r] * inv);
            p1[r] = f2bf(c1[r] * inv);
        }
        const size_t n8 = (size_t)(nb + tl * 16 + l16) * 8;
        *(u16x4*)(ab0 + n8) = p0;
        *(u16x4*)(ab1 + n8) = p1;
    }
}

// ---------------------------------------------------------------------------
extern "C" void kernel_launch(void* const* d_in, const int* in_sizes, int n_in,
                              void* d_out, int out_size, void* d_ws, size_t ws_size,
                              hipStream_t stream)
{
    (void)in_sizes; (void)n_in; (void)out_size;

    const float* x      = (const float*)d_in[0];
    const float* y      = (const float*)d_in[1];
    const float* qkv_w  = (const float*)d_in[2];
    const float* dw5_w  = (const float*)d_in[3];
    const float* pwg_w  = (const float*)d_in[4];
    const float* proj_w = (const float*)d_in[5];
    const float* proj_g = (const float*)d_in[6];
    const float* proj_b = (const float*)d_in[7];
    const float* proj_m = (const float*)d_in[8];
    const float* proj_v = (const float*)d_in[9];
    const float* inv_w  = (const float*)d_in[10];
    const float* inv_b  = (const float*)d_in[11];
    const float* dwc_w  = (const float*)d_in[12];
    const float* dwc_b  = (const float*)d_in[13];
    const float* pw_w   = (const float*)d_in[14];
    const float* pw_g   = (const float*)d_in[15];
    const float* pw_b   = (const float*)d_in[16];
    const float* pw_m   = (const float*)d_in[17];
    const float* pw_v   = (const float*)d_in[18];

    float* ws = (float*)d_ws;
    unsigned short* wqkv_b  = (unsigned short*)(ws + WQKV_OFF);
    unsigned short* wproj_b = (unsigned short*)(ws + WPROJ_OFF);
    unsigned short* winv_b  = (unsigned short*)(ws + WINV_OFF);
    unsigned short* wpw_b   = (unsigned short*)(ws + WPW_OFF);
    float* out = (float*)d_out;

    wconv_all<<<dim3(416), 256, 0, stream>>>(qkv_w, proj_w, inv_w, pw_w,
                                             wqkv_b, wproj_b, winv_b, wpw_b);

    if (ws_size >= (size_t)BATCH_NEED_F * 4ull) {
        // ---------------- batched path: both chains as images 0..31 ----------
        unsigned short* bxt  = (unsigned short*)(ws + BXT_OFF);
        unsigned short* bqkv = (unsigned short*)(ws + BQKV_OFF);
        unsigned short* bdpw = (unsigned short*)(ws + BDPW_OFF);
        unsigned short* batt = (unsigned short*)(ws + BATT_OFF);
        unsigned short* bt1t = (unsigned short*)(ws + BT1T_OFF);
        unsigned short* bh1t = (unsigned short*)(ws + BH1T_OFF);
        unsigned short* bh2t = (unsigned short*)(ws + BH2T_OFF);

        xpose2<<<dim3(4096), 256, 0, stream>>>(x, y, bxt, 256);
        gemm_direct<128, 128, 0, false, 1><<<dim3(6, 256), 256, 0, stream>>>(
            bxt, nullptr, wqkv_b, nullptr, bqkv, 768, 256,
            nullptr, nullptr, nullptr, nullptr, nullptr, nullptr, nullptr, nullptr);
        dwconv5x5_v3<<<dim3(12288), 256, 0, stream>>>(bqkv, dw5_w, bdpw);
        grouped_pw<<<dim3(3072), 256, 0, stream>>>(bdpw, pwg_w);
        attn_fused<<<dim3(512), 256, 0, stream>>>(bqkv, bdpw, batt);
        gemm_direct<64, 64, 1, false, 2><<<dim3(4, 512), 256, 0, stream>>>(
            batt, nullptr, wproj_b, nullptr, bt1t, 256, 512,
            x, y, nullptr, proj_g, proj_b, proj_m, proj_v, nullptr);
        gemm_direct<128, 128, 2, false, 2><<<dim3(8, 256), 256, 0, stream>>>(
            bt1t, nullptr, winv_b, nullptr, bh1t, 1024, 256,
            nullptr, nullptr, nullptr, nullptr, nullptr, nullptr, nullptr, inv_b);
        dwconv3x3_h2<<<dim3(8192), 256, 0, stream>>>(bh1t, dwc_w, dwc_b, bh2t);
        gemm_direct<64, 64, 3, false, 0><<<dim3(4, 256), 256, 0, stream>>>(
            bh2t, bh2t + (size_t)16 * 1024 * 1024, wpw_b, out, nullptr, 256, 1024,
            nullptr, nullptr, bt1t, pw_g, pw_b, pw_m, pw_v, nullptr);
    } else {
        // ---------------- fallback: per-chain (R14 structure) ----------------
        unsigned short* wxt  = (unsigned short*)(ws + XT_OFF);
        unsigned short* wqkv = (unsigned short*)(ws + QKV_OFF);
        unsigned short* wdpw = (unsigned short*)(ws + DPW_OFF);
        unsigned short* watt = (unsigned short*)(ws + ATT_OFF);
        float*          wt1  = ws + T1_OFF;
        unsigned short* wt1t = (unsigned short*)(ws + T1T_OFF);
        unsigned short* wh1t = (unsigned short*)(ws + H1T_OFF);
        unsigned short* wh2t = (unsigned short*)(ws + H2T_OFF);

        for (int blk = 0; blk < 2; blk++) {
            const float* t = (blk == 0) ? x : y;
            xpose2<<<dim3(2048), 256, 0, stream>>>(t, t, wxt, 256);
            gemm_direct<128, 128, 0, false, 1><<<dim3(6, 128), 256, 0, stream>>>(
                wxt, nullptr, wqkv_b, nullptr, wqkv, 768, 256,
                nullptr, nullptr, nullptr, nullptr, nullptr, nullptr, nullptr, nullptr);
            dwconv5x5_v3<<<dim3(6144), 256, 0, stream>>>(wqkv, dw5_w, wdpw);
            grouped_pw<<<dim3(1536), 256, 0, stream>>>(wdpw, pwg_w);
            attn_fused<<<dim3(256), 256, 0, stream>>>(wqkv, wdpw, watt);
            gemm_direct<64, 64, 1, false, 3><<<dim3(4, 256), 256, 0, stream>>>(
                watt, watt, wproj_b, wt1, wt1t, 256, 512,
                t, t, nullptr, proj_g, proj_b, proj_m, proj_v, nullptr);
            gemm_direct<128, 128, 2, false, 2><<<dim3(8, 128), 256, 0, stream>>>(
                wt1t, nullptr, winv_b, nullptr, wh1t, 1024, 256,
                nullptr, nullptr, nullptr, nullptr, nullptr, nullptr, nullptr, inv_b);
            dwconv3x3_h2<<<dim3(4096), 256, 0, stream>>>(wh1t, dwc_w, dwc_b, wh2t);
            if (blk == 0) {
                gemm_direct<64, 64, 1, false, 0><<<dim3(4, 256), 256, 0, stream>>>(
                    wh2t, nullptr, wpw_b, out, nullptr, 256, 1024,
                    wt1, wt1, nullptr, pw_g, pw_b, pw_m, pw_v, nullptr);
            } else {
                gemm_direct<64, 64, 1, true, 0><<<dim3(4, 256), 256, 0, stream>>>(
                    wh2t, nullptr, wpw_b, out, nullptr, 256, 1024,
                    wt1, wt1, nullptr, pw_g, pw_b, pw_m, pw_v, nullptr);
            }
        }
    }
}

// Round 20
// 248.316 us; speedup vs baseline: 1.0724x; 1.0167x over previous
//
#include <hip/hip_runtime.h>
#include <cstddef>

#define NPIX 1024   // H*W = 32*32

// ---------------------------------------------------------------------------
// Workspace layouts (float-slot offsets).
// BATCHED (both residual chains as images 0..31): peak 38,174,720 floats.
// FALLBACK (per-chain, R14 layout): peak 34,045,952 floats.
// ---------------------------------------------------------------------------
static constexpr size_t WQKV_OFF  = 0;
static constexpr size_t WPROJ_OFF = 98304;
static constexpr size_t WINV_OFF  = 163840;
static constexpr size_t WPW_OFF   = 294912;
// batched
static constexpr size_t BXT_OFF   = 425984;
static constexpr size_t BQKV_OFF  = 4620288;
static constexpr size_t BDPW_OFF  = 17203200;
static constexpr size_t BATT_OFF  = 29786112;
static constexpr size_t BT1T_OFF  = 425984;     // alias XT32
static constexpr size_t BH1T_OFF  = 4620288;    // alias QKV32..
static constexpr size_t BH2T_OFF  = 21397504;   // alias DPW-tail+ATT
static constexpr size_t BATCH_NEED_F = 38174720;
// fallback (R14)
static constexpr size_t XT_OFF    = 425984;
static constexpr size_t QKV_OFF   = 2523136;
static constexpr size_t DPW_OFF   = 8814592;
static constexpr size_t ATT_OFF   = 15106048;
static constexpr size_t T1_OFF    = 21463040;
static constexpr size_t T1T_OFF   = 25657344;
static constexpr size_t H1T_OFF   = 425984;
static constexpr size_t H2T_OFF   = 25657344;

typedef __attribute__((ext_vector_type(8))) short bf16x8;
typedef __attribute__((ext_vector_type(8))) unsigned short u16x8;
typedef __attribute__((ext_vector_type(4))) unsigned short u16x4;
typedef __attribute__((ext_vector_type(4))) float f32x4;

__device__ inline unsigned short f2bf(float f) {
    union { float f; unsigned int u; } v; v.f = f;
    unsigned int u = v.u;
    u += 0x7FFFu + ((u >> 16) & 1u);        // round-to-nearest-even
    return (unsigned short)(u >> 16);
}
__device__ inline float bf2f(unsigned short u) {
    union { float f; unsigned int u; } v; v.u = ((unsigned int)u) << 16;
    return v.f;
}
__device__ inline u16x8 zero8() {
    u16x8 z = {0, 0, 0, 0, 0, 0, 0, 0};
    return z;
}

// ---------------------------------------------------------------------------
// Weight convert (all 4 weights in ONE launch): fp32 [O][K] -> bf16 [K/8][O][8]
// ---------------------------------------------------------------------------
__global__ __launch_bounds__(256)
void wconv_all(const float* __restrict__ w0, const float* __restrict__ w1,
               const float* __restrict__ w2, const float* __restrict__ w3,
               unsigned short* __restrict__ d0, unsigned short* __restrict__ d1,
               unsigned short* __restrict__ d2, unsigned short* __restrict__ d3)
{
    const int bid = blockIdx.x;
    const float* W; unsigned short* WB; int O, K, base;
    if (bid < 96)       { W = w0; WB = d0; O = 768;  K = 256;  base = 0;   }
    else if (bid < 160) { W = w1; WB = d1; O = 256;  K = 512;  base = 96;  }
    else if (bid < 288) { W = w2; WB = d2; O = 1024; K = 256;  base = 160; }
    else                { W = w3; WB = d3; O = 256;  K = 1024; base = 288; }
    const int idx = (bid - base) * 256 + threadIdx.x;
    if (idx >= O * (K >> 3)) return;
    const int o = idx % O;
    const int koct = idx / O;
    u16x8 v;
#pragma unroll
    for (int j = 0; j < 8; j++) v[j] = f2bf(W[(size_t)o * K + koct * 8 + j]);
    *(u16x8*)(WB + ((size_t)koct * O + o) * 8) = v;
}

// ---------------------------------------------------------------------------
// Transpose, dual-source: image ib<16 from X0, else X1.
// ---------------------------------------------------------------------------
__global__ __launch_bounds__(256)
void xpose2(const float* __restrict__ X0, const float* __restrict__ X1,
            unsigned short* __restrict__ XT, const int C)
{
    __shared__ float tt[8][260];
    const int t = threadIdx.x;
    const int octs = C >> 3;
    const int strips = octs * 4;
    const int ib = blockIdx.x / strips;
    const int rem = blockIdx.x - ib * strips;
    const int coct = rem >> 2;
    const int n0 = (rem & 3) * 256;
    const float* src = (ib < 16) ? X0 + (size_t)ib * C * NPIX
                                 : X1 + (size_t)(ib - 16) * C * NPIX;
    const int cc = t >> 5;
    const int c8 = (t & 31) * 8;
    const float* xp = src + ((size_t)(coct * 8 + cc)) * NPIX + n0 + c8;
    *(float4*)(&tt[cc][c8])     = *(const float4*)(xp);
    *(float4*)(&tt[cc][c8 + 4]) = *(const float4*)(xp + 4);
    __syncthreads();
    u16x8 v;
#pragma unroll
    for (int j = 0; j < 8; j++) v[j] = f2bf(tt[j][t]);
    *(u16x8*)(XT + (((size_t)ib * octs + coct) * NPIX + n0 + t) * 8) = v;
}

// ---------------------------------------------------------------------------
// MFMA GEMM, DIRECT global->VGPR fragments, 4-DEEP register pipeline
// (16 k-octs in flight; prefetch distance ~4x the old 2-deep scheme).
// Operands blocked bf16 [K/8][rows][8].  K/8 must be a multiple of 16
// (K in {256,512,1024} -> octs in {32,64,128}).
// EPI: 0 plain; 1 BN + fp32 residual; 2 bias+hswish; 3 DUAL interleaved
//      second K-stream X2 into acc2 (shared A), BN+2*shift+bf16 residuals.
// OMODE: 0 fp32 [c][n] (+ACC); 1 bf16 [c][n]; 2 blocked bf16; 3 fp32+blocked.
// ---------------------------------------------------------------------------
template<int BM, int BN, int EPI, bool ACC, int OMODE>
__global__ __launch_bounds__(256)
void gemm_direct(const unsigned short* __restrict__ X, const unsigned short* __restrict__ X2,
                 const unsigned short* __restrict__ W,
                 float* __restrict__ Y, unsigned short* __restrict__ YB,
                 const int O, const int K,
                 const float* __restrict__ res, const float* __restrict__ res2,
                 const unsigned short* __restrict__ resb,
                 const float* __restrict__ bng, const float* __restrict__ bnb,
                 const float* __restrict__ bnm, const float* __restrict__ bnv,
                 const float* __restrict__ bias)
{
    constexpr int TN = NPIX / BN;
    constexpr int WAVES_N = (BN >= 128) ? 2 : 1;
    constexpr int WM = BM / (4 / WAVES_N);
    constexpr int MI = WM / 16;
    constexpr int NJ = 4;
    constexpr int TSTR = (OMODE == 1) ? (BN + 8) : (BM + 8);
    constexpr int TSZ  = (OMODE == 1) ? BM * TSTR : ((OMODE >= 2) ? BN * TSTR : 64);
    __shared__ unsigned short T[TSZ];

    const int t    = threadIdx.x;
    const int lane = t & 63;
    const int w    = t >> 6;

    // XCD-bijective block swizzle (all grids are multiples of 8)
    const int gx  = gridDim.x;
    const int nwg = gx * gridDim.y;
    int bid = blockIdx.y * gx + blockIdx.x;
    bid = (bid & 7) * (nwg >> 3) + (bid >> 3);
    const int bx = bid % gx;
    const int by = bid / gx;

    const int o0 = bx * BM;
    const int b  = by / TN;
    const int n0 = (by % TN) * BN;

    const int wn = (WAVES_N == 2) ? (w & 1) * 64 : 0;
    const int wo = (WAVES_N == 2) ? (w >> 1) * WM : w * WM;

    const int l16 = lane & 15;
    const int lq  = lane >> 4;

    f32x4 acc[MI][NJ];
    f32x4 acc2[MI][NJ];
#pragma unroll
    for (int i = 0; i < MI; i++)
#pragma unroll
        for (int j = 0; j < NJ; j++) {
            f32x4 z = {0.f, 0.f, 0.f, 0.f};
            acc[i][j] = z;
            acc2[i][j] = z;
        }

    const unsigned short* Ab = W + ((size_t)lq * O + o0 + wo + l16) * 8;
    const size_t strideA = (size_t)O * 8;
    const size_t strideB = (size_t)NPIX * 8;
    const size_t boff = ((size_t)lq * NPIX + n0 + wn + l16) * 8;
    const int octs = K >> 3;                    // multiple of 16

    auto ldA_ = [&](bf16x8* fr, int kb) {
#pragma unroll
        for (int i = 0; i < MI; i++)
            fr[i] = *(const bf16x8*)(Ab + (size_t)kb * strideA + i * 128);
    };
    auto ldB_ = [&](bf16x8* fr, const unsigned short* Bb, int kb) {
#pragma unroll
        for (int j = 0; j < NJ; j++)
            fr[j] = *(const bf16x8*)(Bb + (size_t)kb * strideB + j * 128);
    };
    auto domfma_ = [&](f32x4 (&ac)[MI][NJ], bf16x8* af, bf16x8* bf) {
#pragma unroll
        for (int i = 0; i < MI; i++)
#pragma unroll
            for (int j = 0; j < NJ; j++)
                ac[i][j] = __builtin_amdgcn_mfma_f32_16x16x32_bf16(
                    af[i], bf[j], ac[i][j], 0, 0, 0);
    };

    if (EPI != 3) {
        const unsigned short* Bb = X + (size_t)b * K * NPIX + boff;
        bf16x8 a0[MI], b0[NJ], a1[MI], b1[NJ], a2s[MI], b2[NJ], a3[MI], b3[NJ];
        ldA_(a0, 0);  ldB_(b0, Bb, 0);
        ldA_(a1, 4);  ldB_(b1, Bb, 4);
        ldA_(a2s, 8); ldB_(b2, Bb, 8);
        ldA_(a3, 12); ldB_(b3, Bb, 12);
        for (int kb = 0; kb < octs; kb += 16) {
            domfma_(acc, a0, b0);
            if (kb + 16 < octs) { ldA_(a0, kb + 16); ldB_(b0, Bb, kb + 16); }
            domfma_(acc, a1, b1);
            if (kb + 20 < octs) { ldA_(a1, kb + 20); ldB_(b1, Bb, kb + 20); }
            domfma_(acc, a2s, b2);
            if (kb + 24 < octs) { ldA_(a2s, kb + 24); ldB_(b2, Bb, kb + 24); }
            domfma_(acc, a3, b3);
            if (kb + 28 < octs) { ldA_(a3, kb + 28); ldB_(b3, Bb, kb + 28); }
        }
    } else {
        // interleaved dual stream, shared A, 4-deep
        const unsigned short* B1 = X  + (size_t)b * K * NPIX + boff;
        const unsigned short* B2 = X2 + (size_t)b * K * NPIX + boff;
        bf16x8 a0[MI], a1[MI], a2s[MI], a3[MI];
        bf16x8 p0[NJ], p1[NJ], p2[NJ], p3[NJ];
        bf16x8 q0[NJ], q1[NJ], q2[NJ], q3[NJ];
        ldA_(a0, 0);  ldB_(p0, B1, 0);  ldB_(q0, B2, 0);
        ldA_(a1, 4);  ldB_(p1, B1, 4);  ldB_(q1, B2, 4);
        ldA_(a2s, 8); ldB_(p2, B1, 8);  ldB_(q2, B2, 8);
        ldA_(a3, 12); ldB_(p3, B1, 12); ldB_(q3, B2, 12);
        for (int kb = 0; kb < octs; kb += 16) {
            domfma_(acc,  a0, p0);
            domfma_(acc2, a0, q0);
            if (kb + 16 < octs) { ldA_(a0, kb + 16); ldB_(p0, B1, kb + 16); ldB_(q0, B2, kb + 16); }
            domfma_(acc,  a1, p1);
            domfma_(acc2, a1, q1);
            if (kb + 20 < octs) { ldA_(a1, kb + 20); ldB_(p1, B1, kb + 20); ldB_(q1, B2, kb + 20); }
            domfma_(acc,  a2s, p2);
            domfma_(acc2, a2s, q2);
            if (kb + 24 < octs) { ldA_(a2s, kb + 24); ldB_(p2, B1, kb + 24); ldB_(q2, B2, kb + 24); }
            domfma_(acc,  a3, p3);
            domfma_(acc2, a3, q3);
            if (kb + 28 < octs) { ldA_(a3, kb + 28); ldB_(p3, B1, kb + 28); ldB_(q3, B2, kb + 28); }
        }
    }

    // epilogue. C/D: col = lane&15 (n), row = (lane>>4)*4 + reg (o)
    const int r0q = lq * 4;
    float scale[MI][4], shift[MI][4];
    if (EPI == 1 || EPI == 3) {
#pragma unroll
        for (int i = 0; i < MI; i++)
#pragma unroll
            for (int r = 0; r < 4; r++) {
                const int o = o0 + wo + i * 16 + r0q + r;
                const float inv = bng[o] / sqrtf(bnv[o] + 1e-5f);
                scale[i][r] = inv;
                shift[i][r] = bnb[o] - bnm[o] * inv;
            }
    } else if (EPI == 2) {
#pragma unroll
        for (int i = 0; i < MI; i++)
#pragma unroll
            for (int r = 0; r < 4; r++)
                shift[i][r] = bias[o0 + wo + i * 16 + r0q + r];
    }

#pragma unroll
    for (int i = 0; i < MI; i++) {
#pragma unroll
        for (int j = 0; j < NJ; j++) {
            const int nn = n0 + wn + j * 16 + l16;
            const int nl = wn + j * 16 + l16;
            const int ob = wo + i * 16 + r0q;
            const size_t base = ((size_t)b * O + o0 + ob) * NPIX + nn;
            u16x4 r1v, r2v;
            if (EPI == 3) {
                const size_t ro = (((size_t)(b * 32 + ((o0 + ob) >> 3)) * NPIX + nn) * 8
                                   + ((o0 + ob) & 7));
                r1v = *(const u16x4*)(resb + ro);
                r2v = *(const u16x4*)(resb + (size_t)16 * 262144 + ro);
            }
            u16x4 p4;
#pragma unroll
            for (int r = 0; r < 4; r++) {
                const size_t off = base + (size_t)r * NPIX;
                float v = acc[i][j][r];
                if (EPI == 1) {
                    const float* rs = (b < 16) ? res : res2;
                    const size_t roff = ((size_t)(b & 15) * O + o0 + ob + r) * NPIX + nn;
                    v = v * scale[i][r] + shift[i][r] + rs[roff];
                } else if (EPI == 2) {
                    v += shift[i][r];
                    v = v * fminf(fmaxf(v + 3.f, 0.f), 6.f) * (1.f / 6.f);
                } else if (EPI == 3) {
                    v = (v + acc2[i][j][r]) * scale[i][r] + 2.f * shift[i][r]
                        + bf2f(r1v[r]) + bf2f(r2v[r]);
                }
                if (OMODE == 0 || OMODE == 3) {
                    if (ACC) v += Y[off];
                    Y[off] = v;
                }
                if (OMODE == 1) {
                    T[(size_t)(ob + r) * TSTR + nl] = f2bf(v);
                } else if (OMODE >= 2) {
                    p4[r] = f2bf(v);
                }
            }
            if (OMODE >= 2)
                *(u16x4*)(T + (size_t)nl * TSTR + ob) = p4;
        }
    }

    if (OMODE >= 1) {
        __syncthreads();
        constexpr int CNT = BM * BN / 2048;
        if (OMODE == 1) {
#pragma unroll
            for (int k = 0; k < CNT; k++) {
                const int idx = t + k * 256;
                const int o   = idx / (BN / 8);
                const int n8  = (idx % (BN / 8)) * 8;
                const u16x8 v = *(const u16x8*)(T + (size_t)o * TSTR + n8);
                *(u16x8*)(YB + ((size_t)b * O + o0 + o) * NPIX + n0 + n8) = v;
            }
        } else {
#pragma unroll
            for (int k = 0; k < CNT; k++) {
                const int idx = t + k * 256;
                const int oo  = idx / BN;
                const int nn  = idx % BN;
                const u16x8 v = *(const u16x8*)(T + (size_t)nn * TSTR + oo * 8);
                *(u16x8*)(YB + (((size_t)b * (O >> 3) + (o0 >> 3) + oo) * NPIX + n0 + nn) * 8) = v;
            }
        }
    }
}

// ---------------------------------------------------------------------------
// Depthwise 5x5 SAME, bf16 [c][n] in/out. 2 channels/block, stride-44 fp32 LDS.
// ---------------------------------------------------------------------------
__global__ __launch_bounds__(256)
void dwconv5x5_v3(const unsigned short* __restrict__ X, const float* __restrict__ Wd,
                  unsigned short* __restrict__ Y)
{
    __shared__ float tile[2 * 36 * 44];
    __shared__ float wl[64];
    const int t     = threadIdx.x;
    const int cpair = blockIdx.x % 384;
    const int b     = blockIdx.x / 384;
    const int cbase = cpair * 2;
    const unsigned short* xp = X + ((size_t)b * 768 + cbase) * NPIX;

#pragma unroll
    for (int k = 0; k < 4; k++) {
        const int i = t + k * 256;
        if (i < 792) {
            f32x4 z = {0.f, 0.f, 0.f, 0.f};
            *(f32x4*)(&tile[i * 4]) = z;
        }
    }
    if (t < 50) wl[(t / 25) * 32 + (t % 25)] = Wd[cbase * 25 + t];
    __syncthreads();

    const int ch = t >> 7;
    const int tm = t & 127;
    const int r  = tm >> 2;
    const int c8 = (tm & 3) * 8;

    {
        const u16x8 v = *(const u16x8*)(xp + (size_t)ch * NPIX + r * 32 + c8);
        float* wp = &tile[ch * 1584 + (r + 2) * 44 + c8 + 2];
#pragma unroll
        for (int j = 0; j < 8; j += 2) {
            float2 f2v = make_float2(bf2f(v[j]), bf2f(v[j + 1]));
            *(float2*)(wp + j) = f2v;
        }
    }
    float wk[25];
#pragma unroll
    for (int i = 0; i < 25; i++) wk[i] = wl[ch * 32 + i];
    __syncthreads();

    float acc[8];
#pragma unroll
    for (int j = 0; j < 8; j++) acc[j] = 0.f;

#pragma unroll
    for (int ky = 0; ky < 5; ky++) {
        const float* rp = &tile[ch * 1584 + (r + ky) * 44 + c8];
        const f32x4 a = *(const f32x4*)(rp);
        const f32x4 bq = *(const f32x4*)(rp + 4);
        const f32x4 cq = *(const f32x4*)(rp + 8);
        const float in[12] = {a[0], a[1], a[2], a[3], bq[0], bq[1], bq[2], bq[3],
                              cq[0], cq[1], cq[2], cq[3]};
#pragma unroll
        for (int kx = 0; kx < 5; kx++) {
            const float wv = wk[ky * 5 + kx];
#pragma unroll
            for (int j = 0; j < 8; j++)
                acc[j] = fmaf(in[j + kx], wv, acc[j]);
        }
    }

    u16x8 o8;
#pragma unroll
    for (int j = 0; j < 8; j++) o8[j] = f2bf(acc[j]);
    *(u16x8*)(Y + ((size_t)b * 768 + cbase + ch) * NPIX + r * 32 + c8) = o8;
}

// ---------------------------------------------------------------------------
// Depthwise 3x3 + bias + hswish, blocked bf16 in/out — 2 px x 8 ch per thread,
// direct global reads, no pixel LDS.
// ---------------------------------------------------------------------------
__global__ __launch_bounds__(256)
void dwconv3x3_h2(const unsigned short* __restrict__ X, const float* __restrict__ Wd,
                  const float* __restrict__ bias, unsigned short* __restrict__ Y)
{
    __shared__ float wl[72];
    __shared__ float bb[8];
    const int t    = threadIdx.x;
    const int bid  = blockIdx.x;
    const int half = bid & 1;
    const int coct = (bid >> 1) & 127;
    const int b    = bid >> 8;
    const unsigned short* xp = X + ((size_t)(b * 128 + coct)) * NPIX * 8;
    if (t < 72) wl[t] = Wd[coct * 72 + t];
    if (t < 8)  bb[t] = bias[coct * 8 + t];
    __syncthreads();

    const int px0 = half * 512 + t * 2;   // 2 consecutive pixels
    const int hr  = px0 >> 5;             // image row
    const int c0  = px0 & 31;             // image col (even)

    float acc[8][2];
#pragma unroll
    for (int ch = 0; ch < 8; ch++) {
        acc[ch][0] = bb[ch];
        acc[ch][1] = bb[ch];
    }

#pragma unroll
    for (int ky = 0; ky < 3; ky++) {
        const int rr = hr + ky - 1;
        if (rr >= 0 && rr < 32) {
            u16x8 P[4];
#pragma unroll
            for (int m = 0; m < 4; m++) {
                const int col = c0 - 1 + m;
                const int colc = col < 0 ? 0 : (col > 31 ? 31 : col);
                u16x8 v = *(const u16x8*)(xp + (size_t)(rr * 32 + colc) * 8);
                if (col < 0 || col > 31) v = zero8();
                P[m] = v;
            }
#pragma unroll
            for (int ch = 0; ch < 8; ch++) {
                float g[4];
#pragma unroll
                for (int m = 0; m < 4; m++) g[m] = bf2f(P[m][ch]);
#pragma unroll
                for (int j = 0; j < 2; j++)
#pragma unroll
                    for (int kx = 0; kx < 3; kx++)
                        acc[ch][j] = fmaf(g[j + kx], wl[ch * 9 + ky * 3 + kx], acc[ch][j]);
            }
        }
    }
    unsigned short* yp = Y + ((size_t)(b * 128 + coct)) * NPIX * 8 + (size_t)px0 * 8;
#pragma unroll
    for (int j = 0; j < 2; j++) {
        u16x8 o8;
#pragma unroll
        for (int ch = 0; ch < 8; ch++) {
            float v = acc[ch][j];
            v = v * fminf(fmaxf(v + 3.f, 0.f), 6.f) * (1.f / 6.f);
            o8[ch] = f2bf(v);
        }
        *(u16x8*)(yp + j * 8) = o8;
    }
}

// ---------------------------------------------------------------------------
// Grouped 32->32 1x1 (24 groups), in-place on bf16 [c][n] D.
// ---------------------------------------------------------------------------
__global__ __launch_bounds__(256)
void grouped_pw(unsigned short* __restrict__ D, const float* __restrict__ Wg)
{
    __shared__ float ws[1024];
    const int t     = threadIdx.x;
    const int blk   = blockIdx.x;
    const int chunk = blk & 3;
    const int bg    = blk >> 2;
    const int g     = bg % 24;
    const int b     = bg / 24;
    for (int i = t; i < 1024; i += 256) ws[i] = Wg[g * 1024 + i];
    __syncthreads();
    const int px = chunk * 256 + t;
    unsigned short* dp = D + ((size_t)(b * 768 + g * 32)) * NPIX + px;
    float in[32];
#pragma unroll
    for (int i = 0; i < 32; i++) in[i] = bf2f(dp[(size_t)i * NPIX]);
#pragma unroll
    for (int o = 0; o < 32; o++) {
        float s = 0.f;
#pragma unroll
        for (int i = 0; i < 32; i++) s = fmaf(ws[o * 32 + i], in[i], s);
        dp[(size_t)o * NPIX] = f2bf(s);
    }
}

// ---------------------------------------------------------------------------
// FUSED attention v2: one block per (b,h), 4 waves, no transpose LDS.
// ---------------------------------------------------------------------------
__global__ __launch_bounds__(256)
void attn_fused(const unsigned short* __restrict__ qkv,
                const unsigned short* __restrict__ dpw,
                unsigned short* __restrict__ att)
{
    __shared__ float kvred[4][33 * 33];
    __shared__ float kvs[1056];

    const int t    = threadIdx.x;
    const int lane = t & 63;
    const int w    = t >> 6;
    const int bh   = blockIdx.x;
    const int b    = bh >> 4;
    const int h    = bh & 15;

    const unsigned short* base = (h < 8)
        ? qkv + ((size_t)(b * 768 + h * 96)) * NPIX
        : dpw + ((size_t)(b * 768 + (h - 8) * 96)) * NPIX;
    const unsigned short* qp = base;
    const unsigned short* kp = base + 32 * NPIX;
    const unsigned short* vp = base + 64 * NPIX;

    const int l16 = lane & 15;
    const int lq  = lane >> 4;
    const int ko  = lq * 8;
    const int nb  = w * 256;

    // phase 1: kv partials
    {
        f32x4 acc[3][2];
#pragma unroll
        for (int i = 0; i < 3; i++)
#pragma unroll
            for (int j = 0; j < 2; j++) {
                f32x4 z = {0.f, 0.f, 0.f, 0.f};
                acc[i][j] = z;
            }
        bf16x8 ones;
#pragma unroll
        for (int j = 0; j < 8; j++) ones[j] = (l16 == 0) ? (short)0x3F80 : (short)0;

#pragma unroll
        for (int s = 0; s < 8; s++) {
            const int n0 = nb + s * 32 + ko;
            const bf16x8 av0 = *(const bf16x8*)(vp + (size_t)l16 * NPIX + n0);
            const bf16x8 av1 = *(const bf16x8*)(vp + (size_t)(16 + l16) * NPIX + n0);
            const u16x8 k0 = *(const u16x8*)(kp + (size_t)l16 * NPIX + n0);
            const u16x8 k1 = *(const u16x8*)(kp + (size_t)(16 + l16) * NPIX + n0);
            bf16x8 bk0, bk1;
#pragma unroll
            for (int j = 0; j < 8; j++) {
                bk0[j] = (k0[j] & 0x8000u) ? (short)0 : (short)k0[j];
                bk1[j] = (k1[j] & 0x8000u) ? (short)0 : (short)k1[j];
            }
            acc[0][0] = __builtin_amdgcn_mfma_f32_16x16x32_bf16(av0,  bk0, acc[0][0], 0, 0, 0);
            acc[0][1] = __builtin_amdgcn_mfma_f32_16x16x32_bf16(av0,  bk1, acc[0][1], 0, 0, 0);
            acc[1][0] = __builtin_amdgcn_mfma_f32_16x16x32_bf16(av1,  bk0, acc[1][0], 0, 0, 0);
            acc[1][1] = __builtin_amdgcn_mfma_f32_16x16x32_bf16(av1,  bk1, acc[1][1], 0, 0, 0);
            acc[2][0] = __builtin_amdgcn_mfma_f32_16x16x32_bf16(ones, bk0, acc[2][0], 0, 0, 0);
            acc[2][1] = __builtin_amdgcn_mfma_f32_16x16x32_bf16(ones, bk1, acc[2][1], 0, 0, 0);
        }
        const int rbase = lq * 4;
#pragma unroll
        for (int dt = 0; dt < 2; dt++)
#pragma unroll
            for (int et = 0; et < 2; et++)
#pragma unroll
                for (int r = 0; r < 4; r++)
                    kvred[w][(dt * 16 + rbase + r) * 33 + et * 16 + l16] = acc[dt][et][r];
        if (rbase == 0) {
#pragma unroll
            for (int et = 0; et < 2; et++)
                kvred[w][32 * 33 + et * 16 + l16] = acc[2][et][0];
        }
    }
    __syncthreads();
#pragma unroll
    for (int k = 0; k < 5; k++) {
        const int idx = t + k * 256;
        if (idx < 1056) {
            const int a = (idx >> 5) * 33 + (idx & 31);
            kvs[idx] = kvred[0][a] + kvred[1][a] + kvred[2][a] + kvred[3][a];
        }
    }
    __syncthreads();

    // phase 2: out = kv · relu(Q), K=32; output straight from regs.
    bf16x8 a0, a1, a2;
#pragma unroll
    for (int j = 0; j < 8; j++) {
        a0[j] = (short)f2bf(kvs[l16 * 32 + ko + j]);
        a1[j] = (short)f2bf(kvs[(16 + l16) * 32 + ko + j]);
        a2[j] = (l16 == 0) ? (short)f2bf(kvs[32 * 32 + ko + j]) : (short)0;
    }
    bf16x8 bfr[16];
    const unsigned short* qb = qp + (size_t)ko * NPIX + nb + l16;
#pragma unroll
    for (int tl = 0; tl < 16; tl++) {
        bf16x8 bf;
#pragma unroll
        for (int j = 0; j < 8; j++) {
            const unsigned short v = qb[(size_t)j * NPIX + tl * 16];
            bf[j] = (v & 0x8000u) ? (short)0 : (short)v;
        }
        bfr[tl] = bf;
    }

    const int db0 = lq >> 1;
    const int sub = (lq & 1) * 4;
    unsigned short* ab0 = att + (((size_t)(b * 64 + h * 4 + db0)) * NPIX) * 8 + sub;
    unsigned short* ab1 = att + (((size_t)(b * 64 + h * 4 + 2 + db0)) * NPIX) * 8 + sub;

#pragma unroll
    for (int tl = 0; tl < 16; tl++) {
        f32x4 z = {0.f, 0.f, 0.f, 0.f};
        z = __builtin_amdgcn_mfma_f32_16x16x32_bf16(a2, bfr[tl], z, 0, 0, 0);
        const float den = __shfl(z[0], l16, 64);     // den(col l16) from lane l16
        const float inv = 1.f / (den + 1e-15f);
        f32x4 c0 = {0.f, 0.f, 0.f, 0.f};
        f32x4 c1 = {0.f, 0.f, 0.f, 0.f};
        c0 = __builtin_amdgcn_mfma_f32_16x16x32_bf16(a0, bfr[tl], c0, 0, 0, 0);
        c1 = __builtin_amdgcn_mfma_f32_16x16x32_bf16(a1, bfr[tl], c1, 0, 0, 0);
        u16x4 p0, p1;
#pragma unroll
        for (int r = 0; r < 4; r++) {
            p0[r] = f2bf(c0[r] * inv);
            p1[r] = f2bf(c1[r] * inv);
        }
        const size_t n8 = (size_t)(nb + tl * 16 + l16) * 8;
        *(u16x4*)(ab0 + n8) = p0;
        *(u16x4*)(ab1 + n8) = p1;
    }
}

// ---------------------------------------------------------------------------
extern "C" void kernel_launch(void* const* d_in, const int* in_sizes, int n_in,
                              void* d_out, int out_size, void* d_ws, size_t ws_size,
                              hipStream_t stream)
{
    (void)in_sizes; (void)n_in; (void)out_size;

    const float* x      = (const float*)d_in[0];
    const float* y      = (const float*)d_in[1];
    const float* qkv_w  = (const float*)d_in[2];
    const float* dw5_w  = (const float*)d_in[3];
    const float* pwg_w  = (const float*)d_in[4];
    const float* proj_w = (const float*)d_in[5];
    const float* proj_g = (const float*)d_in[6];
    const float* proj_b = (const float*)d_in[7];
    const float* proj_m = (const float*)d_in[8];
    const float* proj_v = (const float*)d_in[9];
    const float* inv_w  = (const float*)d_in[10];
    const float* inv_b  = (const float*)d_in[11];
    const float* dwc_w  = (const float*)d_in[12];
    const float* dwc_b  = (const float*)d_in[13];
    const float* pw_w   = (const float*)d_in[14];
    const float* pw_g   = (const float*)d_in[15];
    const float* pw_b   = (const float*)d_in[16];
    const float* pw_m   = (const float*)d_in[17];
    const float* pw_v   = (const float*)d_in[18];

    float* ws = (float*)d_ws;
    unsigned short* wqkv_b  = (unsigned short*)(ws + WQKV_OFF);
    unsigned short* wproj_b = (unsigned short*)(ws + WPROJ_OFF);
    unsigned short* winv_b  = (unsigned short*)(ws + WINV_OFF);
    unsigned short* wpw_b   = (unsigned short*)(ws + WPW_OFF);
    float* out = (float*)d_out;

    wconv_all<<<dim3(416), 256, 0, stream>>>(qkv_w, proj_w, inv_w, pw_w,
                                             wqkv_b, wproj_b, winv_b, wpw_b);

    if (ws_size >= (size_t)BATCH_NEED_F * 4ull) {
        // ---------------- batched path: both chains as images 0..31 ----------
        unsigned short* bxt  = (unsigned short*)(ws + BXT_OFF);
        unsigned short* bqkv = (unsigned short*)(ws + BQKV_OFF);
        unsigned short* bdpw = (unsigned short*)(ws + BDPW_OFF);
        unsigned short* batt = (unsigned short*)(ws + BATT_OFF);
        unsigned short* bt1t = (unsigned short*)(ws + BT1T_OFF);
        unsigned short* bh1t = (unsigned short*)(ws + BH1T_OFF);
        unsigned short* bh2t = (unsigned short*)(ws + BH2T_OFF);

        xpose2<<<dim3(4096), 256, 0, stream>>>(x, y, bxt, 256);
        gemm_direct<128, 128, 0, false, 1><<<dim3(6, 256), 256, 0, stream>>>(
            bxt, nullptr, wqkv_b, nullptr, bqkv, 768, 256,
            nullptr, nullptr, nullptr, nullptr, nullptr, nullptr, nullptr, nullptr);
        dwconv5x5_v3<<<dim3(12288), 256, 0, stream>>>(bqkv, dw5_w, bdpw);
        grouped_pw<<<dim3(3072), 256, 0, stream>>>(bdpw, pwg_w);
        attn_fused<<<dim3(512), 256, 0, stream>>>(bqkv, bdpw, batt);
        gemm_direct<64, 64, 1, false, 2><<<dim3(4, 512), 256, 0, stream>>>(
            batt, nullptr, wproj_b, nullptr, bt1t, 256, 512,
            x, y, nullptr, proj_g, proj_b, proj_m, proj_v, nullptr);
        gemm_direct<128, 128, 2, false, 2><<<dim3(8, 256), 256, 0, stream>>>(
            bt1t, nullptr, winv_b, nullptr, bh1t, 1024, 256,
            nullptr, nullptr, nullptr, nullptr, nullptr, nullptr, nullptr, inv_b);
        dwconv3x3_h2<<<dim3(8192), 256, 0, stream>>>(bh1t, dwc_w, dwc_b, bh2t);
        gemm_direct<64, 64, 3, false, 0><<<dim3(4, 256), 256, 0, stream>>>(
            bh2t, bh2t + (size_t)16 * 1024 * 1024, wpw_b, out, nullptr, 256, 1024,
            nullptr, nullptr, bt1t, pw_g, pw_b, pw_m, pw_v, nullptr);
    } else {
        // ---------------- fallback: per-chain (R14 structure) ----------------
        unsigned short* wxt  = (unsigned short*)(ws + XT_OFF);
        unsigned short* wqkv = (unsigned short*)(ws + QKV_OFF);
        unsigned short* wdpw = (unsigned short*)(ws + DPW_OFF);
        unsigned short* watt = (unsigned short*)(ws + ATT_OFF);
        float*          wt1  = ws + T1_OFF;
        unsigned short* wt1t = (unsigned short*)(ws + T1T_OFF);
        unsigned short* wh1t = (unsigned short*)(ws + H1T_OFF);
        unsigned short* wh2t = (unsigned short*)(ws + H2T_OFF);

        for (int blk = 0; blk < 2; blk++) {
            const float* t = (blk == 0) ? x : y;
            xpose2<<<dim3(2048), 256, 0, stream>>>(t, t, wxt, 256);
            gemm_direct<128, 128, 0, false, 1><<<dim3(6, 128), 256, 0, stream>>>(
                wxt, nullptr, wqkv_b, nullptr, wqkv, 768, 256,
                nullptr, nullptr, nullptr, nullptr, nullptr, nullptr, nullptr, nullptr);
            dwconv5x5_v3<<<dim3(6144), 256, 0, stream>>>(wqkv, dw5_w, wdpw);
            grouped_pw<<<dim3(1536), 256, 0, stream>>>(wdpw, pwg_w);
            attn_fused<<<dim3(256), 256, 0, stream>>>(wqkv, wdpw, watt);
            gemm_direct<64, 64, 1, false, 3><<<dim3(4, 256), 256, 0, stream>>>(
                watt, watt, wproj_b, wt1, wt1t, 256, 512,
                t, t, nullptr, proj_g, proj_b, proj_m, proj_v, nullptr);
            gemm_direct<128, 128, 2, false, 2><<<dim3(8, 128), 256, 0, stream>>>(
                wt1t, nullptr, winv_b, nullptr, wh1t, 1024, 256,
                nullptr, nullptr, nullptr, nullptr, nullptr, nullptr, nullptr, inv_b);
            dwconv3x3_h2<<<dim3(4096), 256, 0, stream>>>(wh1t, dwc_w, dwc_b, wh2t);
            if (blk == 0) {
                gemm_direct<64, 64, 1, false, 0><<<dim3(4, 256), 256, 0, stream>>>(
                    wh2t, nullptr, wpw_b, out, nullptr, 256, 1024,
                    wt1, wt1, nullptr, pw_g, pw_b, pw_m, pw_v, nullptr);
            } else {
                gemm_direct<64, 64, 1, true, 0><<<dim3(4, 256), 256, 0, stream>>>(
                    wh2t, nullptr, wpw_b, out, nullptr, 256, 1024,
                    wt1, wt1, nullptr, pw_g, pw_b, pw_m, pw_v, nullptr);
            }
        }
    }
}

// Round 21
// 234.872 us; speedup vs baseline: 1.1337x; 1.0572x over previous
//
#include <hip/hip_runtime.h>
#include <cstddef>

#define NPIX 1024   // H*W = 32*32

// ---------------------------------------------------------------------------
// Workspace layouts (float-slot offsets).
// BATCHED (both residual chains as images 0..31): peak 38,174,720 floats.
// FALLBACK (per-chain, R14 layout): peak 34,045,952 floats.
// ---------------------------------------------------------------------------
static constexpr size_t WQKV_OFF  = 0;
static constexpr size_t WPROJ_OFF = 98304;
static constexpr size_t WINV_OFF  = 163840;
static constexpr size_t WPW_OFF   = 294912;
// batched
static constexpr size_t BXT_OFF   = 425984;
static constexpr size_t BQKV_OFF  = 4620288;
static constexpr size_t BDPW_OFF  = 17203200;
static constexpr size_t BATT_OFF  = 29786112;
static constexpr size_t BT1T_OFF  = 425984;     // alias XT32
static constexpr size_t BH1T_OFF  = 4620288;    // alias QKV32..
static constexpr size_t BH2T_OFF  = 21397504;   // alias DPW-tail+ATT
static constexpr size_t BATCH_NEED_F = 38174720;
// fallback (R14)
static constexpr size_t XT_OFF    = 425984;
static constexpr size_t QKV_OFF   = 2523136;
static constexpr size_t DPW_OFF   = 8814592;
static constexpr size_t ATT_OFF   = 15106048;
static constexpr size_t T1_OFF    = 21463040;
static constexpr size_t T1T_OFF   = 25657344;
static constexpr size_t H1T_OFF   = 425984;
static constexpr size_t H2T_OFF   = 25657344;

typedef __attribute__((ext_vector_type(8))) short bf16x8;
typedef __attribute__((ext_vector_type(8))) unsigned short u16x8;
typedef __attribute__((ext_vector_type(4))) unsigned short u16x4;
typedef __attribute__((ext_vector_type(4))) float f32x4;

__device__ inline unsigned short f2bf(float f) {
    union { float f; unsigned int u; } v; v.f = f;
    unsigned int u = v.u;
    u += 0x7FFFu + ((u >> 16) & 1u);        // round-to-nearest-even
    return (unsigned short)(u >> 16);
}
__device__ inline float bf2f(unsigned short u) {
    union { float f; unsigned int u; } v; v.u = ((unsigned int)u) << 16;
    return v.f;
}
__device__ inline u16x8 zero8() {
    u16x8 z = {0, 0, 0, 0, 0, 0, 0, 0};
    return z;
}

// ---------------------------------------------------------------------------
// Weight convert (all 4 weights in ONE launch): fp32 [O][K] -> bf16 [K/8][O][8]
// ---------------------------------------------------------------------------
__global__ __launch_bounds__(256)
void wconv_all(const float* __restrict__ w0, const float* __restrict__ w1,
               const float* __restrict__ w2, const float* __restrict__ w3,
               unsigned short* __restrict__ d0, unsigned short* __restrict__ d1,
               unsigned short* __restrict__ d2, unsigned short* __restrict__ d3)
{
    const int bid = blockIdx.x;
    const float* W; unsigned short* WB; int O, K, base;
    if (bid < 96)       { W = w0; WB = d0; O = 768;  K = 256;  base = 0;   }
    else if (bid < 160) { W = w1; WB = d1; O = 256;  K = 512;  base = 96;  }
    else if (bid < 288) { W = w2; WB = d2; O = 1024; K = 256;  base = 160; }
    else                { W = w3; WB = d3; O = 256;  K = 1024; base = 288; }
    const int idx = (bid - base) * 256 + threadIdx.x;
    if (idx >= O * (K >> 3)) return;
    const int o = idx % O;
    const int koct = idx / O;
    u16x8 v;
#pragma unroll
    for (int j = 0; j < 8; j++) v[j] = f2bf(W[(size_t)o * K + koct * 8 + j]);
    *(u16x8*)(WB + ((size_t)koct * O + o) * 8) = v;
}

// ---------------------------------------------------------------------------
// Transpose, dual-source: image ib<16 from X0, else X1.
// ---------------------------------------------------------------------------
__global__ __launch_bounds__(256)
void xpose2(const float* __restrict__ X0, const float* __restrict__ X1,
            unsigned short* __restrict__ XT, const int C)
{
    __shared__ float tt[8][260];
    const int t = threadIdx.x;
    const int octs = C >> 3;
    const int strips = octs * 4;
    const int ib = blockIdx.x / strips;
    const int rem = blockIdx.x - ib * strips;
    const int coct = rem >> 2;
    const int n0 = (rem & 3) * 256;
    const float* src = (ib < 16) ? X0 + (size_t)ib * C * NPIX
                                 : X1 + (size_t)(ib - 16) * C * NPIX;
    const int cc = t >> 5;
    const int c8 = (t & 31) * 8;
    const float* xp = src + ((size_t)(coct * 8 + cc)) * NPIX + n0 + c8;
    *(float4*)(&tt[cc][c8])     = *(const float4*)(xp);
    *(float4*)(&tt[cc][c8 + 4]) = *(const float4*)(xp + 4);
    __syncthreads();
    u16x8 v;
#pragma unroll
    for (int j = 0; j < 8; j++) v[j] = f2bf(tt[j][t]);
    *(u16x8*)(XT + (((size_t)ib * octs + coct) * NPIX + n0 + t) * 8) = v;
}

// ---------------------------------------------------------------------------
// MFMA GEMM, DIRECT global->VGPR fragments, 4-DEEP register pipeline.
// Operands blocked bf16 [K/8][rows][8].  K/8 multiple of 16.
// EPI: 0 plain; 1 BN + fp32 residual; 2 bias+hswish; 3 DUAL interleaved
//      second K-stream X2 into acc2 (shared A), BN+2*shift+bf16 residuals.
// OMODE: 0 fp32 [c][n] (+ACC); 1 bf16 [c][n]; 2 blocked bf16; 3 fp32+blocked.
// ---------------------------------------------------------------------------
template<int BM, int BN, int EPI, bool ACC, int OMODE>
__global__ __launch_bounds__(256)
void gemm_direct(const unsigned short* __restrict__ X, const unsigned short* __restrict__ X2,
                 const unsigned short* __restrict__ W,
                 float* __restrict__ Y, unsigned short* __restrict__ YB,
                 const int O, const int K,
                 const float* __restrict__ res, const float* __restrict__ res2,
                 const unsigned short* __restrict__ resb,
                 const float* __restrict__ bng, const float* __restrict__ bnb,
                 const float* __restrict__ bnm, const float* __restrict__ bnv,
                 const float* __restrict__ bias)
{
    constexpr int TN = NPIX / BN;
    constexpr int WAVES_N = (BN >= 128) ? 2 : 1;
    constexpr int WM = BM / (4 / WAVES_N);
    constexpr int MI = WM / 16;
    constexpr int NJ = 4;
    constexpr int TSTR = (OMODE == 1) ? (BN + 8) : (BM + 8);
    constexpr int TSZ  = (OMODE == 1) ? BM * TSTR : ((OMODE >= 2) ? BN * TSTR : 64);
    __shared__ unsigned short T[TSZ];

    const int t    = threadIdx.x;
    const int lane = t & 63;
    const int w    = t >> 6;

    // XCD-bijective block swizzle (all grids are multiples of 8)
    const int gx  = gridDim.x;
    const int nwg = gx * gridDim.y;
    int bid = blockIdx.y * gx + blockIdx.x;
    bid = (bid & 7) * (nwg >> 3) + (bid >> 3);
    const int bx = bid % gx;
    const int by = bid / gx;

    const int o0 = bx * BM;
    const int b  = by / TN;
    const int n0 = (by % TN) * BN;

    const int wn = (WAVES_N == 2) ? (w & 1) * 64 : 0;
    const int wo = (WAVES_N == 2) ? (w >> 1) * WM : w * WM;

    const int l16 = lane & 15;
    const int lq  = lane >> 4;

    f32x4 acc[MI][NJ];
    f32x4 acc2[MI][NJ];
#pragma unroll
    for (int i = 0; i < MI; i++)
#pragma unroll
        for (int j = 0; j < NJ; j++) {
            f32x4 z = {0.f, 0.f, 0.f, 0.f};
            acc[i][j] = z;
            acc2[i][j] = z;
        }

    const unsigned short* Ab = W + ((size_t)lq * O + o0 + wo + l16) * 8;
    const size_t strideA = (size_t)O * 8;
    const size_t strideB = (size_t)NPIX * 8;
    const size_t boff = ((size_t)lq * NPIX + n0 + wn + l16) * 8;
    const int octs = K >> 3;                    // multiple of 16

    auto ldA_ = [&](bf16x8* fr, int kb) {
#pragma unroll
        for (int i = 0; i < MI; i++)
            fr[i] = *(const bf16x8*)(Ab + (size_t)kb * strideA + i * 128);
    };
    auto ldB_ = [&](bf16x8* fr, const unsigned short* Bb, int kb) {
#pragma unroll
        for (int j = 0; j < NJ; j++)
            fr[j] = *(const bf16x8*)(Bb + (size_t)kb * strideB + j * 128);
    };
    auto domfma_ = [&](f32x4 (&ac)[MI][NJ], bf16x8* af, bf16x8* bf) {
#pragma unroll
        for (int i = 0; i < MI; i++)
#pragma unroll
            for (int j = 0; j < NJ; j++)
                ac[i][j] = __builtin_amdgcn_mfma_f32_16x16x32_bf16(
                    af[i], bf[j], ac[i][j], 0, 0, 0);
    };

    if (EPI != 3) {
        const unsigned short* Bb = X + (size_t)b * K * NPIX + boff;
        bf16x8 a0[MI], b0[NJ], a1[MI], b1[NJ], a2s[MI], b2[NJ], a3[MI], b3[NJ];
        ldA_(a0, 0);  ldB_(b0, Bb, 0);
        ldA_(a1, 4);  ldB_(b1, Bb, 4);
        ldA_(a2s, 8); ldB_(b2, Bb, 8);
        ldA_(a3, 12); ldB_(b3, Bb, 12);
        for (int kb = 0; kb < octs; kb += 16) {
            domfma_(acc, a0, b0);
            if (kb + 16 < octs) { ldA_(a0, kb + 16); ldB_(b0, Bb, kb + 16); }
            domfma_(acc, a1, b1);
            if (kb + 20 < octs) { ldA_(a1, kb + 20); ldB_(b1, Bb, kb + 20); }
            domfma_(acc, a2s, b2);
            if (kb + 24 < octs) { ldA_(a2s, kb + 24); ldB_(b2, Bb, kb + 24); }
            domfma_(acc, a3, b3);
            if (kb + 28 < octs) { ldA_(a3, kb + 28); ldB_(b3, Bb, kb + 28); }
        }
    } else {
        // interleaved dual stream, shared A, 4-deep
        const unsigned short* B1 = X  + (size_t)b * K * NPIX + boff;
        const unsigned short* B2 = X2 + (size_t)b * K * NPIX + boff;
        bf16x8 a0[MI], a1[MI], a2s[MI], a3[MI];
        bf16x8 p0[NJ], p1[NJ], p2[NJ], p3[NJ];
        bf16x8 q0[NJ], q1[NJ], q2[NJ], q3[NJ];
        ldA_(a0, 0);  ldB_(p0, B1, 0);  ldB_(q0, B2, 0);
        ldA_(a1, 4);  ldB_(p1, B1, 4);  ldB_(q1, B2, 4);
        ldA_(a2s, 8); ldB_(p2, B1, 8);  ldB_(q2, B2, 8);
        ldA_(a3, 12); ldB_(p3, B1, 12); ldB_(q3, B2, 12);
        for (int kb = 0; kb < octs; kb += 16) {
            domfma_(acc,  a0, p0);
            domfma_(acc2, a0, q0);
            if (kb + 16 < octs) { ldA_(a0, kb + 16); ldB_(p0, B1, kb + 16); ldB_(q0, B2, kb + 16); }
            domfma_(acc,  a1, p1);
            domfma_(acc2, a1, q1);
            if (kb + 20 < octs) { ldA_(a1, kb + 20); ldB_(p1, B1, kb + 20); ldB_(q1, B2, kb + 20); }
            domfma_(acc,  a2s, p2);
            domfma_(acc2, a2s, q2);
            if (kb + 24 < octs) { ldA_(a2s, kb + 24); ldB_(p2, B1, kb + 24); ldB_(q2, B2, kb + 24); }
            domfma_(acc,  a3, p3);
            domfma_(acc2, a3, q3);
            if (kb + 28 < octs) { ldA_(a3, kb + 28); ldB_(p3, B1, kb + 28); ldB_(q3, B2, kb + 28); }
        }
    }

    // epilogue. C/D: col = lane&15 (n), row = (lane>>4)*4 + reg (o)
    const int r0q = lq * 4;
    float scale[MI][4], shift[MI][4];
    if (EPI == 1 || EPI == 3) {
#pragma unroll
        for (int i = 0; i < MI; i++)
#pragma unroll
            for (int r = 0; r < 4; r++) {
                const int o = o0 + wo + i * 16 + r0q + r;
                const float inv = bng[o] / sqrtf(bnv[o] + 1e-5f);
                scale[i][r] = inv;
                shift[i][r] = bnb[o] - bnm[o] * inv;
            }
    } else if (EPI == 2) {
#pragma unroll
        for (int i = 0; i < MI; i++)
#pragma unroll
            for (int r = 0; r < 4; r++)
                shift[i][r] = bias[o0 + wo + i * 16 + r0q + r];
    }

#pragma unroll
    for (int i = 0; i < MI; i++) {
#pragma unroll
        for (int j = 0; j < NJ; j++) {
            const int nn = n0 + wn + j * 16 + l16;
            const int nl = wn + j * 16 + l16;
            const int ob = wo + i * 16 + r0q;
            const size_t base = ((size_t)b * O + o0 + ob) * NPIX + nn;
            u16x4 r1v, r2v;
            if (EPI == 3) {
                const size_t ro = (((size_t)(b * 32 + ((o0 + ob) >> 3)) * NPIX + nn) * 8
                                   + ((o0 + ob) & 7));
                r1v = *(const u16x4*)(resb + ro);
                r2v = *(const u16x4*)(resb + (size_t)16 * 262144 + ro);
            }
            u16x4 p4;
#pragma unroll
            for (int r = 0; r < 4; r++) {
                const size_t off = base + (size_t)r * NPIX;
                float v = acc[i][j][r];
                if (EPI == 1) {
                    const float* rs = (b < 16) ? res : res2;
                    const size_t roff = ((size_t)(b & 15) * O + o0 + ob + r) * NPIX + nn;
                    v = v * scale[i][r] + shift[i][r] + rs[roff];
                } else if (EPI == 2) {
                    v += shift[i][r];
                    v = v * fminf(fmaxf(v + 3.f, 0.f), 6.f) * (1.f / 6.f);
                } else if (EPI == 3) {
                    v = (v + acc2[i][j][r]) * scale[i][r] + 2.f * shift[i][r]
                        + bf2f(r1v[r]) + bf2f(r2v[r]);
                }
                if (OMODE == 0 || OMODE == 3) {
                    if (ACC) v += Y[off];
                    Y[off] = v;
                }
                if (OMODE == 1) {
                    T[(size_t)(ob + r) * TSTR + nl] = f2bf(v);
                } else if (OMODE >= 2) {
                    p4[r] = f2bf(v);
                }
            }
            if (OMODE >= 2)
                *(u16x4*)(T + (size_t)nl * TSTR + ob) = p4;
        }
    }

    if (OMODE >= 1) {
        __syncthreads();
        constexpr int CNT = BM * BN / 2048;
        if (OMODE == 1) {
#pragma unroll
            for (int k = 0; k < CNT; k++) {
                const int idx = t + k * 256;
                const int o   = idx / (BN / 8);
                const int n8  = (idx % (BN / 8)) * 8;
                const u16x8 v = *(const u16x8*)(T + (size_t)o * TSTR + n8);
                *(u16x8*)(YB + ((size_t)b * O + o0 + o) * NPIX + n0 + n8) = v;
            }
        } else {
#pragma unroll
            for (int k = 0; k < CNT; k++) {
                const int idx = t + k * 256;
                const int oo  = idx / BN;
                const int nn  = idx % BN;
                const u16x8 v = *(const u16x8*)(T + (size_t)nn * TSTR + oo * 8);
                *(u16x8*)(YB + (((size_t)b * (O >> 3) + (o0 >> 3) + oo) * NPIX + n0 + nn) * 8) = v;
            }
        }
    }
}

// ---------------------------------------------------------------------------
// Depthwise 5x5 SAME, bf16 [c][n] in/out. 2 channels/block, stride-44 fp32 LDS.
// ---------------------------------------------------------------------------
__global__ __launch_bounds__(256)
void dwconv5x5_v3(const unsigned short* __restrict__ X, const float* __restrict__ Wd,
                  unsigned short* __restrict__ Y)
{
    __shared__ float tile[2 * 36 * 44];
    __shared__ float wl[64];
    const int t     = threadIdx.x;
    const int cpair = blockIdx.x % 384;
    const int b     = blockIdx.x / 384;
    const int cbase = cpair * 2;
    const unsigned short* xp = X + ((size_t)b * 768 + cbase) * NPIX;

#pragma unroll
    for (int k = 0; k < 4; k++) {
        const int i = t + k * 256;
        if (i < 792) {
            f32x4 z = {0.f, 0.f, 0.f, 0.f};
            *(f32x4*)(&tile[i * 4]) = z;
        }
    }
    if (t < 50) wl[(t / 25) * 32 + (t % 25)] = Wd[cbase * 25 + t];
    __syncthreads();

    const int ch = t >> 7;
    const int tm = t & 127;
    const int r  = tm >> 2;
    const int c8 = (tm & 3) * 8;

    {
        const u16x8 v = *(const u16x8*)(xp + (size_t)ch * NPIX + r * 32 + c8);
        float* wp = &tile[ch * 1584 + (r + 2) * 44 + c8 + 2];
#pragma unroll
        for (int j = 0; j < 8; j += 2) {
            float2 f2v = make_float2(bf2f(v[j]), bf2f(v[j + 1]));
            *(float2*)(wp + j) = f2v;
        }
    }
    float wk[25];
#pragma unroll
    for (int i = 0; i < 25; i++) wk[i] = wl[ch * 32 + i];
    __syncthreads();

    float acc[8];
#pragma unroll
    for (int j = 0; j < 8; j++) acc[j] = 0.f;

#pragma unroll
    for (int ky = 0; ky < 5; ky++) {
        const float* rp = &tile[ch * 1584 + (r + ky) * 44 + c8];
        const f32x4 a = *(const f32x4*)(rp);
        const f32x4 bq = *(const f32x4*)(rp + 4);
        const f32x4 cq = *(const f32x4*)(rp + 8);
        const float in[12] = {a[0], a[1], a[2], a[3], bq[0], bq[1], bq[2], bq[3],
                              cq[0], cq[1], cq[2], cq[3]};
#pragma unroll
        for (int kx = 0; kx < 5; kx++) {
            const float wv = wk[ky * 5 + kx];
#pragma unroll
            for (int j = 0; j < 8; j++)
                acc[j] = fmaf(in[j + kx], wv, acc[j]);
        }
    }

    u16x8 o8;
#pragma unroll
    for (int j = 0; j < 8; j++) o8[j] = f2bf(acc[j]);
    *(u16x8*)(Y + ((size_t)b * 768 + cbase + ch) * NPIX + r * 32 + c8) = o8;
}

// ---------------------------------------------------------------------------
// Depthwise 3x3 + bias + hswish, blocked bf16 in/out — 2 px x 8 ch per thread,
// direct global reads, no pixel LDS.
// ---------------------------------------------------------------------------
__global__ __launch_bounds__(256)
void dwconv3x3_h2(const unsigned short* __restrict__ X, const float* __restrict__ Wd,
                  const float* __restrict__ bias, unsigned short* __restrict__ Y)
{
    __shared__ float wl[72];
    __shared__ float bb[8];
    const int t    = threadIdx.x;
    const int bid  = blockIdx.x;
    const int half = bid & 1;
    const int coct = (bid >> 1) & 127;
    const int b    = bid >> 8;
    const unsigned short* xp = X + ((size_t)(b * 128 + coct)) * NPIX * 8;
    if (t < 72) wl[t] = Wd[coct * 72 + t];
    if (t < 8)  bb[t] = bias[coct * 8 + t];
    __syncthreads();

    const int px0 = half * 512 + t * 2;   // 2 consecutive pixels
    const int hr  = px0 >> 5;             // image row
    const int c0  = px0 & 31;             // image col (even)

    float acc[8][2];
#pragma unroll
    for (int ch = 0; ch < 8; ch++) {
        acc[ch][0] = bb[ch];
        acc[ch][1] = bb[ch];
    }

#pragma unroll
    for (int ky = 0; ky < 3; ky++) {
        const int rr = hr + ky - 1;
        if (rr >= 0 && rr < 32) {
            u16x8 P[4];
#pragma unroll
            for (int m = 0; m < 4; m++) {
                const int col = c0 - 1 + m;
                const int colc = col < 0 ? 0 : (col > 31 ? 31 : col);
                u16x8 v = *(const u16x8*)(xp + (size_t)(rr * 32 + colc) * 8);
                if (col < 0 || col > 31) v = zero8();
                P[m] = v;
            }
#pragma unroll
            for (int ch = 0; ch < 8; ch++) {
                float g[4];
#pragma unroll
                for (int m = 0; m < 4; m++) g[m] = bf2f(P[m][ch]);
#pragma unroll
                for (int j = 0; j < 2; j++)
#pragma unroll
                    for (int kx = 0; kx < 3; kx++)
                        acc[ch][j] = fmaf(g[j + kx], wl[ch * 9 + ky * 3 + kx], acc[ch][j]);
            }
        }
    }
    unsigned short* yp = Y + ((size_t)(b * 128 + coct)) * NPIX * 8 + (size_t)px0 * 8;
#pragma unroll
    for (int j = 0; j < 2; j++) {
        u16x8 o8;
#pragma unroll
        for (int ch = 0; ch < 8; ch++) {
            float v = acc[ch][j];
            v = v * fminf(fmaxf(v + 3.f, 0.f), 6.f) * (1.f / 6.f);
            o8[ch] = f2bf(v);
        }
        *(u16x8*)(yp + j * 8) = o8;
    }
}

// ---------------------------------------------------------------------------
// Grouped 32->32 1x1 via MFMA: one block per (b,g), 4 waves x 256-px chunks.
// out[o][n] = sum_i W[g][o][i] * in[i][n], K=32 (one MFMA k-step).
// A-frags converted in-register from fp32 weights (i contiguous);
// B-frags: scalar strided u16 loads (all loaded BEFORE stores -> in-place
// safe; wave-exclusive pixel chunks). 32 MFMAs/wave replace 1024 VALU
// FMAs/thread of the old kernel. C/D: col=lane&15 (n), row=lq*4+r (o).
// ---------------------------------------------------------------------------
__global__ __launch_bounds__(256)
void grouped_mfma(unsigned short* __restrict__ D, const float* __restrict__ Wg)
{
    const int t    = threadIdx.x;
    const int lane = t & 63;
    const int w    = t >> 6;
    const int bg   = blockIdx.x;          // b*24 + g
    const int g    = bg % 24;
    const int b    = bg / 24;
    const int l16  = lane & 15;
    const int lq   = lane >> 4;
    const int ko   = lq * 8;              // i-oct within K=32
    const int nb   = w * 256;

    unsigned short* dp = D + ((size_t)(b * 768 + g * 32)) * NPIX;

    // A-frags from fp32 weights: a0 -> o = l16, a1 -> o = 16+l16 (i contiguous)
    bf16x8 a0, a1;
#pragma unroll
    for (int j = 0; j < 8; j++) {
        a0[j] = (short)f2bf(Wg[g * 1024 + l16 * 32 + ko + j]);
        a1[j] = (short)f2bf(Wg[g * 1024 + (16 + l16) * 32 + ko + j]);
    }

    // B-frags: 16 n-tiles of 16 px; lane (lq,l16): b[j] = in[ko+j][nb+tl*16+l16]
    bf16x8 bfr[16];
    const unsigned short* ib = dp + (size_t)ko * NPIX + nb + l16;
#pragma unroll
    for (int tl = 0; tl < 16; tl++) {
        bf16x8 bf;
#pragma unroll
        for (int j = 0; j < 8; j++)
            bf[j] = (short)ib[(size_t)j * NPIX + tl * 16];
        bfr[tl] = bf;
    }

    // compute + store (all reads above complete before any write)
    const int ro = lq * 4;
#pragma unroll
    for (int tl = 0; tl < 16; tl++) {
        f32x4 c0 = {0.f, 0.f, 0.f, 0.f};
        f32x4 c1 = {0.f, 0.f, 0.f, 0.f};
        c0 = __builtin_amdgcn_mfma_f32_16x16x32_bf16(a0, bfr[tl], c0, 0, 0, 0);
        c1 = __builtin_amdgcn_mfma_f32_16x16x32_bf16(a1, bfr[tl], c1, 0, 0, 0);
        const int n = nb + tl * 16 + l16;
#pragma unroll
        for (int r = 0; r < 4; r++) {
            dp[(size_t)(ro + r) * NPIX + n]        = f2bf(c0[r]);
            dp[(size_t)(16 + ro + r) * NPIX + n]   = f2bf(c1[r]);
        }
    }
}

// ---------------------------------------------------------------------------
// FUSED attention v2: one block per (b,h), 4 waves, no transpose LDS.
// ---------------------------------------------------------------------------
__global__ __launch_bounds__(256)
void attn_fused(const unsigned short* __restrict__ qkv,
                const unsigned short* __restrict__ dpw,
                unsigned short* __restrict__ att)
{
    __shared__ float kvred[4][33 * 33];
    __shared__ float kvs[1056];

    const int t    = threadIdx.x;
    const int lane = t & 63;
    const int w    = t >> 6;
    const int bh   = blockIdx.x;
    const int b    = bh >> 4;
    const int h    = bh & 15;

    const unsigned short* base = (h < 8)
        ? qkv + ((size_t)(b * 768 + h * 96)) * NPIX
        : dpw + ((size_t)(b * 768 + (h - 8) * 96)) * NPIX;
    const unsigned short* qp = base;
    const unsigned short* kp = base + 32 * NPIX;
    const unsigned short* vp = base + 64 * NPIX;

    const int l16 = lane & 15;
    const int lq  = lane >> 4;
    const int ko  = lq * 8;
    const int nb  = w * 256;

    // phase 1: kv partials
    {
        f32x4 acc[3][2];
#pragma unroll
        for (int i = 0; i < 3; i++)
#pragma unroll
            for (int j = 0; j < 2; j++) {
                f32x4 z = {0.f, 0.f, 0.f, 0.f};
                acc[i][j] = z;
            }
        bf16x8 ones;
#pragma unroll
        for (int j = 0; j < 8; j++) ones[j] = (l16 == 0) ? (short)0x3F80 : (short)0;

#pragma unroll
        for (int s = 0; s < 8; s++) {
            const int n0 = nb + s * 32 + ko;
            const bf16x8 av0 = *(const bf16x8*)(vp + (size_t)l16 * NPIX + n0);
            const bf16x8 av1 = *(const bf16x8*)(vp + (size_t)(16 + l16) * NPIX + n0);
            const u16x8 k0 = *(const u16x8*)(kp + (size_t)l16 * NPIX + n0);
            const u16x8 k1 = *(const u16x8*)(kp + (size_t)(16 + l16) * NPIX + n0);
            bf16x8 bk0, bk1;
#pragma unroll
            for (int j = 0; j < 8; j++) {
                bk0[j] = (k0[j] & 0x8000u) ? (short)0 : (short)k0[j];
                bk1[j] = (k1[j] & 0x8000u) ? (short)0 : (short)k1[j];
            }
            acc[0][0] = __builtin_amdgcn_mfma_f32_16x16x32_bf16(av0,  bk0, acc[0][0], 0, 0, 0);
            acc[0][1] = __builtin_amdgcn_mfma_f32_16x16x32_bf16(av0,  bk1, acc[0][1], 0, 0, 0);
            acc[1][0] = __builtin_amdgcn_mfma_f32_16x16x32_bf16(av1,  bk0, acc[1][0], 0, 0, 0);
            acc[1][1] = __builtin_amdgcn_mfma_f32_16x16x32_bf16(av1,  bk1, acc[1][1], 0, 0, 0);
            acc[2][0] = __builtin_amdgcn_mfma_f32_16x16x32_bf16(ones, bk0, acc[2][0], 0, 0, 0);
            acc[2][1] = __builtin_amdgcn_mfma_f32_16x16x32_bf16(ones, bk1, acc[2][1], 0, 0, 0);
        }
        const int rbase = lq * 4;
#pragma unroll
        for (int dt = 0; dt < 2; dt++)
#pragma unroll
            for (int et = 0; et < 2; et++)
#pragma unroll
                for (int r = 0; r < 4; r++)
                    kvred[w][(dt * 16 + rbase + r) * 33 + et * 16 + l16] = acc[dt][et][r];
        if (rbase == 0) {
#pragma unroll
            for (int et = 0; et < 2; et++)
                kvred[w][32 * 33 + et * 16 + l16] = acc[2][et][0];
        }
    }
    __syncthreads();
#pragma unroll
    for (int k = 0; k < 5; k++) {
        const int idx = t + k * 256;
        if (idx < 1056) {
            const int a = (idx >> 5) * 33 + (idx & 31);
            kvs[idx] = kvred[0][a] + kvred[1][a] + kvred[2][a] + kvred[3][a];
        }
    }
    __syncthreads();

    // phase 2: out = kv · relu(Q), K=32; output straight from regs.
    bf16x8 a0, a1, a2;
#pragma unroll
    for (int j = 0; j < 8; j++) {
        a0[j] = (short)f2bf(kvs[l16 * 32 + ko + j]);
        a1[j] = (short)f2bf(kvs[(16 + l16) * 32 + ko + j]);
        a2[j] = (l16 == 0) ? (short)f2bf(kvs[32 * 32 + ko + j]) : (short)0;
    }
    bf16x8 bfr[16];
    const unsigned short* qb = qp + (size_t)ko * NPIX + nb + l16;
#pragma unroll
    for (int tl = 0; tl < 16; tl++) {
        bf16x8 bf;
#pragma unroll
        for (int j = 0; j < 8; j++) {
            const unsigned short v = qb[(size_t)j * NPIX + tl * 16];
            bf[j] = (v & 0x8000u) ? (short)0 : (short)v;
        }
        bfr[tl] = bf;
    }

    const int db0 = lq >> 1;
    const int sub = (lq & 1) * 4;
    unsigned short* ab0 = att + (((size_t)(b * 64 + h * 4 + db0)) * NPIX) * 8 + sub;
    unsigned short* ab1 = att + (((size_t)(b * 64 + h * 4 + 2 + db0)) * NPIX) * 8 + sub;

#pragma unroll
    for (int tl = 0; tl < 16; tl++) {
        f32x4 z = {0.f, 0.f, 0.f, 0.f};
        z = __builtin_amdgcn_mfma_f32_16x16x32_bf16(a2, bfr[tl], z, 0, 0, 0);
        const float den = __shfl(z[0], l16, 64);     // den(col l16) from lane l16
        const float inv = 1.f / (den + 1e-15f);
        f32x4 c0 = {0.f, 0.f, 0.f, 0.f};
        f32x4 c1 = {0.f, 0.f, 0.f, 0.f};
        c0 = __builtin_amdgcn_mfma_f32_16x16x32_bf16(a0, bfr[tl], c0, 0, 0, 0);
        c1 = __builtin_amdgcn_mfma_f32_16x16x32_bf16(a1, bfr[tl], c1, 0, 0, 0);
        u16x4 p0, p1;
#pragma unroll
        for (int r = 0; r < 4; r++) {
            p0[r] = f2bf(c0[r] * inv);
            p1[r] = f2bf(c1[r] * inv);
        }
        const size_t n8 = (size_t)(nb + tl * 16 + l16) * 8;
        *(u16x4*)(ab0 + n8) = p0;
        *(u16x4*)(ab1 + n8) = p1;
    }
}

// ---------------------------------------------------------------------------
extern "C" void kernel_launch(void* const* d_in, const int* in_sizes, int n_in,
                              void* d_out, int out_size, void* d_ws, size_t ws_size,
                              hipStream_t stream)
{
    (void)in_sizes; (void)n_in; (void)out_size;

    const float* x      = (const float*)d_in[0];
    const float* y      = (const float*)d_in[1];
    const float* qkv_w  = (const float*)d_in[2];
    const float* dw5_w  = (const float*)d_in[3];
    const float* pwg_w  = (const float*)d_in[4];
    const float* proj_w = (const float*)d_in[5];
    const float* proj_g = (const float*)d_in[6];
    const float* proj_b = (const float*)d_in[7];
    const float* proj_m = (const float*)d_in[8];
    const float* proj_v = (const float*)d_in[9];
    const float* inv_w  = (const float*)d_in[10];
    const float* inv_b  = (const float*)d_in[11];
    const float* dwc_w  = (const float*)d_in[12];
    const float* dwc_b  = (const float*)d_in[13];
    const float* pw_w   = (const float*)d_in[14];
    const float* pw_g   = (const float*)d_in[15];
    const float* pw_b   = (const float*)d_in[16];
    const float* pw_m   = (const float*)d_in[17];
    const float* pw_v   = (const float*)d_in[18];

    float* ws = (float*)d_ws;
    unsigned short* wqkv_b  = (unsigned short*)(ws + WQKV_OFF);
    unsigned short* wproj_b = (unsigned short*)(ws + WPROJ_OFF);
    unsigned short* winv_b  = (unsigned short*)(ws + WINV_OFF);
    unsigned short* wpw_b   = (unsigned short*)(ws + WPW_OFF);
    float* out = (float*)d_out;

    wconv_all<<<dim3(416), 256, 0, stream>>>(qkv_w, proj_w, inv_w, pw_w,
                                             wqkv_b, wproj_b, winv_b, wpw_b);

    if (ws_size >= (size_t)BATCH_NEED_F * 4ull) {
        // ---------------- batched path: both chains as images 0..31 ----------
        unsigned short* bxt  = (unsigned short*)(ws + BXT_OFF);
        unsigned short* bqkv = (unsigned short*)(ws + BQKV_OFF);
        unsigned short* bdpw = (unsigned short*)(ws + BDPW_OFF);
        unsigned short* batt = (unsigned short*)(ws + BATT_OFF);
        unsigned short* bt1t = (unsigned short*)(ws + BT1T_OFF);
        unsigned short* bh1t = (unsigned short*)(ws + BH1T_OFF);
        unsigned short* bh2t = (unsigned short*)(ws + BH2T_OFF);

        xpose2<<<dim3(4096), 256, 0, stream>>>(x, y, bxt, 256);
        gemm_direct<128, 128, 0, false, 1><<<dim3(6, 256), 256, 0, stream>>>(
            bxt, nullptr, wqkv_b, nullptr, bqkv, 768, 256,
            nullptr, nullptr, nullptr, nullptr, nullptr, nullptr, nullptr, nullptr);
        dwconv5x5_v3<<<dim3(12288), 256, 0, stream>>>(bqkv, dw5_w, bdpw);
        grouped_mfma<<<dim3(768), 256, 0, stream>>>(bdpw, pwg_w);
        attn_fused<<<dim3(512), 256, 0, stream>>>(bqkv, bdpw, batt);
        gemm_direct<64, 64, 1, false, 2><<<dim3(4, 512), 256, 0, stream>>>(
            batt, nullptr, wproj_b, nullptr, bt1t, 256, 512,
            x, y, nullptr, proj_g, proj_b, proj_m, proj_v, nullptr);
        gemm_direct<128, 128, 2, false, 2><<<dim3(8, 256), 256, 0, stream>>>(
            bt1t, nullptr, winv_b, nullptr, bh1t, 1024, 256,
            nullptr, nullptr, nullptr, nullptr, nullptr, nullptr, nullptr, inv_b);
        dwconv3x3_h2<<<dim3(8192), 256, 0, stream>>>(bh1t, dwc_w, dwc_b, bh2t);
        gemm_direct<64, 64, 3, false, 0><<<dim3(4, 256), 256, 0, stream>>>(
            bh2t, bh2t + (size_t)16 * 1024 * 1024, wpw_b, out, nullptr, 256, 1024,
            nullptr, nullptr, bt1t, pw_g, pw_b, pw_m, pw_v, nullptr);
    } else {
        // ---------------- fallback: per-chain (R14 structure) ----------------
        unsigned short* wxt  = (unsigned short*)(ws + XT_OFF);
        unsigned short* wqkv = (unsigned short*)(ws + QKV_OFF);
        unsigned short* wdpw = (unsigned short*)(ws + DPW_OFF);
        unsigned short* watt = (unsigned short*)(ws + ATT_OFF);
        float*          wt1  = ws + T1_OFF;
        unsigned short* wt1t = (unsigned short*)(ws + T1T_OFF);
        unsigned short* wh1t = (unsigned short*)(ws + H1T_OFF);
        unsigned short* wh2t = (unsigned short*)(ws + H2T_OFF);

        for (int blk = 0; blk < 2; blk++) {
            const float* t = (blk == 0) ? x : y;
            xpose2<<<dim3(2048), 256, 0, stream>>>(t, t, wxt, 256);
            gemm_direct<128, 128, 0, false, 1><<<dim3(6, 128), 256, 0, stream>>>(
                wxt, nullptr, wqkv_b, nullptr, wqkv, 768, 256,
                nullptr, nullptr, nullptr, nullptr, nullptr, nullptr, nullptr, nullptr);
            dwconv5x5_v3<<<dim3(6144), 256, 0, stream>>>(wqkv, dw5_w, wdpw);
            grouped_mfma<<<dim3(384), 256, 0, stream>>>(wdpw, pwg_w);
            attn_fused<<<dim3(256), 256, 0, stream>>>(wqkv, wdpw, watt);
            gemm_direct<64, 64, 1, false, 3><<<dim3(4, 256), 256, 0, stream>>>(
                watt, watt, wproj_b, wt1, wt1t, 256, 512,
                t, t, nullptr, proj_g, proj_b, proj_m, proj_v, nullptr);
            gemm_direct<128, 128, 2, false, 2><<<dim3(8, 128), 256, 0, stream>>>(
                wt1t, nullptr, winv_b, nullptr, wh1t, 1024, 256,
                nullptr, nullptr, nullptr, nullptr, nullptr, nullptr, nullptr, inv_b);
            dwconv3x3_h2<<<dim3(4096), 256, 0, stream>>>(wh1t, dwc_w, dwc_b, wh2t);
            if (blk == 0) {
                gemm_direct<64, 64, 1, false, 0><<<dim3(4, 256), 256, 0, stream>>>(
                    wh2t, nullptr, wpw_b, out, nullptr, 256, 1024,
                    wt1, wt1, nullptr, pw_g, pw_b, pw_m, pw_v, nullptr);
            } else {
                gemm_direct<64, 64, 1, true, 0><<<dim3(4, 256), 256, 0, stream>>>(
                    wh2t, nullptr, wpw_b, out, nullptr, 256, 1024,
                    wt1, wt1, nullptr, pw_g, pw_b, pw_m, pw_v, nullptr);
            }
        }
    }
}

// Round 22
// 232.751 us; speedup vs baseline: 1.1441x; 1.0091x over previous
//
#include <hip/hip_runtime.h>
#include <cstddef>

#define NPIX 1024   // H*W = 32*32

// ---------------------------------------------------------------------------
// Workspace layouts (float-slot offsets).
// BATCHED (both residual chains as images 0..31): peak 38,174,720 floats.
// FALLBACK (per-chain, R14 layout): peak 34,045,952 floats.
// ---------------------------------------------------------------------------
static constexpr size_t WQKV_OFF  = 0;
static constexpr size_t WPROJ_OFF = 98304;
static constexpr size_t WINV_OFF  = 163840;
static constexpr size_t WPW_OFF   = 294912;
// batched
static constexpr size_t BXT_OFF   = 425984;
static constexpr size_t BQKV_OFF  = 4620288;
static constexpr size_t BDPW_OFF  = 17203200;
static constexpr size_t BATT_OFF  = 29786112;
static constexpr size_t BT1T_OFF  = 425984;     // alias XT32
static constexpr size_t BH1T_OFF  = 4620288;    // alias QKV32..
static constexpr size_t BH2T_OFF  = 21397504;   // alias DPW-tail+ATT
static constexpr size_t BATCH_NEED_F = 38174720;
// fallback (R14)
static constexpr size_t XT_OFF    = 425984;
static constexpr size_t QKV_OFF   = 2523136;
static constexpr size_t DPW_OFF   = 8814592;
static constexpr size_t ATT_OFF   = 15106048;
static constexpr size_t T1_OFF    = 21463040;
static constexpr size_t T1T_OFF   = 25657344;
static constexpr size_t H1T_OFF   = 425984;
static constexpr size_t H2T_OFF   = 25657344;

typedef __attribute__((ext_vector_type(8))) short bf16x8;
typedef __attribute__((ext_vector_type(8))) unsigned short u16x8;
typedef __attribute__((ext_vector_type(4))) unsigned short u16x4;
typedef __attribute__((ext_vector_type(4))) float f32x4;

__device__ inline unsigned short f2bf(float f) {
    union { float f; unsigned int u; } v; v.f = f;
    unsigned int u = v.u;
    u += 0x7FFFu + ((u >> 16) & 1u);        // round-to-nearest-even
    return (unsigned short)(u >> 16);
}
__device__ inline float bf2f(unsigned short u) {
    union { float f; unsigned int u; } v; v.u = ((unsigned int)u) << 16;
    return v.f;
}
__device__ inline u16x8 zero8() {
    u16x8 z = {0, 0, 0, 0, 0, 0, 0, 0};
    return z;
}

// ---------------------------------------------------------------------------
// Weight convert (all 4 weights in ONE launch): fp32 [O][K] -> bf16 [K/8][O][8]
// ---------------------------------------------------------------------------
__global__ __launch_bounds__(256)
void wconv_all(const float* __restrict__ w0, const float* __restrict__ w1,
               const float* __restrict__ w2, const float* __restrict__ w3,
               unsigned short* __restrict__ d0, unsigned short* __restrict__ d1,
               unsigned short* __restrict__ d2, unsigned short* __restrict__ d3)
{
    const int bid = blockIdx.x;
    const float* W; unsigned short* WB; int O, K, base;
    if (bid < 96)       { W = w0; WB = d0; O = 768;  K = 256;  base = 0;   }
    else if (bid < 160) { W = w1; WB = d1; O = 256;  K = 512;  base = 96;  }
    else if (bid < 288) { W = w2; WB = d2; O = 1024; K = 256;  base = 160; }
    else                { W = w3; WB = d3; O = 256;  K = 1024; base = 288; }
    const int idx = (bid - base) * 256 + threadIdx.x;
    if (idx >= O * (K >> 3)) return;
    const int o = idx % O;
    const int koct = idx / O;
    u16x8 v;
#pragma unroll
    for (int j = 0; j < 8; j++) v[j] = f2bf(W[(size_t)o * K + koct * 8 + j]);
    *(u16x8*)(WB + ((size_t)koct * O + o) * 8) = v;
}

// ---------------------------------------------------------------------------
// Transpose, dual-source: image ib<16 from X0, else X1.
// ---------------------------------------------------------------------------
__global__ __launch_bounds__(256)
void xpose2(const float* __restrict__ X0, const float* __restrict__ X1,
            unsigned short* __restrict__ XT, const int C)
{
    __shared__ float tt[8][260];
    const int t = threadIdx.x;
    const int octs = C >> 3;
    const int strips = octs * 4;
    const int ib = blockIdx.x / strips;
    const int rem = blockIdx.x - ib * strips;
    const int coct = rem >> 2;
    const int n0 = (rem & 3) * 256;
    const float* src = (ib < 16) ? X0 + (size_t)ib * C * NPIX
                                 : X1 + (size_t)(ib - 16) * C * NPIX;
    const int cc = t >> 5;
    const int c8 = (t & 31) * 8;
    const float* xp = src + ((size_t)(coct * 8 + cc)) * NPIX + n0 + c8;
    *(float4*)(&tt[cc][c8])     = *(const float4*)(xp);
    *(float4*)(&tt[cc][c8 + 4]) = *(const float4*)(xp + 4);
    __syncthreads();
    u16x8 v;
#pragma unroll
    for (int j = 0; j < 8; j++) v[j] = f2bf(tt[j][t]);
    *(u16x8*)(XT + (((size_t)ib * octs + coct) * NPIX + n0 + t) * 8) = v;
}

// ---------------------------------------------------------------------------
// MFMA GEMM, DIRECT global->VGPR fragments, 4-DEEP register pipeline.
// Operands blocked bf16 [K/8][rows][8].  K/8 multiple of 16.
// EPI: 0 plain; 1 BN + fp32 residual; 2 bias+hswish; 3 DUAL interleaved
//      second K-stream X2 into acc2 (shared A), BN+2*shift+bf16 residuals.
// OMODE: 0 fp32 [c][n] (+ACC); 1 bf16 [c][n] DIRECT scalar stores;
//        2 blocked bf16 DIRECT u16x4 stores (lane's 4 acc regs are 4
//        contiguous channels: o&7 = (lq&1)*4 + r); 3 fp32 + blocked direct.
// NO epilogue LDS, no barrier (R18 attn insight applied to GEMM).
// ---------------------------------------------------------------------------
template<int BM, int BN, int EPI, bool ACC, int OMODE>
__global__ __launch_bounds__(256)
void gemm_direct(const unsigned short* __restrict__ X, const unsigned short* __restrict__ X2,
                 const unsigned short* __restrict__ W,
                 float* __restrict__ Y, unsigned short* __restrict__ YB,
                 const int O, const int K,
                 const float* __restrict__ res, const float* __restrict__ res2,
                 const unsigned short* __restrict__ resb,
                 const float* __restrict__ bng, const float* __restrict__ bnb,
                 const float* __restrict__ bnm, const float* __restrict__ bnv,
                 const float* __restrict__ bias)
{
    constexpr int TN = NPIX / BN;
    constexpr int WAVES_N = (BN >= 128) ? 2 : 1;
    constexpr int WM = BM / (4 / WAVES_N);
    constexpr int MI = WM / 16;
    constexpr int NJ = 4;

    const int t    = threadIdx.x;
    const int lane = t & 63;
    const int w    = t >> 6;

    // XCD-bijective block swizzle (all grids are multiples of 8)
    const int gx  = gridDim.x;
    const int nwg = gx * gridDim.y;
    int bid = blockIdx.y * gx + blockIdx.x;
    bid = (bid & 7) * (nwg >> 3) + (bid >> 3);
    const int bx = bid % gx;
    const int by = bid / gx;

    const int o0 = bx * BM;
    const int b  = by / TN;
    const int n0 = (by % TN) * BN;

    const int wn = (WAVES_N == 2) ? (w & 1) * 64 : 0;
    const int wo = (WAVES_N == 2) ? (w >> 1) * WM : w * WM;

    const int l16 = lane & 15;
    const int lq  = lane >> 4;

    f32x4 acc[MI][NJ];
    f32x4 acc2[MI][NJ];
#pragma unroll
    for (int i = 0; i < MI; i++)
#pragma unroll
        for (int j = 0; j < NJ; j++) {
            f32x4 z = {0.f, 0.f, 0.f, 0.f};
            acc[i][j] = z;
            acc2[i][j] = z;
        }

    const unsigned short* Ab = W + ((size_t)lq * O + o0 + wo + l16) * 8;
    const size_t strideA = (size_t)O * 8;
    const size_t strideB = (size_t)NPIX * 8;
    const size_t boff = ((size_t)lq * NPIX + n0 + wn + l16) * 8;
    const int octs = K >> 3;                    // multiple of 16

    auto ldA_ = [&](bf16x8* fr, int kb) {
#pragma unroll
        for (int i = 0; i < MI; i++)
            fr[i] = *(const bf16x8*)(Ab + (size_t)kb * strideA + i * 128);
    };
    auto ldB_ = [&](bf16x8* fr, const unsigned short* Bb, int kb) {
#pragma unroll
        for (int j = 0; j < NJ; j++)
            fr[j] = *(const bf16x8*)(Bb + (size_t)kb * strideB + j * 128);
    };
    auto domfma_ = [&](f32x4 (&ac)[MI][NJ], bf16x8* af, bf16x8* bf) {
#pragma unroll
        for (int i = 0; i < MI; i++)
#pragma unroll
            for (int j = 0; j < NJ; j++)
                ac[i][j] = __builtin_amdgcn_mfma_f32_16x16x32_bf16(
                    af[i], bf[j], ac[i][j], 0, 0, 0);
    };

    if (EPI != 3) {
        const unsigned short* Bb = X + (size_t)b * K * NPIX + boff;
        bf16x8 a0[MI], b0[NJ], a1[MI], b1[NJ], a2s[MI], b2[NJ], a3[MI], b3[NJ];
        ldA_(a0, 0);  ldB_(b0, Bb, 0);
        ldA_(a1, 4);  ldB_(b1, Bb, 4);
        ldA_(a2s, 8); ldB_(b2, Bb, 8);
        ldA_(a3, 12); ldB_(b3, Bb, 12);
        for (int kb = 0; kb < octs; kb += 16) {
            domfma_(acc, a0, b0);
            if (kb + 16 < octs) { ldA_(a0, kb + 16); ldB_(b0, Bb, kb + 16); }
            domfma_(acc, a1, b1);
            if (kb + 20 < octs) { ldA_(a1, kb + 20); ldB_(b1, Bb, kb + 20); }
            domfma_(acc, a2s, b2);
            if (kb + 24 < octs) { ldA_(a2s, kb + 24); ldB_(b2, Bb, kb + 24); }
            domfma_(acc, a3, b3);
            if (kb + 28 < octs) { ldA_(a3, kb + 28); ldB_(b3, Bb, kb + 28); }
        }
    } else {
        // interleaved dual stream, shared A, 4-deep
        const unsigned short* B1 = X  + (size_t)b * K * NPIX + boff;
        const unsigned short* B2 = X2 + (size_t)b * K * NPIX + boff;
        bf16x8 a0[MI], a1[MI], a2s[MI], a3[MI];
        bf16x8 p0[NJ], p1[NJ], p2[NJ], p3[NJ];
        bf16x8 q0[NJ], q1[NJ], q2[NJ], q3[NJ];
        ldA_(a0, 0);  ldB_(p0, B1, 0);  ldB_(q0, B2, 0);
        ldA_(a1, 4);  ldB_(p1, B1, 4);  ldB_(q1, B2, 4);
        ldA_(a2s, 8); ldB_(p2, B1, 8);  ldB_(q2, B2, 8);
        ldA_(a3, 12); ldB_(p3, B1, 12); ldB_(q3, B2, 12);
        for (int kb = 0; kb < octs; kb += 16) {
            domfma_(acc,  a0, p0);
            domfma_(acc2, a0, q0);
            if (kb + 16 < octs) { ldA_(a0, kb + 16); ldB_(p0, B1, kb + 16); ldB_(q0, B2, kb + 16); }
            domfma_(acc,  a1, p1);
            domfma_(acc2, a1, q1);
            if (kb + 20 < octs) { ldA_(a1, kb + 20); ldB_(p1, B1, kb + 20); ldB_(q1, B2, kb + 20); }
            domfma_(acc,  a2s, p2);
            domfma_(acc2, a2s, q2);
            if (kb + 24 < octs) { ldA_(a2s, kb + 24); ldB_(p2, B1, kb + 24); ldB_(q2, B2, kb + 24); }
            domfma_(acc,  a3, p3);
            domfma_(acc2, a3, q3);
            if (kb + 28 < octs) { ldA_(a3, kb + 28); ldB_(p3, B1, kb + 28); ldB_(q3, B2, kb + 28); }
        }
    }

    // epilogue. C/D: col = lane&15 (n), row = (lane>>4)*4 + reg (o)
    const int r0q = lq * 4;
    float scale[MI][4], shift[MI][4];
    if (EPI == 1 || EPI == 3) {
#pragma unroll
        for (int i = 0; i < MI; i++)
#pragma unroll
            for (int r = 0; r < 4; r++) {
                const int o = o0 + wo + i * 16 + r0q + r;
                const float inv = bng[o] / sqrtf(bnv[o] + 1e-5f);
                scale[i][r] = inv;
                shift[i][r] = bnb[o] - bnm[o] * inv;
            }
    } else if (EPI == 2) {
#pragma unroll
        for (int i = 0; i < MI; i++)
#pragma unroll
            for (int r = 0; r < 4; r++)
                shift[i][r] = bias[o0 + wo + i * 16 + r0q + r];
    }

#pragma unroll
    for (int i = 0; i < MI; i++) {
#pragma unroll
        for (int j = 0; j < NJ; j++) {
            const int nn = n0 + wn + j * 16 + l16;
            const int ob = wo + i * 16 + r0q;           // o base within tile
            const size_t base = ((size_t)b * O + o0 + ob) * NPIX + nn;
            u16x4 r1v, r2v;
            if (EPI == 3) {
                const size_t ro = (((size_t)(b * 32 + ((o0 + ob) >> 3)) * NPIX + nn) * 8
                                   + ((o0 + ob) & 7));
                r1v = *(const u16x4*)(resb + ro);
                r2v = *(const u16x4*)(resb + (size_t)16 * 262144 + ro);
            }
            u16x4 p4;
#pragma unroll
            for (int r = 0; r < 4; r++) {
                const size_t off = base + (size_t)r * NPIX;
                float v = acc[i][j][r];
                if (EPI == 1) {
                    const float* rs = (b < 16) ? res : res2;
                    const size_t roff = ((size_t)(b & 15) * O + o0 + ob + r) * NPIX + nn;
                    v = v * scale[i][r] + shift[i][r] + rs[roff];
                } else if (EPI == 2) {
                    v += shift[i][r];
                    v = v * fminf(fmaxf(v + 3.f, 0.f), 6.f) * (1.f / 6.f);
                } else if (EPI == 3) {
                    v = (v + acc2[i][j][r]) * scale[i][r] + 2.f * shift[i][r]
                        + bf2f(r1v[r]) + bf2f(r2v[r]);
                }
                if (OMODE == 0 || OMODE == 3) {
                    if (ACC) v += Y[off];
                    Y[off] = v;
                }
                if (OMODE == 1) {
                    YB[off] = f2bf(v);                 // direct [c][n] store
                } else if (OMODE >= 2) {
                    p4[r] = f2bf(v);
                }
            }
            if (OMODE >= 2) {
                // direct blocked store: lane's 4 regs = 4 contiguous channels
                // (o&7 = (lq&1)*4 + r since o0, wo, i*16 are multiples of 8)
                const int oct = (o0 + ob) >> 3;
                const int sub = (o0 + ob) & 7;         // 0 or 4
                *(u16x4*)(YB + (((size_t)b * (O >> 3) + oct) * NPIX + nn) * 8 + sub) = p4;
            }
        }
    }
}

// ---------------------------------------------------------------------------
// Depthwise 5x5 SAME, bf16 [c][n] in/out. 2 channels/block, stride-44 fp32 LDS.
// ---------------------------------------------------------------------------
__global__ __launch_bounds__(256)
void dwconv5x5_v3(const unsigned short* __restrict__ X, const float* __restrict__ Wd,
                  unsigned short* __restrict__ Y)
{
    __shared__ float tile[2 * 36 * 44];
    __shared__ float wl[64];
    const int t     = threadIdx.x;
    const int cpair = blockIdx.x % 384;
    const int b     = blockIdx.x / 384;
    const int cbase = cpair * 2;
    const unsigned short* xp = X + ((size_t)b * 768 + cbase) * NPIX;

#pragma unroll
    for (int k = 0; k < 4; k++) {
        const int i = t + k * 256;
        if (i < 792) {
            f32x4 z = {0.f, 0.f, 0.f, 0.f};
            *(f32x4*)(&tile[i * 4]) = z;
        }
    }
    if (t < 50) wl[(t / 25) * 32 + (t % 25)] = Wd[cbase * 25 + t];
    __syncthreads();

    const int ch = t >> 7;
    const int tm = t & 127;
    const int r  = tm >> 2;
    const int c8 = (tm & 3) * 8;

    {
        const u16x8 v = *(const u16x8*)(xp + (size_t)ch * NPIX + r * 32 + c8);
        float* wp = &tile[ch * 1584 + (r + 2) * 44 + c8 + 2];
#pragma unroll
        for (int j = 0; j < 8; j += 2) {
            float2 f2v = make_float2(bf2f(v[j]), bf2f(v[j + 1]));
            *(float2*)(wp + j) = f2v;
        }
    }
    float wk[25];
#pragma unroll
    for (int i = 0; i < 25; i++) wk[i] = wl[ch * 32 + i];
    __syncthreads();

    float acc[8];
#pragma unroll
    for (int j = 0; j < 8; j++) acc[j] = 0.f;

#pragma unroll
    for (int ky = 0; ky < 5; ky++) {
        const float* rp = &tile[ch * 1584 + (r + ky) * 44 + c8];
        const f32x4 a = *(const f32x4*)(rp);
        const f32x4 bq = *(const f32x4*)(rp + 4);
        const f32x4 cq = *(const f32x4*)(rp + 8);
        const float in[12] = {a[0], a[1], a[2], a[3], bq[0], bq[1], bq[2], bq[3],
                              cq[0], cq[1], cq[2], cq[3]};
#pragma unroll
        for (int kx = 0; kx < 5; kx++) {
            const float wv = wk[ky * 5 + kx];
#pragma unroll
            for (int j = 0; j < 8; j++)
                acc[j] = fmaf(in[j + kx], wv, acc[j]);
        }
    }

    u16x8 o8;
#pragma unroll
    for (int j = 0; j < 8; j++) o8[j] = f2bf(acc[j]);
    *(u16x8*)(Y + ((size_t)b * 768 + cbase + ch) * NPIX + r * 32 + c8) = o8;
}

// ---------------------------------------------------------------------------
// Depthwise 3x3 + bias + hswish, blocked bf16 in/out — 2 px x 8 ch per thread,
// direct global reads, no pixel LDS.
// ---------------------------------------------------------------------------
__global__ __launch_bounds__(256)
void dwconv3x3_h2(const unsigned short* __restrict__ X, const float* __restrict__ Wd,
                  const float* __restrict__ bias, unsigned short* __restrict__ Y)
{
    __shared__ float wl[72];
    __shared__ float bb[8];
    const int t    = threadIdx.x;
    const int bid  = blockIdx.x;
    const int half = bid & 1;
    const int coct = (bid >> 1) & 127;
    const int b    = bid >> 8;
    const unsigned short* xp = X + ((size_t)(b * 128 + coct)) * NPIX * 8;
    if (t < 72) wl[t] = Wd[coct * 72 + t];
    if (t < 8)  bb[t] = bias[coct * 8 + t];
    __syncthreads();

    const int px0 = half * 512 + t * 2;   // 2 consecutive pixels
    const int hr  = px0 >> 5;             // image row
    const int c0  = px0 & 31;             // image col (even)

    float acc[8][2];
#pragma unroll
    for (int ch = 0; ch < 8; ch++) {
        acc[ch][0] = bb[ch];
        acc[ch][1] = bb[ch];
    }

#pragma unroll
    for (int ky = 0; ky < 3; ky++) {
        const int rr = hr + ky - 1;
        if (rr >= 0 && rr < 32) {
            u16x8 P[4];
#pragma unroll
            for (int m = 0; m < 4; m++) {
                const int col = c0 - 1 + m;
                const int colc = col < 0 ? 0 : (col > 31 ? 31 : col);
                u16x8 v = *(const u16x8*)(xp + (size_t)(rr * 32 + colc) * 8);
                if (col < 0 || col > 31) v = zero8();
                P[m] = v;
            }
#pragma unroll
            for (int ch = 0; ch < 8; ch++) {
                float g[4];
#pragma unroll
                for (int m = 0; m < 4; m++) g[m] = bf2f(P[m][ch]);
#pragma unroll
                for (int j = 0; j < 2; j++)
#pragma unroll
                    for (int kx = 0; kx < 3; kx++)
                        acc[ch][j] = fmaf(g[j + kx], wl[ch * 9 + ky * 3 + kx], acc[ch][j]);
            }
        }
    }
    unsigned short* yp = Y + ((size_t)(b * 128 + coct)) * NPIX * 8 + (size_t)px0 * 8;
#pragma unroll
    for (int j = 0; j < 2; j++) {
        u16x8 o8;
#pragma unroll
        for (int ch = 0; ch < 8; ch++) {
            float v = acc[ch][j];
            v = v * fminf(fmaxf(v + 3.f, 0.f), 6.f) * (1.f / 6.f);
            o8[ch] = f2bf(v);
        }
        *(u16x8*)(yp + j * 8) = o8;
    }
}

// ---------------------------------------------------------------------------
// Grouped 32->32 1x1 via MFMA: one block per (b,g), 4 waves x 256-px chunks.
// ---------------------------------------------------------------------------
__global__ __launch_bounds__(256)
void grouped_mfma(unsigned short* __restrict__ D, const float* __restrict__ Wg)
{
    const int t    = threadIdx.x;
    const int lane = t & 63;
    const int w    = t >> 6;
    const int bg   = blockIdx.x;          // b*24 + g
    const int g    = bg % 24;
    const int b    = bg / 24;
    const int l16  = lane & 15;
    const int lq   = lane >> 4;
    const int ko   = lq * 8;              // i-oct within K=32
    const int nb   = w * 256;

    unsigned short* dp = D + ((size_t)(b * 768 + g * 32)) * NPIX;

    // A-frags from fp32 weights: a0 -> o = l16, a1 -> o = 16+l16 (i contiguous)
    bf16x8 a0, a1;
#pragma unroll
    for (int j = 0; j < 8; j++) {
        a0[j] = (short)f2bf(Wg[g * 1024 + l16 * 32 + ko + j]);
        a1[j] = (short)f2bf(Wg[g * 1024 + (16 + l16) * 32 + ko + j]);
    }

    // B-frags: 16 n-tiles of 16 px; lane (lq,l16): b[j] = in[ko+j][nb+tl*16+l16]
    bf16x8 bfr[16];
    const unsigned short* ib = dp + (size_t)ko * NPIX + nb + l16;
#pragma unroll
    for (int tl = 0; tl < 16; tl++) {
        bf16x8 bf;
#pragma unroll
        for (int j = 0; j < 8; j++)
            bf[j] = (short)ib[(size_t)j * NPIX + tl * 16];
        bfr[tl] = bf;
    }

    // compute + store (all reads above complete before any write)
    const int ro = lq * 4;
#pragma unroll
    for (int tl = 0; tl < 16; tl++) {
        f32x4 c0 = {0.f, 0.f, 0.f, 0.f};
        f32x4 c1 = {0.f, 0.f, 0.f, 0.f};
        c0 = __builtin_amdgcn_mfma_f32_16x16x32_bf16(a0, bfr[tl], c0, 0, 0, 0);
        c1 = __builtin_amdgcn_mfma_f32_16x16x32_bf16(a1, bfr[tl], c1, 0, 0, 0);
        const int n = nb + tl * 16 + l16;
#pragma unroll
        for (int r = 0; r < 4; r++) {
            dp[(size_t)(ro + r) * NPIX + n]        = f2bf(c0[r]);
            dp[(size_t)(16 + ro + r) * NPIX + n]   = f2bf(c1[r]);
        }
    }
}

// ---------------------------------------------------------------------------
// FUSED attention v2: one block per (b,h), 4 waves, no transpose LDS.
// ---------------------------------------------------------------------------
__global__ __launch_bounds__(256)
void attn_fused(const unsigned short* __restrict__ qkv,
                const unsigned short* __restrict__ dpw,
                unsigned short* __restrict__ att)
{
    __shared__ float kvred[4][33 * 33];
    __shared__ float kvs[1056];

    const int t    = threadIdx.x;
    const int lane = t & 63;
    const int w    = t >> 6;
    const int bh   = blockIdx.x;
    const int b    = bh >> 4;
    const int h    = bh & 15;

    const unsigned short* base = (h < 8)
        ? qkv + ((size_t)(b * 768 + h * 96)) * NPIX
        : dpw + ((size_t)(b * 768 + (h - 8) * 96)) * NPIX;
    const unsigned short* qp = base;
    const unsigned short* kp = base + 32 * NPIX;
    const unsigned short* vp = base + 64 * NPIX;

    const int l16 = lane & 15;
    const int lq  = lane >> 4;
    const int ko  = lq * 8;
    const int nb  = w * 256;

    // phase 1: kv partials
    {
        f32x4 acc[3][2];
#pragma unroll
        for (int i = 0; i < 3; i++)
#pragma unroll
            for (int j = 0; j < 2; j++) {
                f32x4 z = {0.f, 0.f, 0.f, 0.f};
                acc[i][j] = z;
            }
        bf16x8 ones;
#pragma unroll
        for (int j = 0; j < 8; j++) ones[j] = (l16 == 0) ? (short)0x3F80 : (short)0;

#pragma unroll
        for (int s = 0; s < 8; s++) {
            const int n0 = nb + s * 32 + ko;
            const bf16x8 av0 = *(const bf16x8*)(vp + (size_t)l16 * NPIX + n0);
            const bf16x8 av1 = *(const bf16x8*)(vp + (size_t)(16 + l16) * NPIX + n0);
            const u16x8 k0 = *(const u16x8*)(kp + (size_t)l16 * NPIX + n0);
            const u16x8 k1 = *(const u16x8*)(kp + (size_t)(16 + l16) * NPIX + n0);
            bf16x8 bk0, bk1;
#pragma unroll
            for (int j = 0; j < 8; j++) {
                bk0[j] = (k0[j] & 0x8000u) ? (short)0 : (short)k0[j];
                bk1[j] = (k1[j] & 0x8000u) ? (short)0 : (short)k1[j];
            }
            acc[0][0] = __builtin_amdgcn_mfma_f32_16x16x32_bf16(av0,  bk0, acc[0][0], 0, 0, 0);
            acc[0][1] = __builtin_amdgcn_mfma_f32_16x16x32_bf16(av0,  bk1, acc[0][1], 0, 0, 0);
            acc[1][0] = __builtin_amdgcn_mfma_f32_16x16x32_bf16(av1,  bk0, acc[1][0], 0, 0, 0);
            acc[1][1] = __builtin_amdgcn_mfma_f32_16x16x32_bf16(av1,  bk1, acc[1][1], 0, 0, 0);
            acc[2][0] = __builtin_amdgcn_mfma_f32_16x16x32_bf16(ones, bk0, acc[2][0], 0, 0, 0);
            acc[2][1] = __builtin_amdgcn_mfma_f32_16x16x32_bf16(ones, bk1, acc[2][1], 0, 0, 0);
        }
        const int rbase = lq * 4;
#pragma unroll
        for (int dt = 0; dt < 2; dt++)
#pragma unroll
            for (int et = 0; et < 2; et++)
#pragma unroll
                for (int r = 0; r < 4; r++)
                    kvred[w][(dt * 16 + rbase + r) * 33 + et * 16 + l16] = acc[dt][et][r];
        if (rbase == 0) {
#pragma unroll
            for (int et = 0; et < 2; et++)
                kvred[w][32 * 33 + et * 16 + l16] = acc[2][et][0];
        }
    }
    __syncthreads();
#pragma unroll
    for (int k = 0; k < 5; k++) {
        const int idx = t + k * 256;
        if (idx < 1056) {
            const int a = (idx >> 5) * 33 + (idx & 31);
            kvs[idx] = kvred[0][a] + kvred[1][a] + kvred[2][a] + kvred[3][a];
        }
    }
    __syncthreads();

    // phase 2: out = kv · relu(Q), K=32; output straight from regs.
    bf16x8 a0, a1, a2;
#pragma unroll
    for (int j = 0; j < 8; j++) {
        a0[j] = (short)f2bf(kvs[l16 * 32 + ko + j]);
        a1[j] = (short)f2bf(kvs[(16 + l16) * 32 + ko + j]);
        a2[j] = (l16 == 0) ? (short)f2bf(kvs[32 * 32 + ko + j]) : (short)0;
    }
    bf16x8 bfr[16];
    const unsigned short* qb = qp + (size_t)ko * NPIX + nb + l16;
#pragma unroll
    for (int tl = 0; tl < 16; tl++) {
        bf16x8 bf;
#pragma unroll
        for (int j = 0; j < 8; j++) {
            const unsigned short v = qb[(size_t)j * NPIX + tl * 16];
            bf[j] = (v & 0x8000u) ? (short)0 : (short)v;
        }
        bfr[tl] = bf;
    }

    const int db0 = lq >> 1;
    const int sub = (lq & 1) * 4;
    unsigned short* ab0 = att + (((size_t)(b * 64 + h * 4 + db0)) * NPIX) * 8 + sub;
    unsigned short* ab1 = att + (((size_t)(b * 64 + h * 4 + 2 + db0)) * NPIX) * 8 + sub;

#pragma unroll
    for (int tl = 0; tl < 16; tl++) {
        f32x4 z = {0.f, 0.f, 0.f, 0.f};
        z = __builtin_amdgcn_mfma_f32_16x16x32_bf16(a2, bfr[tl], z, 0, 0, 0);
        const float den = __shfl(z[0], l16, 64);     // den(col l16) from lane l16
        const float inv = 1.f / (den + 1e-15f);
        f32x4 c0 = {0.f, 0.f, 0.f, 0.f};
        f32x4 c1 = {0.f, 0.f, 0.f, 0.f};
        c0 = __builtin_amdgcn_mfma_f32_16x16x32_bf16(a0, bfr[tl], c0, 0, 0, 0);
        c1 = __builtin_amdgcn_mfma_f32_16x16x32_bf16(a1, bfr[tl], c1, 0, 0, 0);
        u16x4 p0, p1;
#pragma unroll
        for (int r = 0; r < 4; r++) {
            p0[r] = f2bf(c0[r] * inv);
            p1[r] = f2bf(c1[r] * inv);
        }
        const size_t n8 = (size_t)(nb + tl * 16 + l16) * 8;
        *(u16x4*)(ab0 + n8) = p0;
        *(u16x4*)(ab1 + n8) = p1;
    }
}

// ---------------------------------------------------------------------------
extern "C" void kernel_launch(void* const* d_in, const int* in_sizes, int n_in,
                              void* d_out, int out_size, void* d_ws, size_t ws_size,
                              hipStream_t stream)
{
    (void)in_sizes; (void)n_in; (void)out_size;

    const float* x      = (const float*)d_in[0];
    const float* y      = (const float*)d_in[1];
    const float* qkv_w  = (const float*)d_in[2];
    const float* dw5_w  = (const float*)d_in[3];
    const float* pwg_w  = (const float*)d_in[4];
    const float* proj_w = (const float*)d_in[5];
    const float* proj_g = (const float*)d_in[6];
    const float* proj_b = (const float*)d_in[7];
    const float* proj_m = (const float*)d_in[8];
    const float* proj_v = (const float*)d_in[9];
    const float* inv_w  = (const float*)d_in[10];
    const float* inv_b  = (const float*)d_in[11];
    const float* dwc_w  = (const float*)d_in[12];
    const float* dwc_b  = (const float*)d_in[13];
    const float* pw_w   = (const float*)d_in[14];
    const float* pw_g   = (const float*)d_in[15];
    const float* pw_b   = (const float*)d_in[16];
    const float* pw_m   = (const float*)d_in[17];
    const float* pw_v   = (const float*)d_in[18];

    float* ws = (float*)d_ws;
    unsigned short* wqkv_b  = (unsigned short*)(ws + WQKV_OFF);
    unsigned short* wproj_b = (unsigned short*)(ws + WPROJ_OFF);
    unsigned short* winv_b  = (unsigned short*)(ws + WINV_OFF);
    unsigned short* wpw_b   = (unsigned short*)(ws + WPW_OFF);
    float* out = (float*)d_out;

    wconv_all<<<dim3(416), 256, 0, stream>>>(qkv_w, proj_w, inv_w, pw_w,
                                             wqkv_b, wproj_b, winv_b, wpw_b);

    if (ws_size >= (size_t)BATCH_NEED_F * 4ull) {
        // ---------------- batched path: both chains as images 0..31 ----------
        unsigned short* bxt  = (unsigned short*)(ws + BXT_OFF);
        unsigned short* bqkv = (unsigned short*)(ws + BQKV_OFF);
        unsigned short* bdpw = (unsigned short*)(ws + BDPW_OFF);
        unsigned short* batt = (unsigned short*)(ws + BATT_OFF);
        unsigned short* bt1t = (unsigned short*)(ws + BT1T_OFF);
        unsigned short* bh1t = (unsigned short*)(ws + BH1T_OFF);
        unsigned short* bh2t = (unsigned short*)(ws + BH2T_OFF);

        xpose2<<<dim3(4096), 256, 0, stream>>>(x, y, bxt, 256);
        gemm_direct<128, 128, 0, false, 1><<<dim3(6, 256), 256, 0, stream>>>(
            bxt, nullptr, wqkv_b, nullptr, bqkv, 768, 256,
            nullptr, nullptr, nullptr, nullptr, nullptr, nullptr, nullptr, nullptr);
        dwconv5x5_v3<<<dim3(12288), 256, 0, stream>>>(bqkv, dw5_w, bdpw);
        grouped_mfma<<<dim3(768), 256, 0, stream>>>(bdpw, pwg_w);
        attn_fused<<<dim3(512), 256, 0, stream>>>(bqkv, bdpw, batt);
        gemm_direct<64, 64, 1, false, 2><<<dim3(4, 512), 256, 0, stream>>>(
            batt, nullptr, wproj_b, nullptr, bt1t, 256, 512,
            x, y, nullptr, proj_g, proj_b, proj_m, proj_v, nullptr);
        gemm_direct<128, 128, 2, false, 2><<<dim3(8, 256), 256, 0, stream>>>(
            bt1t, nullptr, winv_b, nullptr, bh1t, 1024, 256,
            nullptr, nullptr, nullptr, nullptr, nullptr, nullptr, nullptr, inv_b);
        dwconv3x3_h2<<<dim3(8192), 256, 0, stream>>>(bh1t, dwc_w, dwc_b, bh2t);
        gemm_direct<64, 64, 3, false, 0><<<dim3(4, 256), 256, 0, stream>>>(
            bh2t, bh2t + (size_t)16 * 1024 * 1024, wpw_b, out, nullptr, 256, 1024,
            nullptr, nullptr, bt1t, pw_g, pw_b, pw_m, pw_v, nullptr);
    } else {
        // ---------------- fallback: per-chain (R14 structure) ----------------
        unsigned short* wxt  = (unsigned short*)(ws + XT_OFF);
        unsigned short* wqkv = (unsigned short*)(ws + QKV_OFF);
        unsigned short* wdpw = (unsigned short*)(ws + DPW_OFF);
        unsigned short* watt = (unsigned short*)(ws + ATT_OFF);
        float*          wt1  = ws + T1_OFF;
        unsigned short* wt1t = (unsigned short*)(ws + T1T_OFF);
        unsigned short* wh1t = (unsigned short*)(ws + H1T_OFF);
        unsigned short* wh2t = (unsigned short*)(ws + H2T_OFF);

        for (int blk = 0; blk < 2; blk++) {
            const float* t = (blk == 0) ? x : y;
            xpose2<<<dim3(2048), 256, 0, stream>>>(t, t, wxt, 256);
            gemm_direct<128, 128, 0, false, 1><<<dim3(6, 128), 256, 0, stream>>>(
                wxt, nullptr, wqkv_b, nullptr, wqkv, 768, 256,
                nullptr, nullptr, nullptr, nullptr, nullptr, nullptr, nullptr, nullptr);
            dwconv5x5_v3<<<dim3(6144), 256, 0, stream>>>(wqkv, dw5_w, wdpw);
            grouped_mfma<<<dim3(384), 256, 0, stream>>>(wdpw, pwg_w);
            attn_fused<<<dim3(256), 256, 0, stream>>>(wqkv, wdpw, watt);
            gemm_direct<64, 64, 1, false, 3><<<dim3(4, 256), 256, 0, stream>>>(
                watt, watt, wproj_b, wt1, wt1t, 256, 512,
                t, t, nullptr, proj_g, proj_b, proj_m, proj_v, nullptr);
            gemm_direct<128, 128, 2, false, 2><<<dim3(8, 128), 256, 0, stream>>>(
                wt1t, nullptr, winv_b, nullptr, wh1t, 1024, 256,
                nullptr, nullptr, nullptr, nullptr, nullptr, nullptr, nullptr, inv_b);
            dwconv3x3_h2<<<dim3(4096), 256, 0, stream>>>(wh1t, dwc_w, dwc_b, wh2t);
            if (blk == 0) {
                gemm_direct<64, 64, 1, false, 0><<<dim3(4, 256), 256, 0, stream>>>(
                    wh2t, nullptr, wpw_b, out, nullptr, 256, 1024,
                    wt1, wt1, nullptr, pw_g, pw_b, pw_m, pw_v, nullptr);
            } else {
                gemm_direct<64, 64, 1, true, 0><<<dim3(4, 256), 256, 0, stream>>>(
                    wh2t, nullptr, wpw_b, out, nullptr, 256, 1024,
                    wt1, wt1, nullptr, pw_g, pw_b, pw_m, pw_v, nullptr);
            }
        }
    }
}

// Round 23
// 221.415 us; speedup vs baseline: 1.2027x; 1.0512x over previous
//
#include <hip/hip_runtime.h>
#include <cstddef>

#define NPIX 1024   // H*W = 32*32

// ---------------------------------------------------------------------------
// Workspace layouts (float-slot offsets).
// BATCHED (both residual chains as images 0..31): peak 38,174,720 floats.
// FALLBACK (per-chain, R14 layout): peak 34,045,952 floats.
// ---------------------------------------------------------------------------
static constexpr size_t WQKV_OFF  = 0;
static constexpr size_t WPROJ_OFF = 98304;
static constexpr size_t WINV_OFF  = 163840;
static constexpr size_t WPW_OFF   = 294912;
// batched
static constexpr size_t BXT_OFF   = 425984;
static constexpr size_t BQKV_OFF  = 4620288;
static constexpr size_t BDPW_OFF  = 17203200;
static constexpr size_t BATT_OFF  = 29786112;
static constexpr size_t BT1T_OFF  = 425984;     // alias XT32
static constexpr size_t BH1T_OFF  = 4620288;    // alias QKV32..
static constexpr size_t BH2T_OFF  = 21397504;   // alias DPW-tail+ATT
static constexpr size_t BATCH_NEED_F = 38174720;
// fallback (R14)
static constexpr size_t XT_OFF    = 425984;
static constexpr size_t QKV_OFF   = 2523136;
static constexpr size_t DPW_OFF   = 8814592;
static constexpr size_t ATT_OFF   = 15106048;
static constexpr size_t T1_OFF    = 21463040;
static constexpr size_t T1T_OFF   = 25657344;
static constexpr size_t H1T_OFF   = 425984;
static constexpr size_t H2T_OFF   = 25657344;

typedef __attribute__((ext_vector_type(8))) short bf16x8;
typedef __attribute__((ext_vector_type(8))) unsigned short u16x8;
typedef __attribute__((ext_vector_type(4))) unsigned short u16x4;
typedef __attribute__((ext_vector_type(4))) float f32x4;

__device__ inline unsigned short f2bf(float f) {
    union { float f; unsigned int u; } v; v.f = f;
    unsigned int u = v.u;
    u += 0x7FFFu + ((u >> 16) & 1u);        // round-to-nearest-even
    return (unsigned short)(u >> 16);
}
__device__ inline float bf2f(unsigned short u) {
    union { float f; unsigned int u; } v; v.u = ((unsigned int)u) << 16;
    return v.f;
}
__device__ inline u16x8 zero8() {
    u16x8 z = {0, 0, 0, 0, 0, 0, 0, 0};
    return z;
}

// ---------------------------------------------------------------------------
// Weight convert (all 4 weights in ONE launch): fp32 [O][K] -> bf16 [K/8][O][8]
// ---------------------------------------------------------------------------
__global__ __launch_bounds__(256)
void wconv_all(const float* __restrict__ w0, const float* __restrict__ w1,
               const float* __restrict__ w2, const float* __restrict__ w3,
               unsigned short* __restrict__ d0, unsigned short* __restrict__ d1,
               unsigned short* __restrict__ d2, unsigned short* __restrict__ d3)
{
    const int bid = blockIdx.x;
    const float* W; unsigned short* WB; int O, K, base;
    if (bid < 96)       { W = w0; WB = d0; O = 768;  K = 256;  base = 0;   }
    else if (bid < 160) { W = w1; WB = d1; O = 256;  K = 512;  base = 96;  }
    else if (bid < 288) { W = w2; WB = d2; O = 1024; K = 256;  base = 160; }
    else                { W = w3; WB = d3; O = 256;  K = 1024; base = 288; }
    const int idx = (bid - base) * 256 + threadIdx.x;
    if (idx >= O * (K >> 3)) return;
    const int o = idx % O;
    const int koct = idx / O;
    u16x8 v;
#pragma unroll
    for (int j = 0; j < 8; j++) v[j] = f2bf(W[(size_t)o * K + koct * 8 + j]);
    *(u16x8*)(WB + ((size_t)koct * O + o) * 8) = v;
}

// ---------------------------------------------------------------------------
// Transpose, dual-source: image ib<16 from X0, else X1.
// ---------------------------------------------------------------------------
__global__ __launch_bounds__(256)
void xpose2(const float* __restrict__ X0, const float* __restrict__ X1,
            unsigned short* __restrict__ XT, const int C)
{
    __shared__ float tt[8][260];
    const int t = threadIdx.x;
    const int octs = C >> 3;
    const int strips = octs * 4;
    const int ib = blockIdx.x / strips;
    const int rem = blockIdx.x - ib * strips;
    const int coct = rem >> 2;
    const int n0 = (rem & 3) * 256;
    const float* src = (ib < 16) ? X0 + (size_t)ib * C * NPIX
                                 : X1 + (size_t)(ib - 16) * C * NPIX;
    const int cc = t >> 5;
    const int c8 = (t & 31) * 8;
    const float* xp = src + ((size_t)(coct * 8 + cc)) * NPIX + n0 + c8;
    *(float4*)(&tt[cc][c8])     = *(const float4*)(xp);
    *(float4*)(&tt[cc][c8 + 4]) = *(const float4*)(xp + 4);
    __syncthreads();
    u16x8 v;
#pragma unroll
    for (int j = 0; j < 8; j++) v[j] = f2bf(tt[j][t]);
    *(u16x8*)(XT + (((size_t)ib * octs + coct) * NPIX + n0 + t) * 8) = v;
}

// ---------------------------------------------------------------------------
// MFMA GEMM, DIRECT global->VGPR fragments, constexpr-DEPTH register pipeline
// (DEPTH=2 for dual-stream MI>=2, else 4; all set indices fully unrolled).
// Operands blocked bf16 [K/8][rows][8].  K/8 multiple of 4*DEPTH.
// EPI: 0 plain; 1 BN + fp32 residual; 2 bias+hswish; 3 DUAL interleaved
//      second K-stream X2 into acc2 (shared A), BN+2*shift+bf16 residuals.
// OMODE: 0 fp32 [c][n] (+ACC); 1 bf16 [c][n] direct; 2 blocked bf16 direct.
// NO epilogue LDS, no barriers.
// ---------------------------------------------------------------------------
template<int BM, int BN, int EPI, bool ACC, int OMODE>
__global__ __launch_bounds__(256)
void gemm_direct(const unsigned short* __restrict__ X, const unsigned short* __restrict__ X2,
                 const unsigned short* __restrict__ W,
                 float* __restrict__ Y, unsigned short* __restrict__ YB,
                 const int O, const int K,
                 const float* __restrict__ res, const float* __restrict__ res2,
                 const unsigned short* __restrict__ resb,
                 const float* __restrict__ bng, const float* __restrict__ bnb,
                 const float* __restrict__ bnm, const float* __restrict__ bnv,
                 const float* __restrict__ bias)
{
    constexpr int TN = NPIX / BN;
    constexpr int WAVES_N = (BN >= 128) ? 2 : 1;
    constexpr int WM = BM / (4 / WAVES_N);
    constexpr int MI = WM / 16;
    constexpr int NJ = 4;
    constexpr int DEPTH = (EPI == 3 && MI >= 2) ? 2 : 4;

    const int t    = threadIdx.x;
    const int lane = t & 63;
    const int w    = t >> 6;

    // XCD-bijective block swizzle (all grids are multiples of 8)
    const int gx  = gridDim.x;
    const int nwg = gx * gridDim.y;
    int bid = blockIdx.y * gx + blockIdx.x;
    bid = (bid & 7) * (nwg >> 3) + (bid >> 3);
    const int bx = bid % gx;
    const int by = bid / gx;

    const int o0 = bx * BM;
    const int b  = by / TN;
    const int n0 = (by % TN) * BN;

    const int wn = (WAVES_N == 2) ? (w & 1) * 64 : 0;
    const int wo = (WAVES_N == 2) ? (w >> 1) * WM : w * WM;

    const int l16 = lane & 15;
    const int lq  = lane >> 4;

    f32x4 acc[MI][NJ];
    f32x4 acc2[MI][NJ];
#pragma unroll
    for (int i = 0; i < MI; i++)
#pragma unroll
        for (int j = 0; j < NJ; j++) {
            f32x4 z = {0.f, 0.f, 0.f, 0.f};
            acc[i][j] = z;
            acc2[i][j] = z;
        }

    const unsigned short* Ab = W + ((size_t)lq * O + o0 + wo + l16) * 8;
    const size_t strideA = (size_t)O * 8;
    const size_t strideB = (size_t)NPIX * 8;
    const size_t boff = ((size_t)lq * NPIX + n0 + wn + l16) * 8;
    const int octs = K >> 3;                    // multiple of 4*DEPTH

    auto ldA_ = [&](bf16x8* fr, int kb) {
#pragma unroll
        for (int i = 0; i < MI; i++)
            fr[i] = *(const bf16x8*)(Ab + (size_t)kb * strideA + i * 128);
    };
    auto ldB_ = [&](bf16x8* fr, const unsigned short* Bb, int kb) {
#pragma unroll
        for (int j = 0; j < NJ; j++)
            fr[j] = *(const bf16x8*)(Bb + (size_t)kb * strideB + j * 128);
    };
    auto domfma_ = [&](f32x4 (&ac)[MI][NJ], bf16x8* af, bf16x8* bf) {
#pragma unroll
        for (int i = 0; i < MI; i++)
#pragma unroll
            for (int j = 0; j < NJ; j++)
                ac[i][j] = __builtin_amdgcn_mfma_f32_16x16x32_bf16(
                    af[i], bf[j], ac[i][j], 0, 0, 0);
    };

    {
        const unsigned short* B1 = X + (size_t)b * K * NPIX + boff;
        const unsigned short* B2 = (EPI == 3)
            ? X2 + (size_t)b * K * NPIX + boff : nullptr;
        bf16x8 aS[DEPTH][MI], bS[DEPTH][NJ], qS[DEPTH][NJ];
#pragma unroll
        for (int d = 0; d < DEPTH; d++) {
            ldA_(aS[d], d * 4);
            ldB_(bS[d], B1, d * 4);
            if (EPI == 3) ldB_(qS[d], B2, d * 4);
        }
        for (int kb = 0; kb < octs; kb += 4 * DEPTH) {
#pragma unroll
            for (int d = 0; d < DEPTH; d++) {
                domfma_(acc, aS[d], bS[d]);
                if (EPI == 3) domfma_(acc2, aS[d], qS[d]);
                const int nxt = kb + (DEPTH + d) * 4;
                if (nxt < octs) {
                    ldA_(aS[d], nxt);
                    ldB_(bS[d], B1, nxt);
                    if (EPI == 3) ldB_(qS[d], B2, nxt);
                }
            }
        }
    }

    // epilogue. C/D: col = lane&15 (n), row = (lane>>4)*4 + reg (o)
    const int r0q = lq * 4;
    float scale[MI][4], shift[MI][4];
    if (EPI == 1 || EPI == 3) {
#pragma unroll
        for (int i = 0; i < MI; i++)
#pragma unroll
            for (int r = 0; r < 4; r++) {
                const int o = o0 + wo + i * 16 + r0q + r;
                const float inv = bng[o] / sqrtf(bnv[o] + 1e-5f);
                scale[i][r] = inv;
                shift[i][r] = bnb[o] - bnm[o] * inv;
            }
    } else if (EPI == 2) {
#pragma unroll
        for (int i = 0; i < MI; i++)
#pragma unroll
            for (int r = 0; r < 4; r++)
                shift[i][r] = bias[o0 + wo + i * 16 + r0q + r];
    }

#pragma unroll
    for (int i = 0; i < MI; i++) {
#pragma unroll
        for (int j = 0; j < NJ; j++) {
            const int nn = n0 + wn + j * 16 + l16;
            const int ob = wo + i * 16 + r0q;           // o base within tile
            const size_t base = ((size_t)b * O + o0 + ob) * NPIX + nn;
            u16x4 r1v, r2v;
            if (EPI == 3) {
                const size_t ro = (((size_t)(b * 32 + ((o0 + ob) >> 3)) * NPIX + nn) * 8
                                   + ((o0 + ob) & 7));
                r1v = *(const u16x4*)(resb + ro);
                r2v = *(const u16x4*)(resb + (size_t)16 * 262144 + ro);
            }
            u16x4 p4;
#pragma unroll
            for (int r = 0; r < 4; r++) {
                const size_t off = base + (size_t)r * NPIX;
                float v = acc[i][j][r];
                if (EPI == 1) {
                    const float* rs = (b < 16) ? res : res2;
                    const size_t roff = ((size_t)(b & 15) * O + o0 + ob + r) * NPIX + nn;
                    v = v * scale[i][r] + shift[i][r] + rs[roff];
                } else if (EPI == 2) {
                    v += shift[i][r];
                    v = v * fminf(fmaxf(v + 3.f, 0.f), 6.f) * (1.f / 6.f);
                } else if (EPI == 3) {
                    v = (v + acc2[i][j][r]) * scale[i][r] + 2.f * shift[i][r]
                        + bf2f(r1v[r]) + bf2f(r2v[r]);
                }
                if (OMODE == 0 || OMODE == 3) {
                    if (ACC) v += Y[off];
                    Y[off] = v;
                }
                if (OMODE == 1) {
                    YB[off] = f2bf(v);                 // direct [c][n] store
                } else if (OMODE >= 2) {
                    p4[r] = f2bf(v);
                }
            }
            if (OMODE >= 2) {
                // direct blocked store: lane's 4 regs = 4 contiguous channels
                const int oct = (o0 + ob) >> 3;
                const int sub = (o0 + ob) & 7;         // 0 or 4
                *(u16x4*)(YB + (((size_t)b * (O >> 3) + oct) * NPIX + nn) * 8 + sub) = p4;
            }
        }
    }
}

// ---------------------------------------------------------------------------
// Depthwise 5x5 SAME, bf16 [c][n] in/out. 2 channels/block, stride-44 fp32 LDS.
// ---------------------------------------------------------------------------
__global__ __launch_bounds__(256)
void dwconv5x5_v3(const unsigned short* __restrict__ X, const float* __restrict__ Wd,
                  unsigned short* __restrict__ Y)
{
    __shared__ float tile[2 * 36 * 44];
    __shared__ float wl[64];
    const int t     = threadIdx.x;
    const int cpair = blockIdx.x % 384;
    const int b     = blockIdx.x / 384;
    const int cbase = cpair * 2;
    const unsigned short* xp = X + ((size_t)b * 768 + cbase) * NPIX;

#pragma unroll
    for (int k = 0; k < 4; k++) {
        const int i = t + k * 256;
        if (i < 792) {
            f32x4 z = {0.f, 0.f, 0.f, 0.f};
            *(f32x4*)(&tile[i * 4]) = z;
        }
    }
    if (t < 50) wl[(t / 25) * 32 + (t % 25)] = Wd[cbase * 25 + t];
    __syncthreads();

    const int ch = t >> 7;
    const int tm = t & 127;
    const int r  = tm >> 2;
    const int c8 = (tm & 3) * 8;

    {
        const u16x8 v = *(const u16x8*)(xp + (size_t)ch * NPIX + r * 32 + c8);
        float* wp = &tile[ch * 1584 + (r + 2) * 44 + c8 + 2];
#pragma unroll
        for (int j = 0; j < 8; j += 2) {
            float2 f2v = make_float2(bf2f(v[j]), bf2f(v[j + 1]));
            *(float2*)(wp + j) = f2v;
        }
    }
    float wk[25];
#pragma unroll
    for (int i = 0; i < 25; i++) wk[i] = wl[ch * 32 + i];
    __syncthreads();

    float acc[8];
#pragma unroll
    for (int j = 0; j < 8; j++) acc[j] = 0.f;

#pragma unroll
    for (int ky = 0; ky < 5; ky++) {
        const float* rp = &tile[ch * 1584 + (r + ky) * 44 + c8];
        const f32x4 a = *(const f32x4*)(rp);
        const f32x4 bq = *(const f32x4*)(rp + 4);
        const f32x4 cq = *(const f32x4*)(rp + 8);
        const float in[12] = {a[0], a[1], a[2], a[3], bq[0], bq[1], bq[2], bq[3],
                              cq[0], cq[1], cq[2], cq[3]};
#pragma unroll
        for (int kx = 0; kx < 5; kx++) {
            const float wv = wk[ky * 5 + kx];
#pragma unroll
            for (int j = 0; j < 8; j++)
                acc[j] = fmaf(in[j + kx], wv, acc[j]);
        }
    }

    u16x8 o8;
#pragma unroll
    for (int j = 0; j < 8; j++) o8[j] = f2bf(acc[j]);
    *(u16x8*)(Y + ((size_t)b * 768 + cbase + ch) * NPIX + r * 32 + c8) = o8;
}

// ---------------------------------------------------------------------------
// Depthwise 3x3 + bias + hswish, blocked bf16 in/out — 2 px x 8 ch per thread,
// direct global reads, no pixel LDS.
// ---------------------------------------------------------------------------
__global__ __launch_bounds__(256)
void dwconv3x3_h2(const unsigned short* __restrict__ X, const float* __restrict__ Wd,
                  const float* __restrict__ bias, unsigned short* __restrict__ Y)
{
    __shared__ float wl[72];
    __shared__ float bb[8];
    const int t    = threadIdx.x;
    const int bid  = blockIdx.x;
    const int half = bid & 1;
    const int coct = (bid >> 1) & 127;
    const int b    = bid >> 8;
    const unsigned short* xp = X + ((size_t)(b * 128 + coct)) * NPIX * 8;
    if (t < 72) wl[t] = Wd[coct * 72 + t];
    if (t < 8)  bb[t] = bias[coct * 8 + t];
    __syncthreads();

    const int px0 = half * 512 + t * 2;   // 2 consecutive pixels
    const int hr  = px0 >> 5;             // image row
    const int c0  = px0 & 31;             // image col (even)

    float acc[8][2];
#pragma unroll
    for (int ch = 0; ch < 8; ch++) {
        acc[ch][0] = bb[ch];
        acc[ch][1] = bb[ch];
    }

#pragma unroll
    for (int ky = 0; ky < 3; ky++) {
        const int rr = hr + ky - 1;
        if (rr >= 0 && rr < 32) {
            u16x8 P[4];
#pragma unroll
            for (int m = 0; m < 4; m++) {
                const int col = c0 - 1 + m;
                const int colc = col < 0 ? 0 : (col > 31 ? 31 : col);
                u16x8 v = *(const u16x8*)(xp + (size_t)(rr * 32 + colc) * 8);
                if (col < 0 || col > 31) v = zero8();
                P[m] = v;
            }
#pragma unroll
            for (int ch = 0; ch < 8; ch++) {
                float g[4];
#pragma unroll
                for (int m = 0; m < 4; m++) g[m] = bf2f(P[m][ch]);
#pragma unroll
                for (int j = 0; j < 2; j++)
#pragma unroll
                    for (int kx = 0; kx < 3; kx++)
                        acc[ch][j] = fmaf(g[j + kx], wl[ch * 9 + ky * 3 + kx], acc[ch][j]);
            }
        }
    }
    unsigned short* yp = Y + ((size_t)(b * 128 + coct)) * NPIX * 8 + (size_t)px0 * 8;
#pragma unroll
    for (int j = 0; j < 2; j++) {
        u16x8 o8;
#pragma unroll
        for (int ch = 0; ch < 8; ch++) {
            float v = acc[ch][j];
            v = v * fminf(fmaxf(v + 3.f, 0.f), 6.f) * (1.f / 6.f);
            o8[ch] = f2bf(v);
        }
        *(u16x8*)(yp + j * 8) = o8;
    }
}

// ---------------------------------------------------------------------------
// Grouped 32->32 1x1 via MFMA: one block per (b,g), 4 waves x 256-px chunks.
// ---------------------------------------------------------------------------
__global__ __launch_bounds__(256)
void grouped_mfma(unsigned short* __restrict__ D, const float* __restrict__ Wg)
{
    const int t    = threadIdx.x;
    const int lane = t & 63;
    const int w    = t >> 6;
    const int bg   = blockIdx.x;          // b*24 + g
    const int g    = bg % 24;
    const int b    = bg / 24;
    const int l16  = lane & 15;
    const int lq   = lane >> 4;
    const int ko   = lq * 8;              // i-oct within K=32
    const int nb   = w * 256;

    unsigned short* dp = D + ((size_t)(b * 768 + g * 32)) * NPIX;

    // A-frags from fp32 weights: a0 -> o = l16, a1 -> o = 16+l16 (i contiguous)
    bf16x8 a0, a1;
#pragma unroll
    for (int j = 0; j < 8; j++) {
        a0[j] = (short)f2bf(Wg[g * 1024 + l16 * 32 + ko + j]);
        a1[j] = (short)f2bf(Wg[g * 1024 + (16 + l16) * 32 + ko + j]);
    }

    // B-frags: 16 n-tiles of 16 px; lane (lq,l16): b[j] = in[ko+j][nb+tl*16+l16]
    bf16x8 bfr[16];
    const unsigned short* ib = dp + (size_t)ko * NPIX + nb + l16;
#pragma unroll
    for (int tl = 0; tl < 16; tl++) {
        bf16x8 bf;
#pragma unroll
        for (int j = 0; j < 8; j++)
            bf[j] = (short)ib[(size_t)j * NPIX + tl * 16];
        bfr[tl] = bf;
    }

    // compute + store (all reads above complete before any write)
    const int ro = lq * 4;
#pragma unroll
    for (int tl = 0; tl < 16; tl++) {
        f32x4 c0 = {0.f, 0.f, 0.f, 0.f};
        f32x4 c1 = {0.f, 0.f, 0.f, 0.f};
        c0 = __builtin_amdgcn_mfma_f32_16x16x32_bf16(a0, bfr[tl], c0, 0, 0, 0);
        c1 = __builtin_amdgcn_mfma_f32_16x16x32_bf16(a1, bfr[tl], c1, 0, 0, 0);
        const int n = nb + tl * 16 + l16;
#pragma unroll
        for (int r = 0; r < 4; r++) {
            dp[(size_t)(ro + r) * NPIX + n]        = f2bf(c0[r]);
            dp[(size_t)(16 + ro + r) * NPIX + n]   = f2bf(c1[r]);
        }
    }
}

// ---------------------------------------------------------------------------
// FUSED attention v2: one block per (b,h), 4 waves, no transpose LDS.
// ---------------------------------------------------------------------------
__global__ __launch_bounds__(256)
void attn_fused(const unsigned short* __restrict__ qkv,
                const unsigned short* __restrict__ dpw,
                unsigned short* __restrict__ att)
{
    __shared__ float kvred[4][33 * 33];
    __shared__ float kvs[1056];

    const int t    = threadIdx.x;
    const int lane = t & 63;
    const int w    = t >> 6;
    const int bh   = blockIdx.x;
    const int b    = bh >> 4;
    const int h    = bh & 15;

    const unsigned short* base = (h < 8)
        ? qkv + ((size_t)(b * 768 + h * 96)) * NPIX
        : dpw + ((size_t)(b * 768 + (h - 8) * 96)) * NPIX;
    const unsigned short* qp = base;
    const unsigned short* kp = base + 32 * NPIX;
    const unsigned short* vp = base + 64 * NPIX;

    const int l16 = lane & 15;
    const int lq  = lane >> 4;
    const int ko  = lq * 8;
    const int nb  = w * 256;

    // phase 1: kv partials
    {
        f32x4 acc[3][2];
#pragma unroll
        for (int i = 0; i < 3; i++)
#pragma unroll
            for (int j = 0; j < 2; j++) {
                f32x4 z = {0.f, 0.f, 0.f, 0.f};
                acc[i][j] = z;
            }
        bf16x8 ones;
#pragma unroll
        for (int j = 0; j < 8; j++) ones[j] = (l16 == 0) ? (short)0x3F80 : (short)0;

#pragma unroll
        for (int s = 0; s < 8; s++) {
            const int n0 = nb + s * 32 + ko;
            const bf16x8 av0 = *(const bf16x8*)(vp + (size_t)l16 * NPIX + n0);
            const bf16x8 av1 = *(const bf16x8*)(vp + (size_t)(16 + l16) * NPIX + n0);
            const u16x8 k0 = *(const u16x8*)(kp + (size_t)l16 * NPIX + n0);
            const u16x8 k1 = *(const u16x8*)(kp + (size_t)(16 + l16) * NPIX + n0);
            bf16x8 bk0, bk1;
#pragma unroll
            for (int j = 0; j < 8; j++) {
                bk0[j] = (k0[j] & 0x8000u) ? (short)0 : (short)k0[j];
                bk1[j] = (k1[j] & 0x8000u) ? (short)0 : (short)k1[j];
            }
            acc[0][0] = __builtin_amdgcn_mfma_f32_16x16x32_bf16(av0,  bk0, acc[0][0], 0, 0, 0);
            acc[0][1] = __builtin_amdgcn_mfma_f32_16x16x32_bf16(av0,  bk1, acc[0][1], 0, 0, 0);
            acc[1][0] = __builtin_amdgcn_mfma_f32_16x16x32_bf16(av1,  bk0, acc[1][0], 0, 0, 0);
            acc[1][1] = __builtin_amdgcn_mfma_f32_16x16x32_bf16(av1,  bk1, acc[1][1], 0, 0, 0);
            acc[2][0] = __builtin_amdgcn_mfma_f32_16x16x32_bf16(ones, bk0, acc[2][0], 0, 0, 0);
            acc[2][1] = __builtin_amdgcn_mfma_f32_16x16x32_bf16(ones, bk1, acc[2][1], 0, 0, 0);
        }
        const int rbase = lq * 4;
#pragma unroll
        for (int dt = 0; dt < 2; dt++)
#pragma unroll
            for (int et = 0; et < 2; et++)
#pragma unroll
                for (int r = 0; r < 4; r++)
                    kvred[w][(dt * 16 + rbase + r) * 33 + et * 16 + l16] = acc[dt][et][r];
        if (rbase == 0) {
#pragma unroll
            for (int et = 0; et < 2; et++)
                kvred[w][32 * 33 + et * 16 + l16] = acc[2][et][0];
        }
    }
    __syncthreads();
#pragma unroll
    for (int k = 0; k < 5; k++) {
        const int idx = t + k * 256;
        if (idx < 1056) {
            const int a = (idx >> 5) * 33 + (idx & 31);
            kvs[idx] = kvred[0][a] + kvred[1][a] + kvred[2][a] + kvred[3][a];
        }
    }
    __syncthreads();

    // phase 2: out = kv · relu(Q), K=32; output straight from regs.
    bf16x8 a0, a1, a2;
#pragma unroll
    for (int j = 0; j < 8; j++) {
        a0[j] = (short)f2bf(kvs[l16 * 32 + ko + j]);
        a1[j] = (short)f2bf(kvs[(16 + l16) * 32 + ko + j]);
        a2[j] = (l16 == 0) ? (short)f2bf(kvs[32 * 32 + ko + j]) : (short)0;
    }
    bf16x8 bfr[16];
    const unsigned short* qb = qp + (size_t)ko * NPIX + nb + l16;
#pragma unroll
    for (int tl = 0; tl < 16; tl++) {
        bf16x8 bf;
#pragma unroll
        for (int j = 0; j < 8; j++) {
            const unsigned short v = qb[(size_t)j * NPIX + tl * 16];
            bf[j] = (v & 0x8000u) ? (short)0 : (short)v;
        }
        bfr[tl] = bf;
    }

    const int db0 = lq >> 1;
    const int sub = (lq & 1) * 4;
    unsigned short* ab0 = att + (((size_t)(b * 64 + h * 4 + db0)) * NPIX) * 8 + sub;
    unsigned short* ab1 = att + (((size_t)(b * 64 + h * 4 + 2 + db0)) * NPIX) * 8 + sub;

#pragma unroll
    for (int tl = 0; tl < 16; tl++) {
        f32x4 z = {0.f, 0.f, 0.f, 0.f};
        z = __builtin_amdgcn_mfma_f32_16x16x32_bf16(a2, bfr[tl], z, 0, 0, 0);
        const float den = __shfl(z[0], l16, 64);     // den(col l16) from lane l16
        const float inv = 1.f / (den + 1e-15f);
        f32x4 c0 = {0.f, 0.f, 0.f, 0.f};
        f32x4 c1 = {0.f, 0.f, 0.f, 0.f};
        c0 = __builtin_amdgcn_mfma_f32_16x16x32_bf16(a0, bfr[tl], c0, 0, 0, 0);
        c1 = __builtin_amdgcn_mfma_f32_16x16x32_bf16(a1, bfr[tl], c1, 0, 0, 0);
        u16x4 p0, p1;
#pragma unroll
        for (int r = 0; r < 4; r++) {
            p0[r] = f2bf(c0[r] * inv);
            p1[r] = f2bf(c1[r] * inv);
        }
        const size_t n8 = (size_t)(nb + tl * 16 + l16) * 8;
        *(u16x4*)(ab0 + n8) = p0;
        *(u16x4*)(ab1 + n8) = p1;
    }
}

// ---------------------------------------------------------------------------
extern "C" void kernel_launch(void* const* d_in, const int* in_sizes, int n_in,
                              void* d_out, int out_size, void* d_ws, size_t ws_size,
                              hipStream_t stream)
{
    (void)in_sizes; (void)n_in; (void)out_size;

    const float* x      = (const float*)d_in[0];
    const float* y      = (const float*)d_in[1];
    const float* qkv_w  = (const float*)d_in[2];
    const float* dw5_w  = (const float*)d_in[3];
    const float* pwg_w  = (const float*)d_in[4];
    const float* proj_w = (const float*)d_in[5];
    const float* proj_g = (const float*)d_in[6];
    const float* proj_b = (const float*)d_in[7];
    const float* proj_m = (const float*)d_in[8];
    const float* proj_v = (const float*)d_in[9];
    const float* inv_w  = (const float*)d_in[10];
    const float* inv_b  = (const float*)d_in[11];
    const float* dwc_w  = (const float*)d_in[12];
    const float* dwc_b  = (const float*)d_in[13];
    const float* pw_w   = (const float*)d_in[14];
    const float* pw_g   = (const float*)d_in[15];
    const float* pw_b   = (const float*)d_in[16];
    const float* pw_m   = (const float*)d_in[17];
    const float* pw_v   = (const float*)d_in[18];

    float* ws = (float*)d_ws;
    unsigned short* wqkv_b  = (unsigned short*)(ws + WQKV_OFF);
    unsigned short* wproj_b = (unsigned short*)(ws + WPROJ_OFF);
    unsigned short* winv_b  = (unsigned short*)(ws + WINV_OFF);
    unsigned short* wpw_b   = (unsigned short*)(ws + WPW_OFF);
    float* out = (float*)d_out;

    wconv_all<<<dim3(416), 256, 0, stream>>>(qkv_w, proj_w, inv_w, pw_w,
                                             wqkv_b, wproj_b, winv_b, wpw_b);

    if (ws_size >= (size_t)BATCH_NEED_F * 4ull) {
        // ---------------- batched path: both chains as images 0..31 ----------
        unsigned short* bxt  = (unsigned short*)(ws + BXT_OFF);
        unsigned short* bqkv = (unsigned short*)(ws + BQKV_OFF);
        unsigned short* bdpw = (unsigned short*)(ws + BDPW_OFF);
        unsigned short* batt = (unsigned short*)(ws + BATT_OFF);
        unsigned short* bt1t = (unsigned short*)(ws + BT1T_OFF);
        unsigned short* bh1t = (unsigned short*)(ws + BH1T_OFF);
        unsigned short* bh2t = (unsigned short*)(ws + BH2T_OFF);

        xpose2<<<dim3(4096), 256, 0, stream>>>(x, y, bxt, 256);
        gemm_direct<128, 128, 0, false, 1><<<dim3(6, 256), 256, 0, stream>>>(
            bxt, nullptr, wqkv_b, nullptr, bqkv, 768, 256,
            nullptr, nullptr, nullptr, nullptr, nullptr, nullptr, nullptr, nullptr);
        dwconv5x5_v3<<<dim3(12288), 256, 0, stream>>>(bqkv, dw5_w, bdpw);
        grouped_mfma<<<dim3(768), 256, 0, stream>>>(bdpw, pwg_w);
        attn_fused<<<dim3(512), 256, 0, stream>>>(bqkv, bdpw, batt);
        gemm_direct<64, 64, 1, false, 2><<<dim3(4, 512), 256, 0, stream>>>(
            batt, nullptr, wproj_b, nullptr, bt1t, 256, 512,
            x, y, nullptr, proj_g, proj_b, proj_m, proj_v, nullptr);
        gemm_direct<128, 128, 2, false, 2><<<dim3(8, 256), 256, 0, stream>>>(
            bt1t, nullptr, winv_b, nullptr, bh1t, 1024, 256,
            nullptr, nullptr, nullptr, nullptr, nullptr, nullptr, nullptr, inv_b);
        dwconv3x3_h2<<<dim3(8192), 256, 0, stream>>>(bh1t, dwc_w, dwc_b, bh2t);
        gemm_direct<64, 128, 3, false, 0><<<dim3(4, 128), 256, 0, stream>>>(
            bh2t, bh2t + (size_t)16 * 1024 * 1024, wpw_b, out, nullptr, 256, 1024,
            nullptr, nullptr, bt1t, pw_g, pw_b, pw_m, pw_v, nullptr);
    } else {
        // ---------------- fallback: per-chain (R14 structure) ----------------
        unsigned short* wxt  = (unsigned short*)(ws + XT_OFF);
        unsigned short* wqkv = (unsigned short*)(ws + QKV_OFF);
        unsigned short* wdpw = (unsigned short*)(ws + DPW_OFF);
        unsigned short* watt = (unsigned short*)(ws + ATT_OFF);
        float*          wt1  = ws + T1_OFF;
        unsigned short* wt1t = (unsigned short*)(ws + T1T_OFF);
        unsigned short* wh1t = (unsigned short*)(ws + H1T_OFF);
        unsigned short* wh2t = (unsigned short*)(ws + H2T_OFF);

        for (int blk = 0; blk < 2; blk++) {
            const float* t = (blk == 0) ? x : y;
            xpose2<<<dim3(2048), 256, 0, stream>>>(t, t, wxt, 256);
            gemm_direct<128, 128, 0, false, 1><<<dim3(6, 128), 256, 0, stream>>>(
                wxt, nullptr, wqkv_b, nullptr, wqkv, 768, 256,
                nullptr, nullptr, nullptr, nullptr, nullptr, nullptr, nullptr, nullptr);
            dwconv5x5_v3<<<dim3(6144), 256, 0, stream>>>(wqkv, dw5_w, wdpw);
            grouped_mfma<<<dim3(384), 256, 0, stream>>>(wdpw, pwg_w);
            attn_fused<<<dim3(256), 256, 0, stream>>>(wqkv, wdpw, watt);
            gemm_direct<64, 64, 1, false, 3><<<dim3(4, 256), 256, 0, stream>>>(
                watt, watt, wproj_b, wt1, wt1t, 256, 512,
                t, t, nullptr, proj_g, proj_b, proj_m, proj_v, nullptr);
            gemm_direct<128, 128, 2, false, 2><<<dim3(8, 128), 256, 0, stream>>>(
                wt1t, nullptr, winv_b, nullptr, wh1t, 1024, 256,
                nullptr, nullptr, nullptr, nullptr, nullptr, nullptr, nullptr, inv_b);
            dwconv3x3_h2<<<dim3(4096), 256, 0, stream>>>(wh1t, dwc_w, dwc_b, wh2t);
            if (blk == 0) {
                gemm_direct<64, 64, 1, false, 0><<<dim3(4, 256), 256, 0, stream>>>(
                    wh2t, nullptr, wpw_b, out, nullptr, 256, 1024,
                    wt1, wt1, nullptr, pw_g, pw_b, pw_m, pw_v, nullptr);
            } else {
                gemm_direct<64, 64, 1, true, 0><<<dim3(4, 256), 256, 0, stream>>>(
                    wh2t, nullptr, wpw_b, out, nullptr, 256, 1024,
                    wt1, wt1, nullptr, pw_g, pw_b, pw_m, pw_v, nullptr);
            }
        }
    }
}

// Round 24
// 216.286 us; speedup vs baseline: 1.2312x; 1.0237x over previous
//
#include <hip/hip_runtime.h>
#include <cstddef>

#define NPIX 1024   // H*W = 32*32

// ---------------------------------------------------------------------------
// Workspace layouts (float-slot offsets).
// BATCHED (both residual chains as images 0..31): peak 38,174,720 floats.
// FALLBACK (per-chain, R14 layout): peak 34,045,952 floats.
// ---------------------------------------------------------------------------
static constexpr size_t WQKV_OFF  = 0;
static constexpr size_t WPROJ_OFF = 98304;
static constexpr size_t WINV_OFF  = 163840;
static constexpr size_t WPW_OFF   = 294912;
// batched
static constexpr size_t BXT_OFF   = 425984;
static constexpr size_t BQKV_OFF  = 4620288;
static constexpr size_t BDPW_OFF  = 17203200;
static constexpr size_t BATT_OFF  = 29786112;
static constexpr size_t BT1T_OFF  = 425984;     // alias XT32
static constexpr size_t BH1T_OFF  = 4620288;    // alias QKV32..
static constexpr size_t BH2T_OFF  = 21397504;   // alias DPW-tail+ATT
static constexpr size_t BATCH_NEED_F = 38174720;
// fallback (R14)
static constexpr size_t XT_OFF    = 425984;
static constexpr size_t QKV_OFF   = 2523136;
static constexpr size_t DPW_OFF   = 8814592;
static constexpr size_t ATT_OFF   = 15106048;
static constexpr size_t T1_OFF    = 21463040;
static constexpr size_t T1T_OFF   = 25657344;
static constexpr size_t H1T_OFF   = 425984;
static constexpr size_t H2T_OFF   = 25657344;

typedef __attribute__((ext_vector_type(8))) short bf16x8;
typedef __attribute__((ext_vector_type(8))) unsigned short u16x8;
typedef __attribute__((ext_vector_type(4))) unsigned short u16x4;
typedef __attribute__((ext_vector_type(4))) float f32x4;

__device__ inline unsigned short f2bf(float f) {
    union { float f; unsigned int u; } v; v.f = f;
    unsigned int u = v.u;
    u += 0x7FFFu + ((u >> 16) & 1u);        // round-to-nearest-even
    return (unsigned short)(u >> 16);
}
__device__ inline float bf2f(unsigned short u) {
    union { float f; unsigned int u; } v; v.u = ((unsigned int)u) << 16;
    return v.f;
}
__device__ inline u16x8 zero8() {
    u16x8 z = {0, 0, 0, 0, 0, 0, 0, 0};
    return z;
}

// ---------------------------------------------------------------------------
// Weight convert (all 4 weights in ONE launch): fp32 [O][K] -> bf16 [K/8][O][8]
// ---------------------------------------------------------------------------
__global__ __launch_bounds__(256)
void wconv_all(const float* __restrict__ w0, const float* __restrict__ w1,
               const float* __restrict__ w2, const float* __restrict__ w3,
               unsigned short* __restrict__ d0, unsigned short* __restrict__ d1,
               unsigned short* __restrict__ d2, unsigned short* __restrict__ d3)
{
    const int bid = blockIdx.x;
    const float* W; unsigned short* WB; int O, K, base;
    if (bid < 96)       { W = w0; WB = d0; O = 768;  K = 256;  base = 0;   }
    else if (bid < 160) { W = w1; WB = d1; O = 256;  K = 512;  base = 96;  }
    else if (bid < 288) { W = w2; WB = d2; O = 1024; K = 256;  base = 160; }
    else                { W = w3; WB = d3; O = 256;  K = 1024; base = 288; }
    const int idx = (bid - base) * 256 + threadIdx.x;
    if (idx >= O * (K >> 3)) return;
    const int o = idx % O;
    const int koct = idx / O;
    u16x8 v;
#pragma unroll
    for (int j = 0; j < 8; j++) v[j] = f2bf(W[(size_t)o * K + koct * 8 + j]);
    *(u16x8*)(WB + ((size_t)koct * O + o) * 8) = v;
}

// ---------------------------------------------------------------------------
// Transpose, dual-source: image ib<16 from X0, else X1.
// ---------------------------------------------------------------------------
__global__ __launch_bounds__(256)
void xpose2(const float* __restrict__ X0, const float* __restrict__ X1,
            unsigned short* __restrict__ XT, const int C)
{
    __shared__ float tt[8][260];
    const int t = threadIdx.x;
    const int octs = C >> 3;
    const int strips = octs * 4;
    const int ib = blockIdx.x / strips;
    const int rem = blockIdx.x - ib * strips;
    const int coct = rem >> 2;
    const int n0 = (rem & 3) * 256;
    const float* src = (ib < 16) ? X0 + (size_t)ib * C * NPIX
                                 : X1 + (size_t)(ib - 16) * C * NPIX;
    const int cc = t >> 5;
    const int c8 = (t & 31) * 8;
    const float* xp = src + ((size_t)(coct * 8 + cc)) * NPIX + n0 + c8;
    *(float4*)(&tt[cc][c8])     = *(const float4*)(xp);
    *(float4*)(&tt[cc][c8 + 4]) = *(const float4*)(xp + 4);
    __syncthreads();
    u16x8 v;
#pragma unroll
    for (int j = 0; j < 8; j++) v[j] = f2bf(tt[j][t]);
    *(u16x8*)(XT + (((size_t)ib * octs + coct) * NPIX + n0 + t) * 8) = v;
}

// ---------------------------------------------------------------------------
// MFMA GEMM, DIRECT global->VGPR fragments, constexpr-DEPTH register pipeline
// (DEPTH=2 for dual-stream MI>=2, else 4; all set indices fully unrolled).
// Operands blocked bf16 [K/8][rows][8].  K/8 multiple of 4*DEPTH.
// EPI: 0 plain; 1 BN + fp32 residual; 2 bias+hswish; 3 DUAL interleaved
//      second K-stream X2 into acc2 (shared A), BN+2*shift+bf16 residuals.
// OMODE: 0 fp32 [c][n] (+ACC); 1 bf16 [c][n] direct; 2 blocked bf16 direct.
// NO epilogue LDS, no barriers.
// ---------------------------------------------------------------------------
template<int BM, int BN, int EPI, bool ACC, int OMODE>
__global__ __launch_bounds__(256)
void gemm_direct(const unsigned short* __restrict__ X, const unsigned short* __restrict__ X2,
                 const unsigned short* __restrict__ W,
                 float* __restrict__ Y, unsigned short* __restrict__ YB,
                 const int O, const int K,
                 const float* __restrict__ res, const float* __restrict__ res2,
                 const unsigned short* __restrict__ resb,
                 const float* __restrict__ bng, const float* __restrict__ bnb,
                 const float* __restrict__ bnm, const float* __restrict__ bnv,
                 const float* __restrict__ bias)
{
    constexpr int TN = NPIX / BN;
    constexpr int WAVES_N = (BN >= 128) ? 2 : 1;
    constexpr int WM = BM / (4 / WAVES_N);
    constexpr int MI = WM / 16;
    constexpr int NJ = 4;
    constexpr int DEPTH = (EPI == 3 && MI >= 2) ? 2 : 4;

    const int t    = threadIdx.x;
    const int lane = t & 63;
    const int w    = t >> 6;

    // XCD-bijective block swizzle (all grids are multiples of 8)
    const int gx  = gridDim.x;
    const int nwg = gx * gridDim.y;
    int bid = blockIdx.y * gx + blockIdx.x;
    bid = (bid & 7) * (nwg >> 3) + (bid >> 3);
    const int bx = bid % gx;
    const int by = bid / gx;

    const int o0 = bx * BM;
    const int b  = by / TN;
    const int n0 = (by % TN) * BN;

    const int wn = (WAVES_N == 2) ? (w & 1) * 64 : 0;
    const int wo = (WAVES_N == 2) ? (w >> 1) * WM : w * WM;

    const int l16 = lane & 15;
    const int lq  = lane >> 4;

    f32x4 acc[MI][NJ];
    f32x4 acc2[MI][NJ];
#pragma unroll
    for (int i = 0; i < MI; i++)
#pragma unroll
        for (int j = 0; j < NJ; j++) {
            f32x4 z = {0.f, 0.f, 0.f, 0.f};
            acc[i][j] = z;
            acc2[i][j] = z;
        }

    const unsigned short* Ab = W + ((size_t)lq * O + o0 + wo + l16) * 8;
    const size_t strideA = (size_t)O * 8;
    const size_t strideB = (size_t)NPIX * 8;
    const size_t boff = ((size_t)lq * NPIX + n0 + wn + l16) * 8;
    const int octs = K >> 3;                    // multiple of 4*DEPTH

    auto ldA_ = [&](bf16x8* fr, int kb) {
#pragma unroll
        for (int i = 0; i < MI; i++)
            fr[i] = *(const bf16x8*)(Ab + (size_t)kb * strideA + i * 128);
    };
    auto ldB_ = [&](bf16x8* fr, const unsigned short* Bb, int kb) {
#pragma unroll
        for (int j = 0; j < NJ; j++)
            fr[j] = *(const bf16x8*)(Bb + (size_t)kb * strideB + j * 128);
    };
    auto domfma_ = [&](f32x4 (&ac)[MI][NJ], bf16x8* af, bf16x8* bf) {
#pragma unroll
        for (int i = 0; i < MI; i++)
#pragma unroll
            for (int j = 0; j < NJ; j++)
                ac[i][j] = __builtin_amdgcn_mfma_f32_16x16x32_bf16(
                    af[i], bf[j], ac[i][j], 0, 0, 0);
    };

    {
        const unsigned short* B1 = X + (size_t)b * K * NPIX + boff;
        const unsigned short* B2 = (EPI == 3)
            ? X2 + (size_t)b * K * NPIX + boff : nullptr;
        bf16x8 aS[DEPTH][MI], bS[DEPTH][NJ], qS[DEPTH][NJ];
#pragma unroll
        for (int d = 0; d < DEPTH; d++) {
            ldA_(aS[d], d * 4);
            ldB_(bS[d], B1, d * 4);
            if (EPI == 3) ldB_(qS[d], B2, d * 4);
        }
        for (int kb = 0; kb < octs; kb += 4 * DEPTH) {
#pragma unroll
            for (int d = 0; d < DEPTH; d++) {
                domfma_(acc, aS[d], bS[d]);
                if (EPI == 3) domfma_(acc2, aS[d], qS[d]);
                const int nxt = kb + (DEPTH + d) * 4;
                if (nxt < octs) {
                    ldA_(aS[d], nxt);
                    ldB_(bS[d], B1, nxt);
                    if (EPI == 3) ldB_(qS[d], B2, nxt);
                }
            }
        }
    }

    // epilogue. C/D: col = lane&15 (n), row = (lane>>4)*4 + reg (o)
    const int r0q = lq * 4;
    float scale[MI][4], shift[MI][4];
    if (EPI == 1 || EPI == 3) {
#pragma unroll
        for (int i = 0; i < MI; i++)
#pragma unroll
            for (int r = 0; r < 4; r++) {
                const int o = o0 + wo + i * 16 + r0q + r;
                const float inv = bng[o] / sqrtf(bnv[o] + 1e-5f);
                scale[i][r] = inv;
                shift[i][r] = bnb[o] - bnm[o] * inv;
            }
    } else if (EPI == 2) {
#pragma unroll
        for (int i = 0; i < MI; i++)
#pragma unroll
            for (int r = 0; r < 4; r++)
                shift[i][r] = bias[o0 + wo + i * 16 + r0q + r];
    }

#pragma unroll
    for (int i = 0; i < MI; i++) {
#pragma unroll
        for (int j = 0; j < NJ; j++) {
            const int nn = n0 + wn + j * 16 + l16;
            const int ob = wo + i * 16 + r0q;           // o base within tile
            const size_t base = ((size_t)b * O + o0 + ob) * NPIX + nn;
            u16x4 r1v, r2v;
            if (EPI == 3) {
                const size_t ro = (((size_t)(b * 32 + ((o0 + ob) >> 3)) * NPIX + nn) * 8
                                   + ((o0 + ob) & 7));
                r1v = *(const u16x4*)(resb + ro);
                r2v = *(const u16x4*)(resb + (size_t)16 * 262144 + ro);
            }
            u16x4 p4;
#pragma unroll
            for (int r = 0; r < 4; r++) {
                const size_t off = base + (size_t)r * NPIX;
                float v = acc[i][j][r];
                if (EPI == 1) {
                    const float* rs = (b < 16) ? res : res2;
                    const size_t roff = ((size_t)(b & 15) * O + o0 + ob + r) * NPIX + nn;
                    v = v * scale[i][r] + shift[i][r] + rs[roff];
                } else if (EPI == 2) {
                    v += shift[i][r];
                    v = v * fminf(fmaxf(v + 3.f, 0.f), 6.f) * (1.f / 6.f);
                } else if (EPI == 3) {
                    v = (v + acc2[i][j][r]) * scale[i][r] + 2.f * shift[i][r]
                        + bf2f(r1v[r]) + bf2f(r2v[r]);
                }
                if (OMODE == 0 || OMODE == 3) {
                    if (ACC) v += Y[off];
                    Y[off] = v;
                }
                if (OMODE == 1) {
                    YB[off] = f2bf(v);                 // direct [c][n] store
                } else if (OMODE >= 2) {
                    p4[r] = f2bf(v);
                }
            }
            if (OMODE >= 2) {
                // direct blocked store: lane's 4 regs = 4 contiguous channels
                const int oct = (o0 + ob) >> 3;
                const int sub = (o0 + ob) & 7;         // 0 or 4
                *(u16x4*)(YB + (((size_t)b * (O >> 3) + oct) * NPIX + nn) * 8 + sub) = p4;
            }
        }
    }
}

// ---------------------------------------------------------------------------
// Depthwise 5x5 SAME, bf16 [c][n] in/out. 2 channels/block, stride-44 fp32 LDS.
// ---------------------------------------------------------------------------
__global__ __launch_bounds__(256)
void dwconv5x5_v3(const unsigned short* __restrict__ X, const float* __restrict__ Wd,
                  unsigned short* __restrict__ Y)
{
    __shared__ float tile[2 * 36 * 44];
    __shared__ float wl[64];
    const int t     = threadIdx.x;
    const int cpair = blockIdx.x % 384;
    const int b     = blockIdx.x / 384;
    const int cbase = cpair * 2;
    const unsigned short* xp = X + ((size_t)b * 768 + cbase) * NPIX;

#pragma unroll
    for (int k = 0; k < 4; k++) {
        const int i = t + k * 256;
        if (i < 792) {
            f32x4 z = {0.f, 0.f, 0.f, 0.f};
            *(f32x4*)(&tile[i * 4]) = z;
        }
    }
    if (t < 50) wl[(t / 25) * 32 + (t % 25)] = Wd[cbase * 25 + t];
    __syncthreads();

    const int ch = t >> 7;
    const int tm = t & 127;
    const int r  = tm >> 2;
    const int c8 = (tm & 3) * 8;

    {
        const u16x8 v = *(const u16x8*)(xp + (size_t)ch * NPIX + r * 32 + c8);
        float* wp = &tile[ch * 1584 + (r + 2) * 44 + c8 + 2];
#pragma unroll
        for (int j = 0; j < 8; j += 2) {
            float2 f2v = make_float2(bf2f(v[j]), bf2f(v[j + 1]));
            *(float2*)(wp + j) = f2v;
        }
    }
    float wk[25];
#pragma unroll
    for (int i = 0; i < 25; i++) wk[i] = wl[ch * 32 + i];
    __syncthreads();

    float acc[8];
#pragma unroll
    for (int j = 0; j < 8; j++) acc[j] = 0.f;

#pragma unroll
    for (int ky = 0; ky < 5; ky++) {
        const float* rp = &tile[ch * 1584 + (r + ky) * 44 + c8];
        const f32x4 a = *(const f32x4*)(rp);
        const f32x4 bq = *(const f32x4*)(rp + 4);
        const f32x4 cq = *(const f32x4*)(rp + 8);
        const float in[12] = {a[0], a[1], a[2], a[3], bq[0], bq[1], bq[2], bq[3],
                              cq[0], cq[1], cq[2], cq[3]};
#pragma unroll
        for (int kx = 0; kx < 5; kx++) {
            const float wv = wk[ky * 5 + kx];
#pragma unroll
            for (int j = 0; j < 8; j++)
                acc[j] = fmaf(in[j + kx], wv, acc[j]);
        }
    }

    u16x8 o8;
#pragma unroll
    for (int j = 0; j < 8; j++) o8[j] = f2bf(acc[j]);
    *(u16x8*)(Y + ((size_t)b * 768 + cbase + ch) * NPIX + r * 32 + c8) = o8;
}

// ---------------------------------------------------------------------------
// Depthwise 3x3 + bias + hswish, blocked bf16 in/out — 2 px x 8 ch per thread,
// direct global reads, no pixel LDS.
// ---------------------------------------------------------------------------
__global__ __launch_bounds__(256)
void dwconv3x3_h2(const unsigned short* __restrict__ X, const float* __restrict__ Wd,
                  const float* __restrict__ bias, unsigned short* __restrict__ Y)
{
    __shared__ float wl[72];
    __shared__ float bb[8];
    const int t    = threadIdx.x;
    const int bid  = blockIdx.x;
    const int half = bid & 1;
    const int coct = (bid >> 1) & 127;
    const int b    = bid >> 8;
    const unsigned short* xp = X + ((size_t)(b * 128 + coct)) * NPIX * 8;
    if (t < 72) wl[t] = Wd[coct * 72 + t];
    if (t < 8)  bb[t] = bias[coct * 8 + t];
    __syncthreads();

    const int px0 = half * 512 + t * 2;   // 2 consecutive pixels
    const int hr  = px0 >> 5;             // image row
    const int c0  = px0 & 31;             // image col (even)

    float acc[8][2];
#pragma unroll
    for (int ch = 0; ch < 8; ch++) {
        acc[ch][0] = bb[ch];
        acc[ch][1] = bb[ch];
    }

#pragma unroll
    for (int ky = 0; ky < 3; ky++) {
        const int rr = hr + ky - 1;
        if (rr >= 0 && rr < 32) {
            u16x8 P[4];
#pragma unroll
            for (int m = 0; m < 4; m++) {
                const int col = c0 - 1 + m;
                const int colc = col < 0 ? 0 : (col > 31 ? 31 : col);
                u16x8 v = *(const u16x8*)(xp + (size_t)(rr * 32 + colc) * 8);
                if (col < 0 || col > 31) v = zero8();
                P[m] = v;
            }
#pragma unroll
            for (int ch = 0; ch < 8; ch++) {
                float g[4];
#pragma unroll
                for (int m = 0; m < 4; m++) g[m] = bf2f(P[m][ch]);
#pragma unroll
                for (int j = 0; j < 2; j++)
#pragma unroll
                    for (int kx = 0; kx < 3; kx++)
                        acc[ch][j] = fmaf(g[j + kx], wl[ch * 9 + ky * 3 + kx], acc[ch][j]);
            }
        }
    }
    unsigned short* yp = Y + ((size_t)(b * 128 + coct)) * NPIX * 8 + (size_t)px0 * 8;
#pragma unroll
    for (int j = 0; j < 2; j++) {
        u16x8 o8;
#pragma unroll
        for (int ch = 0; ch < 8; ch++) {
            float v = acc[ch][j];
            v = v * fminf(fmaxf(v + 3.f, 0.f), 6.f) * (1.f / 6.f);
            o8[ch] = f2bf(v);
        }
        *(u16x8*)(yp + j * 8) = o8;
    }
}

// ---------------------------------------------------------------------------
// Grouped 32->32 1x1 via MFMA: one block per (b,g), 4 waves x 256-px chunks.
// ---------------------------------------------------------------------------
__global__ __launch_bounds__(256)
void grouped_mfma(unsigned short* __restrict__ D, const float* __restrict__ Wg)
{
    const int t    = threadIdx.x;
    const int lane = t & 63;
    const int w    = t >> 6;
    const int bg   = blockIdx.x;          // b*24 + g
    const int g    = bg % 24;
    const int b    = bg / 24;
    const int l16  = lane & 15;
    const int lq   = lane >> 4;
    const int ko   = lq * 8;              // i-oct within K=32
    const int nb   = w * 256;

    unsigned short* dp = D + ((size_t)(b * 768 + g * 32)) * NPIX;

    // A-frags from fp32 weights: a0 -> o = l16, a1 -> o = 16+l16 (i contiguous)
    bf16x8 a0, a1;
#pragma unroll
    for (int j = 0; j < 8; j++) {
        a0[j] = (short)f2bf(Wg[g * 1024 + l16 * 32 + ko + j]);
        a1[j] = (short)f2bf(Wg[g * 1024 + (16 + l16) * 32 + ko + j]);
    }

    // B-frags: 16 n-tiles of 16 px; lane (lq,l16): b[j] = in[ko+j][nb+tl*16+l16]
    bf16x8 bfr[16];
    const unsigned short* ib = dp + (size_t)ko * NPIX + nb + l16;
#pragma unroll
    for (int tl = 0; tl < 16; tl++) {
        bf16x8 bf;
#pragma unroll
        for (int j = 0; j < 8; j++)
            bf[j] = (short)ib[(size_t)j * NPIX + tl * 16];
        bfr[tl] = bf;
    }

    // compute + store (all reads above complete before any write)
    const int ro = lq * 4;
#pragma unroll
    for (int tl = 0; tl < 16; tl++) {
        f32x4 c0 = {0.f, 0.f, 0.f, 0.f};
        f32x4 c1 = {0.f, 0.f, 0.f, 0.f};
        c0 = __builtin_amdgcn_mfma_f32_16x16x32_bf16(a0, bfr[tl], c0, 0, 0, 0);
        c1 = __builtin_amdgcn_mfma_f32_16x16x32_bf16(a1, bfr[tl], c1, 0, 0, 0);
        const int n = nb + tl * 16 + l16;
#pragma unroll
        for (int r = 0; r < 4; r++) {
            dp[(size_t)(ro + r) * NPIX + n]        = f2bf(c0[r]);
            dp[(size_t)(16 + ro + r) * NPIX + n]   = f2bf(c1[r]);
        }
    }
}

// ---------------------------------------------------------------------------
// FUSED attention v3: one block per (b,h), 8 WAVES (512 threads) — doubles
// waves/CU vs v2 (grid is only 2 blocks/CU). Each wave owns a 128-px chunk
// in both phases. No transpose LDS; direct reg->global stores.
// ---------------------------------------------------------------------------
__global__ __launch_bounds__(512)
void attn_fused(const unsigned short* __restrict__ qkv,
                const unsigned short* __restrict__ dpw,
                unsigned short* __restrict__ att)
{
    __shared__ float kvred[8][33 * 33];
    __shared__ float kvs[1056];

    const int t    = threadIdx.x;
    const int lane = t & 63;
    const int w    = t >> 6;              // 0..7
    const int bh   = blockIdx.x;
    const int b    = bh >> 4;
    const int h    = bh & 15;

    const unsigned short* base = (h < 8)
        ? qkv + ((size_t)(b * 768 + h * 96)) * NPIX
        : dpw + ((size_t)(b * 768 + (h - 8) * 96)) * NPIX;
    const unsigned short* qp = base;
    const unsigned short* kp = base + 32 * NPIX;
    const unsigned short* vp = base + 64 * NPIX;

    const int l16 = lane & 15;
    const int lq  = lane >> 4;
    const int ko  = lq * 8;
    const int nb  = w * 128;              // 128-px chunk per wave

    // phase 1: kv partials over this wave's 128 px (4 k-steps of 32)
    {
        f32x4 acc[3][2];
#pragma unroll
        for (int i = 0; i < 3; i++)
#pragma unroll
            for (int j = 0; j < 2; j++) {
                f32x4 z = {0.f, 0.f, 0.f, 0.f};
                acc[i][j] = z;
            }
        bf16x8 ones;
#pragma unroll
        for (int j = 0; j < 8; j++) ones[j] = (l16 == 0) ? (short)0x3F80 : (short)0;

#pragma unroll
        for (int s = 0; s < 4; s++) {
            const int n0 = nb + s * 32 + ko;
            const bf16x8 av0 = *(const bf16x8*)(vp + (size_t)l16 * NPIX + n0);
            const bf16x8 av1 = *(const bf16x8*)(vp + (size_t)(16 + l16) * NPIX + n0);
            const u16x8 k0 = *(const u16x8*)(kp + (size_t)l16 * NPIX + n0);
            const u16x8 k1 = *(const u16x8*)(kp + (size_t)(16 + l16) * NPIX + n0);
            bf16x8 bk0, bk1;
#pragma unroll
            for (int j = 0; j < 8; j++) {
                bk0[j] = (k0[j] & 0x8000u) ? (short)0 : (short)k0[j];
                bk1[j] = (k1[j] & 0x8000u) ? (short)0 : (short)k1[j];
            }
            acc[0][0] = __builtin_amdgcn_mfma_f32_16x16x32_bf16(av0,  bk0, acc[0][0], 0, 0, 0);
            acc[0][1] = __builtin_amdgcn_mfma_f32_16x16x32_bf16(av0,  bk1, acc[0][1], 0, 0, 0);
            acc[1][0] = __builtin_amdgcn_mfma_f32_16x16x32_bf16(av1,  bk0, acc[1][0], 0, 0, 0);
            acc[1][1] = __builtin_amdgcn_mfma_f32_16x16x32_bf16(av1,  bk1, acc[1][1], 0, 0, 0);
            acc[2][0] = __builtin_amdgcn_mfma_f32_16x16x32_bf16(ones, bk0, acc[2][0], 0, 0, 0);
            acc[2][1] = __builtin_amdgcn_mfma_f32_16x16x32_bf16(ones, bk1, acc[2][1], 0, 0, 0);
        }
        const int rbase = lq * 4;
#pragma unroll
        for (int dt = 0; dt < 2; dt++)
#pragma unroll
            for (int et = 0; et < 2; et++)
#pragma unroll
                for (int r = 0; r < 4; r++)
                    kvred[w][(dt * 16 + rbase + r) * 33 + et * 16 + l16] = acc[dt][et][r];
        if (rbase == 0) {
#pragma unroll
            for (int et = 0; et < 2; et++)
                kvred[w][32 * 33 + et * 16 + l16] = acc[2][et][0];
        }
    }
    __syncthreads();
#pragma unroll
    for (int k = 0; k < 3; k++) {
        const int idx = t + k * 512;
        if (idx < 1056) {
            const int a = (idx >> 5) * 33 + (idx & 31);
            float s = 0.f;
#pragma unroll
            for (int ww = 0; ww < 8; ww++) s += kvred[ww][a];
            kvs[idx] = s;
        }
    }
    __syncthreads();

    // phase 2: out = kv · relu(Q), K=32; this wave covers 8 n-tiles of 16 px.
    bf16x8 a0, a1, a2;
#pragma unroll
    for (int j = 0; j < 8; j++) {
        a0[j] = (short)f2bf(kvs[l16 * 32 + ko + j]);
        a1[j] = (short)f2bf(kvs[(16 + l16) * 32 + ko + j]);
        a2[j] = (l16 == 0) ? (short)f2bf(kvs[32 * 32 + ko + j]) : (short)0;
    }
    bf16x8 bfr[8];
    const unsigned short* qb = qp + (size_t)ko * NPIX + nb + l16;
#pragma unroll
    for (int tl = 0; tl < 8; tl++) {
        bf16x8 bf;
#pragma unroll
        for (int j = 0; j < 8; j++) {
            const unsigned short v = qb[(size_t)j * NPIX + tl * 16];
            bf[j] = (v & 0x8000u) ? (short)0 : (short)v;
        }
        bfr[tl] = bf;
    }

    const int db0 = lq >> 1;
    const int sub = (lq & 1) * 4;
    unsigned short* ab0 = att + (((size_t)(b * 64 + h * 4 + db0)) * NPIX) * 8 + sub;
    unsigned short* ab1 = att + (((size_t)(b * 64 + h * 4 + 2 + db0)) * NPIX) * 8 + sub;

#pragma unroll
    for (int tl = 0; tl < 8; tl++) {
        f32x4 z = {0.f, 0.f, 0.f, 0.f};
        z = __builtin_amdgcn_mfma_f32_16x16x32_bf16(a2, bfr[tl], z, 0, 0, 0);
        const float den = __shfl(z[0], l16, 64);     // den(col l16) from lane l16
        const float inv = 1.f / (den + 1e-15f);
        f32x4 c0 = {0.f, 0.f, 0.f, 0.f};
        f32x4 c1 = {0.f, 0.f, 0.f, 0.f};
        c0 = __builtin_amdgcn_mfma_f32_16x16x32_bf16(a0, bfr[tl], c0, 0, 0, 0);
        c1 = __builtin_amdgcn_mfma_f32_16x16x32_bf16(a1, bfr[tl], c1, 0, 0, 0);
        u16x4 p0, p1;
#pragma unroll
        for (int r = 0; r < 4; r++) {
            p0[r] = f2bf(c0[r] * inv);
            p1[r] = f2bf(c1[r] * inv);
        }
        const size_t n8 = (size_t)(nb + tl * 16 + l16) * 8;
        *(u16x4*)(ab0 + n8) = p0;
        *(u16x4*)(ab1 + n8) = p1;
    }
}

// ---------------------------------------------------------------------------
extern "C" void kernel_launch(void* const* d_in, const int* in_sizes, int n_in,
                              void* d_out, int out_size, void* d_ws, size_t ws_size,
                              hipStream_t stream)
{
    (void)in_sizes; (void)n_in; (void)out_size;

    const float* x      = (const float*)d_in[0];
    const float* y      = (const float*)d_in[1];
    const float* qkv_w  = (const float*)d_in[2];
    const float* dw5_w  = (const float*)d_in[3];
    const float* pwg_w  = (const float*)d_in[4];
    const float* proj_w = (const float*)d_in[5];
    const float* proj_g = (const float*)d_in[6];
    const float* proj_b = (const float*)d_in[7];
    const float* proj_m = (const float*)d_in[8];
    const float* proj_v = (const float*)d_in[9];
    const float* inv_w  = (const float*)d_in[10];
    const float* inv_b  = (const float*)d_in[11];
    const float* dwc_w  = (const float*)d_in[12];
    const float* dwc_b  = (const float*)d_in[13];
    const float* pw_w   = (const float*)d_in[14];
    const float* pw_g   = (const float*)d_in[15];
    const float* pw_b   = (const float*)d_in[16];
    const float* pw_m   = (const float*)d_in[17];
    const float* pw_v   = (const float*)d_in[18];

    float* ws = (float*)d_ws;
    unsigned short* wqkv_b  = (unsigned short*)(ws + WQKV_OFF);
    unsigned short* wproj_b = (unsigned short*)(ws + WPROJ_OFF);
    unsigned short* winv_b  = (unsigned short*)(ws + WINV_OFF);
    unsigned short* wpw_b   = (unsigned short*)(ws + WPW_OFF);
    float* out = (float*)d_out;

    wconv_all<<<dim3(416), 256, 0, stream>>>(qkv_w, proj_w, inv_w, pw_w,
                                             wqkv_b, wproj_b, winv_b, wpw_b);

    if (ws_size >= (size_t)BATCH_NEED_F * 4ull) {
        // ---------------- batched path: both chains as images 0..31 ----------
        unsigned short* bxt  = (unsigned short*)(ws + BXT_OFF);
        unsigned short* bqkv = (unsigned short*)(ws + BQKV_OFF);
        unsigned short* bdpw = (unsigned short*)(ws + BDPW_OFF);
        unsigned short* batt = (unsigned short*)(ws + BATT_OFF);
        unsigned short* bt1t = (unsigned short*)(ws + BT1T_OFF);
        unsigned short* bh1t = (unsigned short*)(ws + BH1T_OFF);
        unsigned short* bh2t = (unsigned short*)(ws + BH2T_OFF);

        xpose2<<<dim3(4096), 256, 0, stream>>>(x, y, bxt, 256);
        gemm_direct<128, 128, 0, false, 1><<<dim3(6, 256), 256, 0, stream>>>(
            bxt, nullptr, wqkv_b, nullptr, bqkv, 768, 256,
            nullptr, nullptr, nullptr, nullptr, nullptr, nullptr, nullptr, nullptr);
        dwconv5x5_v3<<<dim3(12288), 256, 0, stream>>>(bqkv, dw5_w, bdpw);
        grouped_mfma<<<dim3(768), 256, 0, stream>>>(bdpw, pwg_w);
        attn_fused<<<dim3(512), 512, 0, stream>>>(bqkv, bdpw, batt);
        gemm_direct<64, 64, 1, false, 2><<<dim3(4, 512), 256, 0, stream>>>(
            batt, nullptr, wproj_b, nullptr, bt1t, 256, 512,
            x, y, nullptr, proj_g, proj_b, proj_m, proj_v, nullptr);
        gemm_direct<128, 128, 2, false, 2><<<dim3(8, 256), 256, 0, stream>>>(
            bt1t, nullptr, winv_b, nullptr, bh1t, 1024, 256,
            nullptr, nullptr, nullptr, nullptr, nullptr, nullptr, nullptr, inv_b);
        dwconv3x3_h2<<<dim3(8192), 256, 0, stream>>>(bh1t, dwc_w, dwc_b, bh2t);
        gemm_direct<64, 128, 3, false, 0><<<dim3(4, 128), 256, 0, stream>>>(
            bh2t, bh2t + (size_t)16 * 1024 * 1024, wpw_b, out, nullptr, 256, 1024,
            nullptr, nullptr, bt1t, pw_g, pw_b, pw_m, pw_v, nullptr);
    } else {
        // ---------------- fallback: per-chain (R14 structure) ----------------
        unsigned short* wxt  = (unsigned short*)(ws + XT_OFF);
        unsigned short* wqkv = (unsigned short*)(ws + QKV_OFF);
        unsigned short* wdpw = (unsigned short*)(ws + DPW_OFF);
        unsigned short* watt = (unsigned short*)(ws + ATT_OFF);
        float*          wt1  = ws + T1_OFF;
        unsigned short* wt1t = (unsigned short*)(ws + T1T_OFF);
        unsigned short* wh1t = (unsigned short*)(ws + H1T_OFF);
        unsigned short* wh2t = (unsigned short*)(ws + H2T_OFF);

        for (int blk = 0; blk < 2; blk++) {
            const float* t = (blk == 0) ? x : y;
            xpose2<<<dim3(2048), 256, 0, stream>>>(t, t, wxt, 256);
            gemm_direct<128, 128, 0, false, 1><<<dim3(6, 128), 256, 0, stream>>>(
                wxt, nullptr, wqkv_b, nullptr, wqkv, 768, 256,
                nullptr, nullptr, nullptr, nullptr, nullptr, nullptr, nullptr, nullptr);
            dwconv5x5_v3<<<dim3(6144), 256, 0, stream>>>(wqkv, dw5_w, wdpw);
            grouped_mfma<<<dim3(384), 256, 0, stream>>>(wdpw, pwg_w);
            attn_fused<<<dim3(256), 512, 0, stream>>>(wqkv, wdpw, watt);
            gemm_direct<64, 64, 1, false, 3><<<dim3(4, 256), 256, 0, stream>>>(
                watt, watt, wproj_b, wt1, wt1t, 256, 512,
                t, t, nullptr, proj_g, proj_b, proj_m, proj_v, nullptr);
            gemm_direct<128, 128, 2, false, 2><<<dim3(8, 128), 256, 0, stream>>>(
                wt1t, nullptr, winv_b, nullptr, wh1t, 1024, 256,
                nullptr, nullptr, nullptr, nullptr, nullptr, nullptr, nullptr, inv_b);
            dwconv3x3_h2<<<dim3(4096), 256, 0, stream>>>(wh1t, dwc_w, dwc_b, wh2t);
            if (blk == 0) {
                gemm_direct<64, 64, 1, false, 0><<<dim3(4, 256), 256, 0, stream>>>(
                    wh2t, nullptr, wpw_b, out, nullptr, 256, 1024,
                    wt1, wt1, nullptr, pw_g, pw_b, pw_m, pw_v, nullptr);
            } else {
                gemm_direct<64, 64, 1, true, 0><<<dim3(4, 256), 256, 0, stream>>>(
                    wh2t, nullptr, wpw_b, out, nullptr, 256, 1024,
                    wt1, wt1, nullptr, pw_g, pw_b, pw_m, pw_v, nullptr);
            }
        }
    }
}